// Round 1
// baseline (805.511 us; speedup 1.0000x reference)
//
#include <hip/hip_runtime.h>

typedef _Float16 f16;
typedef __attribute__((ext_vector_type(8))) _Float16 f16x8;
typedef __attribute__((ext_vector_type(4))) _Float16 f16x4;
typedef __attribute__((ext_vector_type(4))) float f32x4;

#define T_SEQ 2048
#define NBATCH 4

__device__ __forceinline__ void gld_lds16(const f16* g, f16* l) {
    __builtin_amdgcn_global_load_lds((const __attribute__((address_space(1))) void*)g,
                                     (__attribute__((address_space(3))) void*)l, 16, 0, 0);
}

// ---------- cast x fp32 -> fp16 ----------
__global__ __launch_bounds__(256) void k_cast(const float* __restrict__ in,
                                              f16* __restrict__ out, int n4) {
    int i = blockIdx.x * 256 + threadIdx.x;
    if (i < n4) {
        float4 v = ((const float4*)in)[i];
        f16x4 o = { (f16)v.x, (f16)v.y, (f16)v.z, (f16)v.w };
        ((f16x4*)out)[i] = o;
    }
}

// ---------- transpose + cast: dst[n][k] = (f16)src[k][n] ----------
__global__ __launch_bounds__(256) void k_transpose(const float* __restrict__ src,
                                                   f16* __restrict__ dst, int K, int N) {
    __shared__ float tile[32][33];
    int n0 = blockIdx.x * 32, k0 = blockIdx.y * 32;
    int tx = threadIdx.x & 31, ty = threadIdx.x >> 5;  // 32 x 8
#pragma unroll
    for (int j = 0; j < 32; j += 8)
        tile[ty + j][tx] = src[(size_t)(k0 + ty + j) * N + n0 + tx];
    __syncthreads();
#pragma unroll
    for (int j = 0; j < 32; j += 8)
        dst[(size_t)(n0 + ty + j) * K + k0 + tx] = (f16)tile[tx][ty + j];
}

// ---------- xPos tables: cos | sin | scale, each [T][64] fp32 ----------
__global__ __launch_bounds__(256) void k_tables(float* __restrict__ tab) {
    int i = blockIdx.x * 256 + threadIdx.x;  // exactly 131072
    int t = i >> 6, f = i & 63;
    float inv_freq = powf(10000.0f, -(2.0f * f) / 128.0f);
    float ang = (float)t * inv_freq;
    float sv = (2.0f * f + 51.2f) / 179.2f;      // (half_idx + 0.4*HD)/(1.4*HD)
    float pw = ((float)t - 1024.0f) / 512.0f;    // (t - T/2)/SCALE_BASE
    tab[i] = cosf(ang);
    tab[131072 + i] = sinf(ang);
    tab[262144 + i] = powf(sv, pw);
}

// ---------- m97-style GEMM:  C[m][n] = sum_k A[m][k] * B[n][k]  (B pre-transposed) ----------
template <typename OutT>
__global__ __launch_bounds__(256) void k_gemm_bt(const f16* __restrict__ A,
                                                 const f16* __restrict__ B,
                                                 OutT* __restrict__ C, int M, int N, int K) {
    __shared__ f16 As[2][128 * 32];
    __shared__ f16 Bs[2][128 * 32];
    const int m0 = blockIdx.y * 128, n0 = blockIdx.x * 128;
    const int tid = threadIdx.x, lane = tid & 63, w = tid >> 6;
    const int wr = w >> 1, wc = w & 1;
    const int cq = lane & 15, gq = lane >> 4;
    f32x4 acc[4][4] = {};
    const int KT = K >> 5;

    auto stage = [&](int buf, int kt) {
#pragma unroll
        for (int qq = 0; qq < 2; ++qq) {
            int c = w * 128 + qq * 64 + lane;  // chunk id 0..511, 8 halfs each
            const f16* ga = A + (size_t)(m0 + (c >> 2)) * K + kt * 32 + (c & 3) * 8;
            gld_lds16(ga, &As[buf][(w * 128 + qq * 64) * 8]);
            const f16* gb = B + (size_t)(n0 + (c >> 2)) * K + kt * 32 + (c & 3) * 8;
            gld_lds16(gb, &Bs[buf][(w * 128 + qq * 64) * 8]);
        }
    };

    stage(0, 0);
    __syncthreads();
    for (int kt = 0; kt < KT; ++kt) {
        int cur = kt & 1;
        if (kt + 1 < KT) stage(cur ^ 1, kt + 1);
        f16x8 a[4], b[4];
#pragma unroll
        for (int mi = 0; mi < 4; ++mi)
            a[mi] = *(const f16x8*)&As[cur][(wr * 64 + mi * 16 + cq) * 32 + gq * 8];
#pragma unroll
        for (int ni = 0; ni < 4; ++ni)
            b[ni] = *(const f16x8*)&Bs[cur][(wc * 64 + ni * 16 + cq) * 32 + gq * 8];
#pragma unroll
        for (int mi = 0; mi < 4; ++mi)
#pragma unroll
            for (int ni = 0; ni < 4; ++ni)
                acc[mi][ni] = __builtin_amdgcn_mfma_f32_16x16x32_f16(a[mi], b[ni], acc[mi][ni], 0, 0, 0);
        __syncthreads();
    }
#pragma unroll
    for (int mi = 0; mi < 4; ++mi)
#pragma unroll
        for (int ni = 0; ni < 4; ++ni)
#pragma unroll
            for (int i = 0; i < 4; ++i) {
                int row = m0 + wr * 64 + mi * 16 + gq * 4 + i;
                int col = n0 + wc * 64 + ni * 16 + cq;
                C[(size_t)row * N + col] = (OutT)acc[mi][ni][i];
            }
}

// ---------- in-place xPos RoPE on qkv [8192][4096]; Q gets *scale*rsqrt(d), K gets /scale ----------
__global__ __launch_bounds__(256) void k_rope(f16* __restrict__ qkv, const float* __restrict__ tab) {
    int idx = blockIdx.x * 256 + threadIdx.x;
    const int QTOT = NBATCH * T_SEQ * 16 * 64;  // 8,388,608
    int f, col0, bt;
    bool isQ = idx < QTOT;
    if (isQ) {
        f = idx & 63; int hh = (idx >> 6) & 15; bt = idx >> 10;
        col0 = hh * 128 + f;
    } else {
        int j = idx - QTOT;
        f = j & 63; int hh = (j >> 6) & 7; bt = j >> 9;
        col0 = 2048 + hh * 128 + f;
    }
    int t = bt & (T_SEQ - 1);
    float cs = tab[t * 64 + f], sn = tab[131072 + t * 64 + f], sc = tab[262144 + t * 64 + f];
    float mult = isQ ? sc * 0.08838834764831845f : 1.0f / sc;  // fold 1/sqrt(128) into Q
    size_t p = (size_t)bt * 4096 + col0;
    float x1 = (float)qkv[p], x2 = (float)qkv[p + 64];
    qkv[p]      = (f16)((x1 * cs - x2 * sn) * mult);
    qkv[p + 64] = (f16)((x2 * cs + x1 * sn) * mult);
}

// ---------- causal GQA flash attention ----------
// grid: b(4) x h(16) x qtile(16); block 256 = 4 waves, each wave owns 32 q rows.
__global__ __launch_bounds__(256) void k_attn(const f16* __restrict__ qkv, f16* __restrict__ ao) {
    const int bid = blockIdx.x;
    const int qt = bid & 15, h = (bid >> 4) & 15, b = bid >> 8;
    const int kvh = h >> 1;
    const int q0 = qt * 128;
    const int tid = threadIdx.x, lane = tid & 63, w = tid >> 6;
    const int cq = lane & 15, gq = lane >> 4;

    __shared__ f16 Klds[64 * 128];   // XOR-swizzled 16B chunks (pre-swizzled global source)
    __shared__ f16 VT[128 * 72];     // V transposed [d][kr], pad 72 vs conflicts
    __shared__ f16 Pl[128 * 72];     // P [q][kr], pad 72

    // Q fragments held in registers for the whole block
    f16x8 qf[2][4];
#pragma unroll
    for (int mi = 0; mi < 2; ++mi)
#pragma unroll
        for (int kk = 0; kk < 4; ++kk)
            qf[mi][kk] = *(const f16x8*)(qkv + (size_t)(b * T_SEQ + q0 + w * 32 + mi * 16 + cq) * 4096
                                         + h * 128 + kk * 32 + gq * 8);

    f32x4 o[2][8] = {};
    float mrow[2][4], lrow[2][4];
#pragma unroll
    for (int mi = 0; mi < 2; ++mi)
#pragma unroll
        for (int i = 0; i < 4; ++i) { mrow[mi][i] = -1e30f; lrow[mi][i] = 0.0f; }

    const int nkt = 2 * qt + 2;
    for (int kt = 0; kt < nkt; ++kt) {
        const int t0 = b * T_SEQ + kt * 64;
        // stage K [64][128]: linear LDS dest, source chunk pre-swizzled (c^(row&7))
#pragma unroll
        for (int qq = 0; qq < 4; ++qq) {
            int c = w * 256 + qq * 64 + lane;
            int row = c >> 4;
            int chnk = (c & 15) ^ (row & 7);
            gld_lds16(qkv + (size_t)(t0 + row) * 4096 + 2048 + kvh * 128 + chnk * 8,
                      &Klds[(size_t)(w * 256 + qq * 64) * 8]);
        }
        // stage V transposed: lane = kr row, wave w covers d-chunks [4w,4w+4)
#pragma unroll
        for (int i = 0; i < 4; ++i) {
            int dc = w * 4 + i;
            f16x8 vv = *(const f16x8*)(qkv + (size_t)(t0 + lane) * 4096 + 3072 + kvh * 128 + dc * 8);
#pragma unroll
            for (int j = 0; j < 8; ++j)
                VT[(dc * 8 + j) * 72 + lane] = vv[j];
        }
        __syncthreads();

        // S = Q K^T  (per wave: 32 q rows x 64 k cols)
        f32x4 s[2][4] = {};
#pragma unroll
        for (int knb = 0; knb < 4; ++knb) {
            int kr = knb * 16 + cq;
            f16x8 kf[4];
#pragma unroll
            for (int kk = 0; kk < 4; ++kk) {
                int chnk = (kk * 4 + gq) ^ (kr & 7);
                kf[kk] = *(const f16x8*)&Klds[kr * 128 + chnk * 8];
            }
#pragma unroll
            for (int kk = 0; kk < 4; ++kk)
#pragma unroll
                for (int mi = 0; mi < 2; ++mi)
                    s[mi][knb] = __builtin_amdgcn_mfma_f32_16x16x32_f16(qf[mi][kk], kf[kk], s[mi][knb], 0, 0, 0);
        }
        // causal mask (only diagonal-region tiles)
        if (kt >= 2 * qt) {
#pragma unroll
            for (int mi = 0; mi < 2; ++mi)
#pragma unroll
                for (int knb = 0; knb < 4; ++knb) {
                    int kr = kt * 64 + knb * 16 + cq;
#pragma unroll
                    for (int i = 0; i < 4; ++i)
                        if (kr > q0 + w * 32 + mi * 16 + gq * 4 + i) s[mi][knb][i] = -1e30f;
                }
        }
        // wave-parallel online softmax (reduce across the 16-lane col group)
#pragma unroll
        for (int mi = 0; mi < 2; ++mi) {
#pragma unroll
            for (int i = 0; i < 4; ++i) {
                float mx = fmaxf(fmaxf(s[mi][0][i], s[mi][1][i]), fmaxf(s[mi][2][i], s[mi][3][i]));
#pragma unroll
                for (int off = 8; off >= 1; off >>= 1) mx = fmaxf(mx, __shfl_xor(mx, off, 64));
                float mold = mrow[mi][i];
                float mnew = fmaxf(mold, mx);
                float fs = __expf(mold - mnew);
                float ps = 0.0f;
#pragma unroll
                for (int knb = 0; knb < 4; ++knb) {
                    float p = __expf(s[mi][knb][i] - mnew);
                    s[mi][knb][i] = p;
                    ps += p;
                }
#pragma unroll
                for (int off = 8; off >= 1; off >>= 1) ps += __shfl_xor(ps, off, 64);
                mrow[mi][i] = mnew;
                lrow[mi][i] = lrow[mi][i] * fs + ps;
#pragma unroll
                for (int nd = 0; nd < 8; ++nd) o[mi][nd][i] *= fs;
            }
#pragma unroll
            for (int knb = 0; knb < 4; ++knb)
#pragma unroll
                for (int i = 0; i < 4; ++i)
                    Pl[(w * 32 + mi * 16 + gq * 4 + i) * 72 + knb * 16 + cq] = (f16)s[mi][knb][i];
        }
        // PV: P rows are same-wave (DS in-order) -> no barrier needed before reads
#pragma unroll
        for (int kk = 0; kk < 2; ++kk) {
            f16x8 pa[2];
#pragma unroll
            for (int mi = 0; mi < 2; ++mi)
                pa[mi] = *(const f16x8*)&Pl[(w * 32 + mi * 16 + cq) * 72 + kk * 32 + gq * 8];
#pragma unroll
            for (int nd = 0; nd < 8; ++nd) {
                f16x8 vb = *(const f16x8*)&VT[(nd * 16 + cq) * 72 + kk * 32 + gq * 8];
#pragma unroll
                for (int mi = 0; mi < 2; ++mi)
                    o[mi][nd] = __builtin_amdgcn_mfma_f32_16x16x32_f16(pa[mi], vb, o[mi][nd], 0, 0, 0);
            }
        }
        __syncthreads();  // protect K/VT/P from next tile's staging
    }
    // epilogue: O / l -> fp16
#pragma unroll
    for (int mi = 0; mi < 2; ++mi)
#pragma unroll
        for (int i = 0; i < 4; ++i) {
            float inv = 1.0f / lrow[mi][i];
            size_t rowb = (size_t)(b * T_SEQ + q0 + w * 32 + mi * 16 + gq * 4 + i) * 2048 + h * 128;
#pragma unroll
            for (int nd = 0; nd < 8; ++nd)
                ao[rowb + nd * 16 + cq] = (f16)(o[mi][nd][i] * inv);
        }
}

extern "C" void kernel_launch(void* const* d_in, const int* in_sizes, int n_in,
                              void* d_out, int out_size, void* d_ws, size_t ws_size,
                              hipStream_t stream) {
    const float* x  = (const float*)d_in[0];
    const float* Wq = (const float*)d_in[1];
    const float* Wk = (const float*)d_in[2];
    const float* Wv = (const float*)d_in[3];
    const float* Wo = (const float*)d_in[4];
    float* out = (float*)d_out;

    // workspace layout (fp16 elems): xh 16.7M | wqkvT 8.4M | woT 4.2M | qkv 33.5M | tab (f32)
    f16* xh    = (f16*)d_ws;
    f16* wqkvT = xh + (size_t)16777216;
    f16* woT   = wqkvT + (size_t)8388608;
    f16* qkv   = woT + (size_t)4194304;
    float* tab = (float*)(qkv + (size_t)33554432);
    f16* ao = xh;  // alias: xh dead after GEMM1

    k_cast<<<16384, 256, 0, stream>>>(x, xh, 4194304);
    k_transpose<<<dim3(64, 64), 256, 0, stream>>>(Wq, wqkvT, 2048, 2048);
    k_transpose<<<dim3(32, 64), 256, 0, stream>>>(Wk, wqkvT + (size_t)2048 * 2048, 2048, 1024);
    k_transpose<<<dim3(32, 64), 256, 0, stream>>>(Wv, wqkvT + (size_t)3072 * 2048, 2048, 1024);
    k_transpose<<<dim3(64, 64), 256, 0, stream>>>(Wo, woT, 2048, 2048);
    k_tables<<<512, 256, 0, stream>>>(tab);
    // QKV projection: qkv[8192][4096]
    k_gemm_bt<f16><<<dim3(32, 64), 256, 0, stream>>>(xh, wqkvT, qkv, 8192, 4096, 2048);
    k_rope<<<49152, 256, 0, stream>>>(qkv, tab);
    k_attn<<<1024, 256, 0, stream>>>(qkv, ao);
    // output projection -> fp32
    k_gemm_bt<float><<<dim3(16, 64), 256, 0, stream>>>(ao, woT, out, 8192, 2048, 2048);
}

// Round 2
// 607.389 us; speedup vs baseline: 1.3262x; 1.3262x over previous
//
#include <hip/hip_runtime.h>

typedef _Float16 f16;
typedef __attribute__((ext_vector_type(8))) _Float16 f16x8;
typedef __attribute__((ext_vector_type(4))) _Float16 f16x4;
typedef __attribute__((ext_vector_type(4))) float f32x4;

#define T_SEQ 2048
#define NBATCH 4

__device__ __forceinline__ void gld_lds16(const f16* g, f16* l) {
    __builtin_amdgcn_global_load_lds((const __attribute__((address_space(1))) void*)g,
                                     (__attribute__((address_space(3))) void*)l, 16, 0, 0);
}

// ---------- cast x fp32 -> fp16 ----------
__global__ __launch_bounds__(256) void k_cast(const float* __restrict__ in,
                                              f16* __restrict__ out, int n4) {
    int i = blockIdx.x * 256 + threadIdx.x;
    if (i < n4) {
        float4 v = ((const float4*)in)[i];
        f16x4 o = { (f16)v.x, (f16)v.y, (f16)v.z, (f16)v.w };
        ((f16x4*)out)[i] = o;
    }
}

// ---------- transpose + cast: dst[n][k] = (f16)src[k][n] ----------
__global__ __launch_bounds__(256) void k_transpose(const float* __restrict__ src,
                                                   f16* __restrict__ dst, int K, int N) {
    __shared__ float tile[32][33];
    int n0 = blockIdx.x * 32, k0 = blockIdx.y * 32;
    int tx = threadIdx.x & 31, ty = threadIdx.x >> 5;  // 32 x 8
#pragma unroll
    for (int j = 0; j < 32; j += 8)
        tile[ty + j][tx] = src[(size_t)(k0 + ty + j) * N + n0 + tx];
    __syncthreads();
#pragma unroll
    for (int j = 0; j < 32; j += 8)
        dst[(size_t)(n0 + ty + j) * K + k0 + tx] = (f16)tile[tx][ty + j];
}

// ---------- xPos tables: cos | sin | scale, each [T][64] fp32 ----------
__global__ __launch_bounds__(256) void k_tables(float* __restrict__ tab) {
    int i = blockIdx.x * 256 + threadIdx.x;  // exactly 131072
    int t = i >> 6, f = i & 63;
    float inv_freq = powf(10000.0f, -(2.0f * f) / 128.0f);
    float ang = (float)t * inv_freq;
    float sv = (2.0f * f + 51.2f) / 179.2f;      // (half_idx + 0.4*HD)/(1.4*HD)
    float pw = ((float)t - 1024.0f) / 512.0f;    // (t - T/2)/SCALE_BASE
    tab[i] = cosf(ang);
    tab[131072 + i] = sinf(ang);
    tab[262144 + i] = powf(sv, pw);
}

// ---------- m97-style GEMM:  C[m][n] = sum_k A[m][k] * B[n][k]  (B pre-transposed) ----------
template <typename OutT>
__global__ __launch_bounds__(256) void k_gemm_bt(const f16* __restrict__ A,
                                                 const f16* __restrict__ B,
                                                 OutT* __restrict__ C, int M, int N, int K) {
    __shared__ f16 As[2][128 * 32];
    __shared__ f16 Bs[2][128 * 32];
    const int m0 = blockIdx.y * 128, n0 = blockIdx.x * 128;
    const int tid = threadIdx.x, lane = tid & 63, w = tid >> 6;
    const int wr = w >> 1, wc = w & 1;
    const int cq = lane & 15, gq = lane >> 4;
    f32x4 acc[4][4] = {};
    const int KT = K >> 5;

    auto stage = [&](int buf, int kt) {
#pragma unroll
        for (int qq = 0; qq < 2; ++qq) {
            int c = w * 128 + qq * 64 + lane;  // chunk id 0..511, 8 halfs each
            const f16* ga = A + (size_t)(m0 + (c >> 2)) * K + kt * 32 + (c & 3) * 8;
            gld_lds16(ga, &As[buf][(w * 128 + qq * 64) * 8]);
            const f16* gb = B + (size_t)(n0 + (c >> 2)) * K + kt * 32 + (c & 3) * 8;
            gld_lds16(gb, &Bs[buf][(w * 128 + qq * 64) * 8]);
        }
    };

    stage(0, 0);
    __syncthreads();
    for (int kt = 0; kt < KT; ++kt) {
        int cur = kt & 1;
        if (kt + 1 < KT) stage(cur ^ 1, kt + 1);
        f16x8 a[4], b[4];
#pragma unroll
        for (int mi = 0; mi < 4; ++mi)
            a[mi] = *(const f16x8*)&As[cur][(wr * 64 + mi * 16 + cq) * 32 + gq * 8];
#pragma unroll
        for (int ni = 0; ni < 4; ++ni)
            b[ni] = *(const f16x8*)&Bs[cur][(wc * 64 + ni * 16 + cq) * 32 + gq * 8];
#pragma unroll
        for (int mi = 0; mi < 4; ++mi)
#pragma unroll
            for (int ni = 0; ni < 4; ++ni)
                acc[mi][ni] = __builtin_amdgcn_mfma_f32_16x16x32_f16(a[mi], b[ni], acc[mi][ni], 0, 0, 0);
        __syncthreads();
    }
#pragma unroll
    for (int mi = 0; mi < 4; ++mi)
#pragma unroll
        for (int ni = 0; ni < 4; ++ni)
#pragma unroll
            for (int i = 0; i < 4; ++i) {
                int row = m0 + wr * 64 + mi * 16 + gq * 4 + i;
                int col = n0 + wc * 64 + ni * 16 + cq;
                C[(size_t)row * N + col] = (OutT)acc[mi][ni][i];
            }
}

// ---------- in-place xPos RoPE on qkv [8192][4096]; Q gets *scale*rsqrt(d), K gets /scale ----------
__global__ __launch_bounds__(256) void k_rope(f16* __restrict__ qkv, const float* __restrict__ tab) {
    int idx = blockIdx.x * 256 + threadIdx.x;
    const int QTOT = NBATCH * T_SEQ * 16 * 64;  // 8,388,608
    int f, col0, bt;
    bool isQ = idx < QTOT;
    if (isQ) {
        f = idx & 63; int hh = (idx >> 6) & 15; bt = idx >> 10;
        col0 = hh * 128 + f;
    } else {
        int j = idx - QTOT;
        f = j & 63; int hh = (j >> 6) & 7; bt = j >> 9;
        col0 = 2048 + hh * 128 + f;
    }
    int t = bt & (T_SEQ - 1);
    float cs = tab[t * 64 + f], sn = tab[131072 + t * 64 + f], sc = tab[262144 + t * 64 + f];
    float mult = isQ ? sc * 0.08838834764831845f : 1.0f / sc;  // fold 1/sqrt(128) into Q
    size_t p = (size_t)bt * 4096 + col0;
    float x1 = (float)qkv[p], x2 = (float)qkv[p + 64];
    qkv[p]      = (f16)((x1 * cs - x2 * sn) * mult);
    qkv[p + 64] = (f16)((x2 * cs + x1 * sn) * mult);
}

// ---------- causal GQA flash attention, v2 ----------
// grid: 512 = b(4) x h(16) x pair(8); block 256 = 4 waves, each wave owns 32 q rows.
// Each block processes q-tiles (15-pr) then (pr): uniform 34 kv-tile iterations.
// Pipeline: K double-buffered via global_load_lds; V prefetched to regs, written to
// LDS after the top barrier (issue-early / write-late). nkt always even -> buffer
// parity is consistent across the two q-tile halves with no extra barrier.
__global__ __launch_bounds__(256) void k_attn(const f16* __restrict__ qkv, f16* __restrict__ ao) {
    // XCD swizzle: blocks sharing (b,kvh) K/V stream land on the same XCD chunk
    const int bid0 = blockIdx.x;
    const int bid = (bid0 & 7) * 64 + (bid0 >> 3);
    const int pr = bid & 7, h = (bid >> 3) & 15, b = bid >> 7;
    const int kvh = h >> 1;
    const int tid = threadIdx.x, lane = tid & 63, w = tid >> 6;
    const int cq = lane & 15, gq = lane >> 4;

    __shared__ f16 Klds[2][64 * 128];  // XOR-swizzled 16B chunks (pre-swizzled global source)
    __shared__ f16 VT[128 * 72];       // V transposed [d][kr], pad 72
    __shared__ f16 Pl[128 * 72];       // P [q][kr], pad 72

    f16x8 vpre[4];

#pragma unroll 1
    for (int half = 0; half < 2; ++half) {
        const int qt = half ? pr : (15 - pr);
        const int q0 = qt * 128;
        const int nkt = 2 * qt + 2;  // even

        // Q fragments in registers for this q-tile
        f16x8 qf[2][4];
#pragma unroll
        for (int mi = 0; mi < 2; ++mi)
#pragma unroll
            for (int kk = 0; kk < 4; ++kk)
                qf[mi][kk] = *(const f16x8*)(qkv + (size_t)(b * T_SEQ + q0 + w * 32 + mi * 16 + cq) * 4096
                                             + h * 128 + kk * 32 + gq * 8);

        f32x4 o[2][8] = {};
        float mrow[2][4], lrow[2][4];
#pragma unroll
        for (int mi = 0; mi < 2; ++mi)
#pragma unroll
            for (int i = 0; i < 4; ++i) { mrow[mi][i] = -1e30f; lrow[mi][i] = 0.0f; }

        // prologue: stage K(0) into buf0, prefetch V(0) into regs
        {
            const int t0 = b * T_SEQ;
#pragma unroll
            for (int qq = 0; qq < 4; ++qq) {
                int c = w * 256 + qq * 64 + lane;
                int row = c >> 4;
                int chnk = (c & 15) ^ (row & 7);
                gld_lds16(qkv + (size_t)(t0 + row) * 4096 + 2048 + kvh * 128 + chnk * 8,
                          &Klds[0][(size_t)(w * 256 + qq * 64) * 8]);
            }
#pragma unroll
            for (int i = 0; i < 4; ++i)
                vpre[i] = *(const f16x8*)(qkv + (size_t)(t0 + lane) * 4096 + 3072 + kvh * 128 + (w * 4 + i) * 8);
        }

#pragma unroll 1
        for (int kt = 0; kt < nkt; ++kt) {
            const int buf = kt & 1;
            __syncthreads();  // K(kt) staged (vmcnt drained), VT free of last iter's readers

            // write V(kt) from regs to LDS transposed
#pragma unroll
            for (int i = 0; i < 4; ++i) {
                int dc = w * 4 + i;
#pragma unroll
                for (int j = 0; j < 8; ++j)
                    VT[(dc * 8 + j) * 72 + lane] = vpre[i][j];
            }
            // prefetch next tile: K -> LDS buf^1, V -> regs (hidden under QK+softmax)
            if (kt + 1 < nkt) {
                const int t1 = b * T_SEQ + (kt + 1) * 64;
#pragma unroll
                for (int qq = 0; qq < 4; ++qq) {
                    int c = w * 256 + qq * 64 + lane;
                    int row = c >> 4;
                    int chnk = (c & 15) ^ (row & 7);
                    gld_lds16(qkv + (size_t)(t1 + row) * 4096 + 2048 + kvh * 128 + chnk * 8,
                              &Klds[buf ^ 1][(size_t)(w * 256 + qq * 64) * 8]);
                }
#pragma unroll
                for (int i = 0; i < 4; ++i)
                    vpre[i] = *(const f16x8*)(qkv + (size_t)(t1 + lane) * 4096 + 3072 + kvh * 128 + (w * 4 + i) * 8);
            }

            // S = Q K^T  (per wave: 32 q rows x 64 k cols)
            f32x4 s[2][4] = {};
#pragma unroll
            for (int knb = 0; knb < 4; ++knb) {
                int kr = knb * 16 + cq;
                f16x8 kf[4];
#pragma unroll
                for (int kk = 0; kk < 4; ++kk) {
                    int chnk = (kk * 4 + gq) ^ (kr & 7);
                    kf[kk] = *(const f16x8*)&Klds[buf][kr * 128 + chnk * 8];
                }
#pragma unroll
                for (int kk = 0; kk < 4; ++kk)
#pragma unroll
                    for (int mi = 0; mi < 2; ++mi)
                        s[mi][knb] = __builtin_amdgcn_mfma_f32_16x16x32_f16(qf[mi][kk], kf[kk], s[mi][knb], 0, 0, 0);
            }
            // causal mask (only diagonal-region tiles)
            if (kt >= 2 * qt) {
#pragma unroll
                for (int mi = 0; mi < 2; ++mi)
#pragma unroll
                    for (int knb = 0; knb < 4; ++knb) {
                        int kr = kt * 64 + knb * 16 + cq;
#pragma unroll
                        for (int i = 0; i < 4; ++i)
                            if (kr > q0 + w * 32 + mi * 16 + gq * 4 + i) s[mi][knb][i] = -1e30f;
                    }
            }
            // wave-parallel online softmax (reduce across the 16-lane col group)
#pragma unroll
            for (int mi = 0; mi < 2; ++mi) {
#pragma unroll
                for (int i = 0; i < 4; ++i) {
                    float mx = fmaxf(fmaxf(s[mi][0][i], s[mi][1][i]), fmaxf(s[mi][2][i], s[mi][3][i]));
#pragma unroll
                    for (int off = 8; off >= 1; off >>= 1) mx = fmaxf(mx, __shfl_xor(mx, off, 64));
                    float mold = mrow[mi][i];
                    float mnew = fmaxf(mold, mx);
                    float fs = __expf(mold - mnew);
                    float ps = 0.0f;
#pragma unroll
                    for (int knb = 0; knb < 4; ++knb) {
                        float p = __expf(s[mi][knb][i] - mnew);
                        s[mi][knb][i] = p;
                        ps += p;
                    }
#pragma unroll
                    for (int off = 8; off >= 1; off >>= 1) ps += __shfl_xor(ps, off, 64);
                    mrow[mi][i] = mnew;
                    lrow[mi][i] = lrow[mi][i] * fs + ps;
#pragma unroll
                    for (int nd = 0; nd < 8; ++nd) o[mi][nd][i] *= fs;
                }
#pragma unroll
                for (int knb = 0; knb < 4; ++knb)
#pragma unroll
                    for (int i = 0; i < 4; ++i)
                        Pl[(w * 32 + mi * 16 + gq * 4 + i) * 72 + knb * 16 + cq] = (f16)s[mi][knb][i];
            }
            __syncthreads();  // VT(kt) writes complete (cross-wave)

            // PV
#pragma unroll
            for (int kk = 0; kk < 2; ++kk) {
                f16x8 pa[2];
#pragma unroll
                for (int mi = 0; mi < 2; ++mi)
                    pa[mi] = *(const f16x8*)&Pl[(w * 32 + mi * 16 + cq) * 72 + kk * 32 + gq * 8];
#pragma unroll
                for (int nd = 0; nd < 8; ++nd) {
                    f16x8 vb = *(const f16x8*)&VT[(nd * 16 + cq) * 72 + kk * 32 + gq * 8];
#pragma unroll
                    for (int mi = 0; mi < 2; ++mi)
                        o[mi][nd] = __builtin_amdgcn_mfma_f32_16x16x32_f16(pa[mi], vb, o[mi][nd], 0, 0, 0);
                }
            }
        }
        // epilogue: O / l -> fp16
#pragma unroll
        for (int mi = 0; mi < 2; ++mi)
#pragma unroll
            for (int i = 0; i < 4; ++i) {
                float inv = 1.0f / lrow[mi][i];
                size_t rowb = (size_t)(b * T_SEQ + q0 + w * 32 + mi * 16 + gq * 4 + i) * 2048 + h * 128;
#pragma unroll
                for (int nd = 0; nd < 8; ++nd)
                    ao[rowb + nd * 16 + cq] = (f16)(o[mi][nd][i] * inv);
            }
    }
}

extern "C" void kernel_launch(void* const* d_in, const int* in_sizes, int n_in,
                              void* d_out, int out_size, void* d_ws, size_t ws_size,
                              hipStream_t stream) {
    const float* x  = (const float*)d_in[0];
    const float* Wq = (const float*)d_in[1];
    const float* Wk = (const float*)d_in[2];
    const float* Wv = (const float*)d_in[3];
    const float* Wo = (const float*)d_in[4];
    float* out = (float*)d_out;

    // workspace layout (fp16 elems): xh 16.7M | wqkvT 8.4M | woT 4.2M | qkv 33.5M | tab (f32)
    f16* xh    = (f16*)d_ws;
    f16* wqkvT = xh + (size_t)16777216;
    f16* woT   = wqkvT + (size_t)8388608;
    f16* qkv   = woT + (size_t)4194304;
    float* tab = (float*)(qkv + (size_t)33554432);
    f16* ao = xh;  // alias: xh dead after GEMM1

    k_cast<<<16384, 256, 0, stream>>>(x, xh, 4194304);
    k_transpose<<<dim3(64, 64), 256, 0, stream>>>(Wq, wqkvT, 2048, 2048);
    k_transpose<<<dim3(32, 64), 256, 0, stream>>>(Wk, wqkvT + (size_t)2048 * 2048, 2048, 1024);
    k_transpose<<<dim3(32, 64), 256, 0, stream>>>(Wv, wqkvT + (size_t)3072 * 2048, 2048, 1024);
    k_transpose<<<dim3(64, 64), 256, 0, stream>>>(Wo, woT, 2048, 2048);
    k_tables<<<512, 256, 0, stream>>>(tab);
    // QKV projection: qkv[8192][4096]
    k_gemm_bt<f16><<<dim3(32, 64), 256, 0, stream>>>(xh, wqkvT, qkv, 8192, 4096, 2048);
    k_rope<<<49152, 256, 0, stream>>>(qkv, tab);
    k_attn<<<512, 256, 0, stream>>>(qkv, ao);
    // output projection -> fp32
    k_gemm_bt<float><<<dim3(16, 64), 256, 0, stream>>>(ao, woT, out, 8192, 2048, 2048);
}

// Round 5
// 517.847 us; speedup vs baseline: 1.5555x; 1.1729x over previous
//
#include <hip/hip_runtime.h>

typedef _Float16 f16;
typedef __attribute__((ext_vector_type(8))) _Float16 f16x8;
typedef __attribute__((ext_vector_type(4))) _Float16 f16x4;
typedef __attribute__((ext_vector_type(4))) float f32x4;
typedef __attribute__((ext_vector_type(16))) float f32x16;
typedef __attribute__((ext_vector_type(4))) unsigned u32x4;

#define T_SEQ 2048
#define NBATCH 4

__device__ __forceinline__ void gld_lds16(const f16* g, f16* l) {
    __builtin_amdgcn_global_load_lds((const __attribute__((address_space(1))) void*)g,
                                     (__attribute__((address_space(3))) void*)l, 16, 0, 0);
}

__device__ __forceinline__ unsigned pk2(float a, float b) {
    __attribute__((ext_vector_type(2))) __fp16 h = __builtin_amdgcn_cvt_pkrtz(a, b);
    return __builtin_bit_cast(unsigned, h);
}

// ---------- cast x fp32 -> fp16 ----------
__global__ __launch_bounds__(256) void k_cast(const float* __restrict__ in,
                                              f16* __restrict__ out, int n4) {
    int i = blockIdx.x * 256 + threadIdx.x;
    if (i < n4) {
        float4 v = ((const float4*)in)[i];
        f16x4 o = { (f16)v.x, (f16)v.y, (f16)v.z, (f16)v.w };
        ((f16x4*)out)[i] = o;
    }
}

// ---------- transpose + cast: dst[n][k] = (f16)src[k][n] ----------
__global__ __launch_bounds__(256) void k_transpose(const float* __restrict__ src,
                                                   f16* __restrict__ dst, int K, int N) {
    __shared__ float tile[32][33];
    int n0 = blockIdx.x * 32, k0 = blockIdx.y * 32;
    int tx = threadIdx.x & 31, ty = threadIdx.x >> 5;  // 32 x 8
#pragma unroll
    for (int j = 0; j < 32; j += 8)
        tile[ty + j][tx] = src[(size_t)(k0 + ty + j) * N + n0 + tx];
    __syncthreads();
#pragma unroll
    for (int j = 0; j < 32; j += 8)
        dst[(size_t)(n0 + ty + j) * K + k0 + tx] = (f16)tile[tx][ty + j];
}

// ---------- xPos tables: cos | sin | scale, each [T][64] fp32 ----------
__global__ __launch_bounds__(256) void k_tables(float* __restrict__ tab) {
    int i = blockIdx.x * 256 + threadIdx.x;  // exactly 131072
    int t = i >> 6, f = i & 63;
    float inv_freq = powf(10000.0f, -(2.0f * f) / 128.0f);
    float ang = (float)t * inv_freq;
    float sv = (2.0f * f + 51.2f) / 179.2f;      // (half_idx + 0.4*HD)/(1.4*HD)
    float pw = ((float)t - 1024.0f) / 512.0f;    // (t - T/2)/SCALE_BASE
    tab[i] = cosf(ang);
    tab[131072 + i] = sinf(ang);
    tab[262144 + i] = powf(sv, pw);
}

// ---------- m97-style GEMM:  C[m][n] = sum_k A[m][k] * B[n][k]  (B pre-transposed) ----------
template <typename OutT>
__global__ __launch_bounds__(256) void k_gemm_bt(const f16* __restrict__ A,
                                                 const f16* __restrict__ B,
                                                 OutT* __restrict__ C, int M, int N, int K) {
    __shared__ f16 As[2][128 * 32];
    __shared__ f16 Bs[2][128 * 32];
    const int m0 = blockIdx.y * 128, n0 = blockIdx.x * 128;
    const int tid = threadIdx.x, lane = tid & 63, w = tid >> 6;
    const int wr = w >> 1, wc = w & 1;
    const int cq = lane & 15, gq = lane >> 4;
    f32x4 acc[4][4] = {};
    const int KT = K >> 5;

    auto stage = [&](int buf, int kt) {
#pragma unroll
        for (int qq = 0; qq < 2; ++qq) {
            int c = w * 128 + qq * 64 + lane;  // chunk id 0..511, 8 halfs each
            const f16* ga = A + (size_t)(m0 + (c >> 2)) * K + kt * 32 + (c & 3) * 8;
            gld_lds16(ga, &As[buf][(w * 128 + qq * 64) * 8]);
            const f16* gb = B + (size_t)(n0 + (c >> 2)) * K + kt * 32 + (c & 3) * 8;
            gld_lds16(gb, &Bs[buf][(w * 128 + qq * 64) * 8]);
        }
    };

    stage(0, 0);
    __syncthreads();
    for (int kt = 0; kt < KT; ++kt) {
        int cur = kt & 1;
        if (kt + 1 < KT) stage(cur ^ 1, kt + 1);
        f16x8 a[4], b[4];
#pragma unroll
        for (int mi = 0; mi < 4; ++mi)
            a[mi] = *(const f16x8*)&As[cur][(wr * 64 + mi * 16 + cq) * 32 + gq * 8];
#pragma unroll
        for (int ni = 0; ni < 4; ++ni)
            b[ni] = *(const f16x8*)&Bs[cur][(wc * 64 + ni * 16 + cq) * 32 + gq * 8];
#pragma unroll
        for (int mi = 0; mi < 4; ++mi)
#pragma unroll
            for (int ni = 0; ni < 4; ++ni)
                acc[mi][ni] = __builtin_amdgcn_mfma_f32_16x16x32_f16(a[mi], b[ni], acc[mi][ni], 0, 0, 0);
        __syncthreads();
    }
#pragma unroll
    for (int mi = 0; mi < 4; ++mi)
#pragma unroll
        for (int ni = 0; ni < 4; ++ni)
#pragma unroll
            for (int i = 0; i < 4; ++i) {
                int row = m0 + wr * 64 + mi * 16 + gq * 4 + i;
                int col = n0 + wc * 64 + ni * 16 + cq;
                C[(size_t)row * N + col] = (OutT)acc[mi][ni][i];
            }
}

// ---------- in-place xPos RoPE on qkv [8192][4096]; Q gets *scale*rsqrt(d), K gets /scale ----------
__global__ __launch_bounds__(256) void k_rope(f16* __restrict__ qkv, const float* __restrict__ tab) {
    int idx = blockIdx.x * 256 + threadIdx.x;
    const int QTOT = NBATCH * T_SEQ * 16 * 64;  // 8,388,608
    int f, col0, bt;
    bool isQ = idx < QTOT;
    if (isQ) {
        f = idx & 63; int hh = (idx >> 6) & 15; bt = idx >> 10;
        col0 = hh * 128 + f;
    } else {
        int j = idx - QTOT;
        f = j & 63; int hh = (j >> 6) & 7; bt = j >> 9;
        col0 = 2048 + hh * 128 + f;
    }
    int t = bt & (T_SEQ - 1);
    float cs = tab[t * 64 + f], sn = tab[131072 + t * 64 + f], sc = tab[262144 + t * 64 + f];
    float mult = isQ ? sc * 0.08838834764831845f : 1.0f / sc;  // fold 1/sqrt(128) into Q
    size_t p = (size_t)bt * 4096 + col0;
    float x1 = (float)qkv[p], x2 = (float)qkv[p + 64];
    qkv[p]      = (f16)((x1 * cs - x2 * sn) * mult);
    qkv[p + 64] = (f16)((x2 * cs + x1 * sn) * mult);
}

// ---------- causal GQA flash attention, v3b: 32x32 swapped-QK, in-register softmax ----------
// grid 512 = b(4) x h(16) x pair(8); block 256 = 4 waves x 32 q-rows.
// St = mfma_32x32x16(K,Q) -> lane owns full k-slice of P for q = lane&31.
// Softmax fully in-lane + shfl_xor(32) half-combine. P->A-frag via cvt_pkrtz+shfl_xor(32)
// (permlane32_swap removed: return-word order was the prime correctness suspect).
// Ot = mfma(VT,P): lane's output column = its own q. One barrier per kv tile.
__global__ __launch_bounds__(256) void k_attn(const f16* __restrict__ qkv, f16* __restrict__ ao) {
    const int bid0 = blockIdx.x;
    const int bid = (bid0 & 7) * 64 + (bid0 >> 3);  // XCD swizzle
    const int pr = bid & 7, h = (bid >> 3) & 15, b = bid >> 7;
    const int kvh = h >> 1;
    const int tid = threadIdx.x, lane = tid & 63, w = tid >> 6;
    const int l31 = lane & 31, hi = lane >> 5;

    __shared__ f16 Klds[2][64 * 128];   // [k][d], 16B chunks XOR-swizzled by (krow&7)
    __shared__ f16 VT[2][128 * 64];     // [d][k], 16B chunks XOR-swizzled by (d&7)

    f16x8 vpre[4];

#pragma unroll 1
    for (int hf = 0; hf < 2; ++hf) {
        const int qt = hf ? pr : (15 - pr);
        const int q0 = qt * 128;
        const int nkt = 2 * qt + 2;  // even, >= 2
        const int qrow = q0 + w * 32 + l31;

        // Q fragments (B-operand): lane holds Q[q=qrow][d = ds*16 + hi*8 + j]
        f16x8 qf[8];
#pragma unroll
        for (int ds = 0; ds < 8; ++ds)
            qf[ds] = *(const f16x8*)(qkv + (size_t)(b * T_SEQ + qrow) * 4096 + h * 128 + ds * 16 + hi * 8);

        f32x16 Ot[4] = {};
        float mrow = -1e30f, lrow = 0.0f;

        // ---- prologue: K(0)->Klds[0], V(0)->regs ----
        {
            const int t0 = b * T_SEQ;
#pragma unroll
            for (int qq = 0; qq < 4; ++qq) {
                int c = w * 256 + qq * 64 + lane;
                int row = c >> 4;
                int chnk = (c & 15) ^ (row & 7);
                gld_lds16(qkv + (size_t)(t0 + row) * 4096 + 2048 + kvh * 128 + chnk * 8,
                          &Klds[0][(w * 256 + qq * 64) * 8]);
            }
#pragma unroll
            for (int i = 0; i < 4; ++i)
                vpre[i] = *(const f16x8*)(qkv + (size_t)(t0 + lane) * 4096 + 3072 + kvh * 128 + (w * 4 + i) * 8);
        }
        __syncthreads();  // K(0) staged, vpre=V(0) arrived
        // VT[0] <- V(0)
#pragma unroll
        for (int i = 0; i < 4; ++i) {
            int dcb = (w * 4 + i) * 8;
#pragma unroll
            for (int j = 0; j < 8; ++j) {
                int d = dcb + j;
                VT[0][d * 64 + (((lane >> 3) ^ (d & 7)) << 3) + (lane & 7)] = vpre[i][j];
            }
        }
        {
            const int t1 = b * T_SEQ + 64;
#pragma unroll
            for (int i = 0; i < 4; ++i)
                vpre[i] = *(const f16x8*)(qkv + (size_t)(t1 + lane) * 4096 + 3072 + kvh * 128 + (w * 4 + i) * 8);
        }
        __syncthreads();  // VT[0] visible

#pragma unroll 1
        for (int kt = 0; kt < nkt; ++kt) {
            const int kb = kt & 1;
            // issue-early: VT[kb^1] <- vpre (=V(kt+1)); stage K(kt+1); vpre <- V(kt+2)
            if (kt + 1 < nkt) {
#pragma unroll
                for (int i = 0; i < 4; ++i) {
                    int dcb = (w * 4 + i) * 8;
#pragma unroll
                    for (int j = 0; j < 8; ++j) {
                        int d = dcb + j;
                        VT[kb ^ 1][d * 64 + (((lane >> 3) ^ (d & 7)) << 3) + (lane & 7)] = vpre[i][j];
                    }
                }
                const int t1 = b * T_SEQ + (kt + 1) * 64;
#pragma unroll
                for (int qq = 0; qq < 4; ++qq) {
                    int c = w * 256 + qq * 64 + lane;
                    int row = c >> 4;
                    int chnk = (c & 15) ^ (row & 7);
                    gld_lds16(qkv + (size_t)(t1 + row) * 4096 + 2048 + kvh * 128 + chnk * 8,
                              &Klds[kb ^ 1][(w * 256 + qq * 64) * 8]);
                }
                if (kt + 2 < nkt) {
                    const int t2 = b * T_SEQ + (kt + 2) * 64;
#pragma unroll
                    for (int i = 0; i < 4; ++i)
                        vpre[i] = *(const f16x8*)(qkv + (size_t)(t2 + lane) * 4096 + 3072 + kvh * 128 + (w * 4 + i) * 8);
                }
            }

            // fully-masked tile for waves 0,1 at the odd diagonal tile: skip compute
            if (!(kt == 2 * qt + 1 && w < 2)) {
                // ---- St = K Q^T (swapped): St[k][q], lane: q=l31, k rows in regs ----
                f32x16 St0 = {}, St1 = {};
                __builtin_amdgcn_s_setprio(1);
#pragma unroll
                for (int ds = 0; ds < 8; ++ds) {
                    int chnk = ((2 * ds + hi) ^ (l31 & 7)) << 3;
                    f16x8 k0 = *(const f16x8*)&Klds[kb][l31 * 128 + chnk];
                    f16x8 k1 = *(const f16x8*)&Klds[kb][(32 + l31) * 128 + chnk];
                    St0 = __builtin_amdgcn_mfma_f32_32x32x16_f16(k0, qf[ds], St0, 0, 0, 0);
                    St1 = __builtin_amdgcn_mfma_f32_32x32x16_f16(k1, qf[ds], St1, 0, 0, 0);
                }
                __builtin_amdgcn_s_setprio(0);

                // ---- causal mask ----
                if (kt >= 2 * qt) {
                    int kbase = kt * 64;
#pragma unroll
                    for (int r = 0; r < 16; ++r) {
                        int krel = (r & 3) + 8 * (r >> 2) + 4 * hi;
                        if (kbase + krel > qrow) St0[r] = -1e30f;
                        if (kbase + 32 + krel > qrow) St1[r] = -1e30f;
                    }
                }

                // ---- in-register online softmax (half-combine via shfl_xor 32) ----
                float tm[16];
#pragma unroll
                for (int r = 0; r < 16; ++r) tm[r] = fmaxf(St0[r], St1[r]);
#pragma unroll
                for (int d = 8; d >= 1; d >>= 1)
#pragma unroll
                    for (int r = 0; r < 8; ++r)
                        if (r < d) tm[r] = fmaxf(tm[r], tm[r + d]);
                float tmax = tm[0];
                float mtile = fmaxf(tmax, __shfl_xor(tmax, 32, 64));

                if (!__all((mtile - mrow) <= 8.0f)) {  // T13 defer-max
                    float mnew = fmaxf(mrow, mtile);
                    float fs = __expf(mrow - mnew);
                    mrow = mnew;
                    lrow *= fs;
#pragma unroll
                    for (int dblk = 0; dblk < 4; ++dblk)
#pragma unroll
                        for (int e = 0; e < 16; ++e) Ot[dblk][e] *= fs;
                }
#pragma unroll
                for (int r = 0; r < 16; ++r) {
                    St0[r] = __expf(St0[r] - mrow);
                    St1[r] = __expf(St1[r] - mrow);
                }
                float ts[16];
#pragma unroll
                for (int r = 0; r < 16; ++r) ts[r] = St0[r] + St1[r];
#pragma unroll
                for (int d = 8; d >= 1; d >>= 1)
#pragma unroll
                    for (int r = 0; r < 8; ++r)
                        if (r < d) ts[r] += ts[r + d];
                float tsum = ts[0];
                lrow += tsum + __shfl_xor(tsum, 32, 64);

                // ---- pack P into A/B-frags (cvt_pkrtz + shfl_xor 32) + PV ----
                // St reg r of block (o>>2) holds kv = 32*(o>>2)+8*(o&3)+4*hi+(r&3).
                // mfma step s needs slot (hi',j) -> kv = 16s + 8hi' + j.
                // hi=0 lane: {x1,x2,sx1,sx2} = kv 16s+0..7; hi=1: {sy1,sy2,y1,y2} = kv 16s+8..15.
#define PV_P(o, pos) ((o) < 4 ? St0[((o) & 3) * 4 + (pos)] : St1[((o) & 3) * 4 + (pos)])
#pragma unroll
                for (int s = 0; s < 4; ++s) {
                    unsigned x1 = pk2(PV_P(2 * s, 0), PV_P(2 * s, 1));
                    unsigned x2 = pk2(PV_P(2 * s, 2), PV_P(2 * s, 3));
                    unsigned y1 = pk2(PV_P(2 * s + 1, 0), PV_P(2 * s + 1, 1));
                    unsigned y2 = pk2(PV_P(2 * s + 1, 2), PV_P(2 * s + 1, 3));
                    unsigned sx1 = __shfl_xor(x1, 32, 64);
                    unsigned sx2 = __shfl_xor(x2, 32, 64);
                    unsigned sy1 = __shfl_xor(y1, 32, 64);
                    unsigned sy2 = __shfl_xor(y2, 32, 64);
                    u32x4 pw;
                    pw[0] = hi ? sy1 : x1;
                    pw[1] = hi ? sy2 : x2;
                    pw[2] = hi ? y1 : sx1;
                    pw[3] = hi ? y2 : sx2;
                    f16x8 pa = __builtin_bit_cast(f16x8, pw);
                    __builtin_amdgcn_s_setprio(1);
#pragma unroll
                    for (int dblk = 0; dblk < 4; ++dblk) {
                        f16x8 vb = *(const f16x8*)&VT[kb][(32 * dblk + l31) * 64 + (((2 * s + hi) ^ (l31 & 7)) << 3)];
                        Ot[dblk] = __builtin_amdgcn_mfma_f32_32x32x16_f16(vb, pa, Ot[dblk], 0, 0, 0);
                    }
                    __builtin_amdgcn_s_setprio(0);
                }
#undef PV_P
            }
            __syncthreads();  // all reads of buf kb done; K(kt+1) staged; VT[kb^1] visible
        }

        // ---- epilogue: lane writes its q-row, d = 32*dblk + 8*rg + 4*hi + e ----
        {
            float inv = 1.0f / lrow;
            size_t rowb = (size_t)(b * T_SEQ + qrow) * 2048 + h * 128;
#pragma unroll
            for (int dblk = 0; dblk < 4; ++dblk)
#pragma unroll
                for (int rg = 0; rg < 4; ++rg) {
                    f16x4 o4 = { (f16)(Ot[dblk][rg * 4 + 0] * inv), (f16)(Ot[dblk][rg * 4 + 1] * inv),
                                 (f16)(Ot[dblk][rg * 4 + 2] * inv), (f16)(Ot[dblk][rg * 4 + 3] * inv) };
                    *(f16x4*)(ao + rowb + dblk * 32 + rg * 8 + hi * 4) = o4;
                }
        }
    }
}

extern "C" void kernel_launch(void* const* d_in, const int* in_sizes, int n_in,
                              void* d_out, int out_size, void* d_ws, size_t ws_size,
                              hipStream_t stream) {
    const float* x  = (const float*)d_in[0];
    const float* Wq = (const float*)d_in[1];
    const float* Wk = (const float*)d_in[2];
    const float* Wv = (const float*)d_in[3];
    const float* Wo = (const float*)d_in[4];
    float* out = (float*)d_out;

    // workspace layout (fp16 elems): xh 16.7M | wqkvT 8.4M | woT 4.2M | qkv 33.5M | tab (f32)
    f16* xh    = (f16*)d_ws;
    f16* wqkvT = xh + (size_t)16777216;
    f16* woT   = wqkvT + (size_t)8388608;
    f16* qkv   = woT + (size_t)4194304;
    float* tab = (float*)(qkv + (size_t)33554432);
    f16* ao = xh;  // alias: xh dead after GEMM1

    k_cast<<<16384, 256, 0, stream>>>(x, xh, 4194304);
    k_transpose<<<dim3(64, 64), 256, 0, stream>>>(Wq, wqkvT, 2048, 2048);
    k_transpose<<<dim3(32, 64), 256, 0, stream>>>(Wk, wqkvT + (size_t)2048 * 2048, 2048, 1024);
    k_transpose<<<dim3(32, 64), 256, 0, stream>>>(Wv, wqkvT + (size_t)3072 * 2048, 2048, 1024);
    k_transpose<<<dim3(64, 64), 256, 0, stream>>>(Wo, woT, 2048, 2048);
    k_tables<<<512, 256, 0, stream>>>(tab);
    // QKV projection: qkv[8192][4096]
    k_gemm_bt<f16><<<dim3(32, 64), 256, 0, stream>>>(xh, wqkvT, qkv, 8192, 4096, 2048);
    k_rope<<<49152, 256, 0, stream>>>(qkv, tab);
    k_attn<<<512, 256, 0, stream>>>(qkv, ao);
    // output projection -> fp32
    k_gemm_bt<float><<<dim3(16, 64), 256, 0, stream>>>(ao, woT, out, 8192, 2048, 2048);
}

// Round 6
// 459.564 us; speedup vs baseline: 1.7528x; 1.1268x over previous
//
#include <hip/hip_runtime.h>

typedef _Float16 f16;
typedef __attribute__((ext_vector_type(8))) _Float16 f16x8;
typedef __attribute__((ext_vector_type(4))) _Float16 f16x4;
typedef __attribute__((ext_vector_type(4))) float f32x4;
typedef __attribute__((ext_vector_type(16))) float f32x16;
typedef __attribute__((ext_vector_type(4))) unsigned u32x4;

#define T_SEQ 2048
#define NBATCH 4

__device__ __forceinline__ void gld_lds16(const f16* g, f16* l) {
    __builtin_amdgcn_global_load_lds((const __attribute__((address_space(1))) void*)g,
                                     (__attribute__((address_space(3))) void*)l, 16, 0, 0);
}

__device__ __forceinline__ unsigned pk2(float a, float b) {
    __attribute__((ext_vector_type(2))) __fp16 h = __builtin_amdgcn_cvt_pkrtz(a, b);
    return __builtin_bit_cast(unsigned, h);
}

// ---------- cast x fp32 -> fp16 ----------
__global__ __launch_bounds__(256) void k_cast(const float* __restrict__ in,
                                              f16* __restrict__ out, int n4) {
    int i = blockIdx.x * 256 + threadIdx.x;
    if (i < n4) {
        float4 v = ((const float4*)in)[i];
        f16x4 o = { (f16)v.x, (f16)v.y, (f16)v.z, (f16)v.w };
        ((f16x4*)out)[i] = o;
    }
}

// ---------- transpose + cast: dst[n][k] = (f16)src[k][n] ----------
__global__ __launch_bounds__(256) void k_transpose(const float* __restrict__ src,
                                                   f16* __restrict__ dst, int K, int N) {
    __shared__ float tile[32][33];
    int n0 = blockIdx.x * 32, k0 = blockIdx.y * 32;
    int tx = threadIdx.x & 31, ty = threadIdx.x >> 5;  // 32 x 8
#pragma unroll
    for (int j = 0; j < 32; j += 8)
        tile[ty + j][tx] = src[(size_t)(k0 + ty + j) * N + n0 + tx];
    __syncthreads();
#pragma unroll
    for (int j = 0; j < 32; j += 8)
        dst[(size_t)(n0 + ty + j) * K + k0 + tx] = (f16)tile[tx][ty + j];
}

// ---------- xPos tables: cos | sin | scale, each [T][64] fp32 ----------
__global__ __launch_bounds__(256) void k_tables(float* __restrict__ tab) {
    int i = blockIdx.x * 256 + threadIdx.x;  // exactly 131072
    int t = i >> 6, f = i & 63;
    float inv_freq = powf(10000.0f, -(2.0f * f) / 128.0f);
    float ang = (float)t * inv_freq;
    float sv = (2.0f * f + 51.2f) / 179.2f;      // (half_idx + 0.4*HD)/(1.4*HD)
    float pw = ((float)t - 1024.0f) / 512.0f;    // (t - T/2)/SCALE_BASE
    tab[i] = cosf(ang);
    tab[131072 + i] = sinf(ang);
    tab[262144 + i] = powf(sv, pw);
}

// ---------- 256x256 8-phase GEMM: C[m][n] = sum_k A[m][k]*B[n][k] (both row-K) ----------
// 8 waves = (wr4 in 0..3: 32-row band) x (wc2 in 0..1: 64-col band) inside a 128x128
// C-quadrant; phases = quadrants Q(0,0),Q(0,1),Q(1,1),Q(1,0). BK=64.
// LDS ring: As[2][256][64], Bs[2][256][64] (128 KiB). Halves die early (Alo,Blo @p1,
// Bhi @p2, Ahi @p3); each phase stages one half-tile via global_load_lds into a dead
// slot: p1 -> Ahi(t+1) [other buf], p2/p3/p4 -> Alo/Blo/Bhi(t+2) [same buf].
// One counted vmcnt(6) per K-tile (leaves t+2's 3 half-tiles = 6 loads in flight).
// T2 XOR swizzle chunk^=(row&7), pre-swizzled global source (involution both sides).
template <typename OutT>
__global__ __launch_bounds__(512, 1) void k_gemm256(const f16* __restrict__ A,
                                                    const f16* __restrict__ B,
                                                    OutT* __restrict__ C, int M, int N, int K) {
    extern __shared__ char smem[];
    f16* As = (f16*)smem;            // [2][256][64]
    f16* Bs = (f16*)smem + 32768;    // [2][256][64]
    const int tid = threadIdx.x, lane = tid & 63, w = tid >> 6;
    const int wr4 = w >> 1, wc2 = w & 1;
    const int cq = lane & 15, gq = lane >> 4;
    const int nbx = gridDim.x;
    const int nwg = nbx * gridDim.y;
    const int bid0 = blockIdx.y * nbx + blockIdx.x;
    const int bid = (bid0 & 7) * (nwg >> 3) + (bid0 >> 3);  // XCD swizzle (nwg%8==0)
    const int m0 = (bid / nbx) * 256, n0 = (bid % nbx) * 256;
    const int KT = K >> 6;

    f32x4 acc[2][2][2][4] = {};
    f16x8 aL[2][2], aH[2][2], bL[4][2], bH[4][2];

    // stage one half-tile (128 rows x 64 k) of operand into LDS; 2 gld_lds per thread
    auto stageA = [&](int buf, int half, int t) {
#pragma unroll
        for (int r = 0; r < 2; ++r) {
            int cb = r * 512 + w * 64;
            int c = cb + lane;
            int row = c >> 3, cc = c & 7;
            gld_lds16(A + (size_t)(m0 + half * 128 + row) * K + t * 64 + ((cc ^ (row & 7)) * 8),
                      As + buf * 16384 + half * 8192 + cb * 8);
        }
    };
    auto stageB = [&](int buf, int half, int t) {
#pragma unroll
        for (int r = 0; r < 2; ++r) {
            int cb = r * 512 + w * 64;
            int c = cb + lane;
            int row = c >> 3, cc = c & 7;
            gld_lds16(B + (size_t)(n0 + half * 128 + row) * K + t * 64 + ((cc ^ (row & 7)) * 8),
                      Bs + buf * 16384 + half * 8192 + cb * 8);
        }
    };
    auto rdA = [&](int buf, int qr, f16x8 a[2][2]) {
#pragma unroll
        for (int mi = 0; mi < 2; ++mi)
#pragma unroll
            for (int ks = 0; ks < 2; ++ks) {
                int R = qr * 128 + wr4 * 32 + mi * 16 + cq;
                a[mi][ks] = *(const f16x8*)&As[buf * 16384 + R * 64 + (((ks * 4 + gq) ^ (cq & 7)) * 8)];
            }
    };
    auto rdB = [&](int buf, int qc, f16x8 b[4][2]) {
#pragma unroll
        for (int ni = 0; ni < 4; ++ni)
#pragma unroll
            for (int ks = 0; ks < 2; ++ks) {
                int R = qc * 128 + wc2 * 64 + ni * 16 + cq;
                b[ni][ks] = *(const f16x8*)&Bs[buf * 16384 + R * 64 + (((ks * 4 + gq) ^ (cq & 7)) * 8)];
            }
    };

    // prologue: tile0 {Alo,Blo,Bhi,Ahi} + tile1 {Alo,Blo,Bhi} = 14 loads; drain tile0
    stageA(0, 0, 0); stageB(0, 0, 0); stageB(0, 1, 0); stageA(0, 1, 0);
    if (KT > 1) { stageA(1, 0, 1); stageB(1, 0, 1); stageB(1, 1, 1); }
    asm volatile("s_waitcnt vmcnt(6)");
    __builtin_amdgcn_s_barrier();

#pragma unroll 1
    for (int t = 0; t < KT; ++t) {
        const int buf = t & 1;
        // ---- p1: Q(0,0) ----
        rdA(buf, 0, aL); rdB(buf, 0, bL);
        if (t + 1 < KT) stageA(buf ^ 1, 1, t + 1);  // Ahi(t+1)
        __builtin_amdgcn_s_barrier();
        asm volatile("s_waitcnt lgkmcnt(0)");
        __builtin_amdgcn_sched_barrier(0);
        __builtin_amdgcn_s_setprio(1);
#pragma unroll
        for (int mi = 0; mi < 2; ++mi)
#pragma unroll
            for (int ni = 0; ni < 4; ++ni)
#pragma unroll
                for (int ks = 0; ks < 2; ++ks)
                    acc[0][0][mi][ni] = __builtin_amdgcn_mfma_f32_16x16x32_f16(aL[mi][ks], bL[ni][ks], acc[0][0][mi][ni], 0, 0, 0);
        __builtin_amdgcn_s_setprio(0);
        __builtin_amdgcn_s_barrier();
        // ---- p2: Q(0,1) ----
        rdB(buf, 1, bH);
        if (t + 2 < KT) stageA(buf, 0, t + 2);  // Alo(t+2) over dead Alo(t)
        __builtin_amdgcn_s_barrier();
        asm volatile("s_waitcnt lgkmcnt(0)");
        __builtin_amdgcn_sched_barrier(0);
        __builtin_amdgcn_s_setprio(1);
#pragma unroll
        for (int mi = 0; mi < 2; ++mi)
#pragma unroll
            for (int ni = 0; ni < 4; ++ni)
#pragma unroll
                for (int ks = 0; ks < 2; ++ks)
                    acc[0][1][mi][ni] = __builtin_amdgcn_mfma_f32_16x16x32_f16(aL[mi][ks], bH[ni][ks], acc[0][1][mi][ni], 0, 0, 0);
        __builtin_amdgcn_s_setprio(0);
        __builtin_amdgcn_s_barrier();
        // ---- p3: Q(1,1) ----
        rdA(buf, 1, aH);
        if (t + 2 < KT) stageB(buf, 0, t + 2);  // Blo(t+2) over dead Blo(t)
        __builtin_amdgcn_s_barrier();
        asm volatile("s_waitcnt lgkmcnt(0)");
        __builtin_amdgcn_sched_barrier(0);
        __builtin_amdgcn_s_setprio(1);
#pragma unroll
        for (int mi = 0; mi < 2; ++mi)
#pragma unroll
            for (int ni = 0; ni < 4; ++ni)
#pragma unroll
                for (int ks = 0; ks < 2; ++ks)
                    acc[1][1][mi][ni] = __builtin_amdgcn_mfma_f32_16x16x32_f16(aH[mi][ks], bH[ni][ks], acc[1][1][mi][ni], 0, 0, 0);
        __builtin_amdgcn_s_setprio(0);
        __builtin_amdgcn_s_barrier();
        // ---- p4: Q(1,0) ---- (no LDS reads; frags in regs)
        if (t + 2 < KT) stageB(buf, 1, t + 2);  // Bhi(t+2) over dead Bhi(t)
        __builtin_amdgcn_s_barrier();
        __builtin_amdgcn_sched_barrier(0);
        __builtin_amdgcn_s_setprio(1);
#pragma unroll
        for (int mi = 0; mi < 2; ++mi)
#pragma unroll
            for (int ni = 0; ni < 4; ++ni)
#pragma unroll
                for (int ks = 0; ks < 2; ++ks)
                    acc[1][0][mi][ni] = __builtin_amdgcn_mfma_f32_16x16x32_f16(aH[mi][ks], bL[ni][ks], acc[1][0][mi][ni], 0, 0, 0);
        __builtin_amdgcn_s_setprio(0);
        // counted drain: all of t+1 arrives; t+2's 3 half-tiles (6 loads) stay in flight
        if (t + 2 < KT) asm volatile("s_waitcnt vmcnt(6)");
        else            asm volatile("s_waitcnt vmcnt(0)");
        __builtin_amdgcn_s_barrier();
    }

    // epilogue
#pragma unroll
    for (int qr = 0; qr < 2; ++qr)
#pragma unroll
        for (int qc = 0; qc < 2; ++qc)
#pragma unroll
            for (int mi = 0; mi < 2; ++mi)
#pragma unroll
                for (int ni = 0; ni < 4; ++ni)
#pragma unroll
                    for (int i = 0; i < 4; ++i) {
                        int row = m0 + qr * 128 + wr4 * 32 + mi * 16 + gq * 4 + i;
                        int col = n0 + qc * 128 + wc2 * 64 + ni * 16 + cq;
                        C[(size_t)row * N + col] = (OutT)acc[qr][qc][mi][ni][i];
                    }
}

// ---------- in-place xPos RoPE on qkv [8192][4096]; Q gets *scale*rsqrt(d), K gets /scale ----------
__global__ __launch_bounds__(256) void k_rope(f16* __restrict__ qkv, const float* __restrict__ tab) {
    int idx = blockIdx.x * 256 + threadIdx.x;
    const int QTOT = NBATCH * T_SEQ * 16 * 64;  // 8,388,608
    int f, col0, bt;
    bool isQ = idx < QTOT;
    if (isQ) {
        f = idx & 63; int hh = (idx >> 6) & 15; bt = idx >> 10;
        col0 = hh * 128 + f;
    } else {
        int j = idx - QTOT;
        f = j & 63; int hh = (j >> 6) & 7; bt = j >> 9;
        col0 = 2048 + hh * 128 + f;
    }
    int t = bt & (T_SEQ - 1);
    float cs = tab[t * 64 + f], sn = tab[131072 + t * 64 + f], sc = tab[262144 + t * 64 + f];
    float mult = isQ ? sc * 0.08838834764831845f : 1.0f / sc;  // fold 1/sqrt(128) into Q
    size_t p = (size_t)bt * 4096 + col0;
    float x1 = (float)qkv[p], x2 = (float)qkv[p + 64];
    qkv[p]      = (f16)((x1 * cs - x2 * sn) * mult);
    qkv[p + 64] = (f16)((x2 * cs + x1 * sn) * mult);
}

// ---------- causal GQA flash attention, v3b: 32x32 swapped-QK, in-register softmax ----------
__global__ __launch_bounds__(256) void k_attn(const f16* __restrict__ qkv, f16* __restrict__ ao) {
    const int bid0 = blockIdx.x;
    const int bid = (bid0 & 7) * 64 + (bid0 >> 3);  // XCD swizzle
    const int pr = bid & 7, h = (bid >> 3) & 15, b = bid >> 7;
    const int kvh = h >> 1;
    const int tid = threadIdx.x, lane = tid & 63, w = tid >> 6;
    const int l31 = lane & 31, hi = lane >> 5;

    __shared__ f16 Klds[2][64 * 128];   // [k][d], 16B chunks XOR-swizzled by (krow&7)
    __shared__ f16 VT[2][128 * 64];     // [d][k], 16B chunks XOR-swizzled by (d&7)

    f16x8 vpre[4];

#pragma unroll 1
    for (int hf = 0; hf < 2; ++hf) {
        const int qt = hf ? pr : (15 - pr);
        const int q0 = qt * 128;
        const int nkt = 2 * qt + 2;  // even, >= 2
        const int qrow = q0 + w * 32 + l31;

        f16x8 qf[8];
#pragma unroll
        for (int ds = 0; ds < 8; ++ds)
            qf[ds] = *(const f16x8*)(qkv + (size_t)(b * T_SEQ + qrow) * 4096 + h * 128 + ds * 16 + hi * 8);

        f32x16 Ot[4] = {};
        float mrow = -1e30f, lrow = 0.0f;

        {
            const int t0 = b * T_SEQ;
#pragma unroll
            for (int qq = 0; qq < 4; ++qq) {
                int c = w * 256 + qq * 64 + lane;
                int row = c >> 4;
                int chnk = (c & 15) ^ (row & 7);
                gld_lds16(qkv + (size_t)(t0 + row) * 4096 + 2048 + kvh * 128 + chnk * 8,
                          &Klds[0][(w * 256 + qq * 64) * 8]);
            }
#pragma unroll
            for (int i = 0; i < 4; ++i)
                vpre[i] = *(const f16x8*)(qkv + (size_t)(t0 + lane) * 4096 + 3072 + kvh * 128 + (w * 4 + i) * 8);
        }
        __syncthreads();
#pragma unroll
        for (int i = 0; i < 4; ++i) {
            int dcb = (w * 4 + i) * 8;
#pragma unroll
            for (int j = 0; j < 8; ++j) {
                int d = dcb + j;
                VT[0][d * 64 + (((lane >> 3) ^ (d & 7)) << 3) + (lane & 7)] = vpre[i][j];
            }
        }
        {
            const int t1 = b * T_SEQ + 64;
#pragma unroll
            for (int i = 0; i < 4; ++i)
                vpre[i] = *(const f16x8*)(qkv + (size_t)(t1 + lane) * 4096 + 3072 + kvh * 128 + (w * 4 + i) * 8);
        }
        __syncthreads();

#pragma unroll 1
        for (int kt = 0; kt < nkt; ++kt) {
            const int kb = kt & 1;
            if (kt + 1 < nkt) {
#pragma unroll
                for (int i = 0; i < 4; ++i) {
                    int dcb = (w * 4 + i) * 8;
#pragma unroll
                    for (int j = 0; j < 8; ++j) {
                        int d = dcb + j;
                        VT[kb ^ 1][d * 64 + (((lane >> 3) ^ (d & 7)) << 3) + (lane & 7)] = vpre[i][j];
                    }
                }
                const int t1 = b * T_SEQ + (kt + 1) * 64;
#pragma unroll
                for (int qq = 0; qq < 4; ++qq) {
                    int c = w * 256 + qq * 64 + lane;
                    int row = c >> 4;
                    int chnk = (c & 15) ^ (row & 7);
                    gld_lds16(qkv + (size_t)(t1 + row) * 4096 + 2048 + kvh * 128 + chnk * 8,
                              &Klds[kb ^ 1][(w * 256 + qq * 64) * 8]);
                }
                if (kt + 2 < nkt) {
                    const int t2 = b * T_SEQ + (kt + 2) * 64;
#pragma unroll
                    for (int i = 0; i < 4; ++i)
                        vpre[i] = *(const f16x8*)(qkv + (size_t)(t2 + lane) * 4096 + 3072 + kvh * 128 + (w * 4 + i) * 8);
                }
            }

            if (!(kt == 2 * qt + 1 && w < 2)) {
                f32x16 St0 = {}, St1 = {};
                __builtin_amdgcn_s_setprio(1);
#pragma unroll
                for (int ds = 0; ds < 8; ++ds) {
                    int chnk = ((2 * ds + hi) ^ (l31 & 7)) << 3;
                    f16x8 k0 = *(const f16x8*)&Klds[kb][l31 * 128 + chnk];
                    f16x8 k1 = *(const f16x8*)&Klds[kb][(32 + l31) * 128 + chnk];
                    St0 = __builtin_amdgcn_mfma_f32_32x32x16_f16(k0, qf[ds], St0, 0, 0, 0);
                    St1 = __builtin_amdgcn_mfma_f32_32x32x16_f16(k1, qf[ds], St1, 0, 0, 0);
                }
                __builtin_amdgcn_s_setprio(0);

                if (kt >= 2 * qt) {
                    int kbase = kt * 64;
#pragma unroll
                    for (int r = 0; r < 16; ++r) {
                        int krel = (r & 3) + 8 * (r >> 2) + 4 * hi;
                        if (kbase + krel > qrow) St0[r] = -1e30f;
                        if (kbase + 32 + krel > qrow) St1[r] = -1e30f;
                    }
                }

                float tm[16];
#pragma unroll
                for (int r = 0; r < 16; ++r) tm[r] = fmaxf(St0[r], St1[r]);
#pragma unroll
                for (int d = 8; d >= 1; d >>= 1)
#pragma unroll
                    for (int r = 0; r < 8; ++r)
                        if (r < d) tm[r] = fmaxf(tm[r], tm[r + d]);
                float tmax = tm[0];
                float mtile = fmaxf(tmax, __shfl_xor(tmax, 32, 64));

                if (!__all((mtile - mrow) <= 8.0f)) {
                    float mnew = fmaxf(mrow, mtile);
                    float fs = __expf(mrow - mnew);
                    mrow = mnew;
                    lrow *= fs;
#pragma unroll
                    for (int dblk = 0; dblk < 4; ++dblk)
#pragma unroll
                        for (int e = 0; e < 16; ++e) Ot[dblk][e] *= fs;
                }
#pragma unroll
                for (int r = 0; r < 16; ++r) {
                    St0[r] = __expf(St0[r] - mrow);
                    St1[r] = __expf(St1[r] - mrow);
                }
                float ts[16];
#pragma unroll
                for (int r = 0; r < 16; ++r) ts[r] = St0[r] + St1[r];
#pragma unroll
                for (int d = 8; d >= 1; d >>= 1)
#pragma unroll
                    for (int r = 0; r < 8; ++r)
                        if (r < d) ts[r] += ts[r + d];
                float tsum = ts[0];
                lrow += tsum + __shfl_xor(tsum, 32, 64);

#define PV_P(o, pos) ((o) < 4 ? St0[((o) & 3) * 4 + (pos)] : St1[((o) & 3) * 4 + (pos)])
#pragma unroll
                for (int s = 0; s < 4; ++s) {
                    unsigned x1 = pk2(PV_P(2 * s, 0), PV_P(2 * s, 1));
                    unsigned x2 = pk2(PV_P(2 * s, 2), PV_P(2 * s, 3));
                    unsigned y1 = pk2(PV_P(2 * s + 1, 0), PV_P(2 * s + 1, 1));
                    unsigned y2 = pk2(PV_P(2 * s + 1, 2), PV_P(2 * s + 1, 3));
                    unsigned sx1 = __shfl_xor(x1, 32, 64);
                    unsigned sx2 = __shfl_xor(x2, 32, 64);
                    unsigned sy1 = __shfl_xor(y1, 32, 64);
                    unsigned sy2 = __shfl_xor(y2, 32, 64);
                    u32x4 pw;
                    pw[0] = hi ? sy1 : x1;
                    pw[1] = hi ? sy2 : x2;
                    pw[2] = hi ? y1 : sx1;
                    pw[3] = hi ? y2 : sx2;
                    f16x8 pa = __builtin_bit_cast(f16x8, pw);
                    __builtin_amdgcn_s_setprio(1);
#pragma unroll
                    for (int dblk = 0; dblk < 4; ++dblk) {
                        f16x8 vb = *(const f16x8*)&VT[kb][(32 * dblk + l31) * 64 + (((2 * s + hi) ^ (l31 & 7)) << 3)];
                        Ot[dblk] = __builtin_amdgcn_mfma_f32_32x32x16_f16(vb, pa, Ot[dblk], 0, 0, 0);
                    }
                    __builtin_amdgcn_s_setprio(0);
                }
#undef PV_P
            }
            __syncthreads();
        }

        {
            float inv = 1.0f / lrow;
            size_t rowb = (size_t)(b * T_SEQ + qrow) * 2048 + h * 128;
#pragma unroll
            for (int dblk = 0; dblk < 4; ++dblk)
#pragma unroll
                for (int rg = 0; rg < 4; ++rg) {
                    f16x4 o4 = { (f16)(Ot[dblk][rg * 4 + 0] * inv), (f16)(Ot[dblk][rg * 4 + 1] * inv),
                                 (f16)(Ot[dblk][rg * 4 + 2] * inv), (f16)(Ot[dblk][rg * 4 + 3] * inv) };
                    *(f16x4*)(ao + rowb + dblk * 32 + rg * 8 + hi * 4) = o4;
                }
        }
    }
}

extern "C" void kernel_launch(void* const* d_in, const int* in_sizes, int n_in,
                              void* d_out, int out_size, void* d_ws, size_t ws_size,
                              hipStream_t stream) {
    const float* x  = (const float*)d_in[0];
    const float* Wq = (const float*)d_in[1];
    const float* Wk = (const float*)d_in[2];
    const float* Wv = (const float*)d_in[3];
    const float* Wo = (const float*)d_in[4];
    float* out = (float*)d_out;

    // workspace layout (fp16 elems): xh 16.7M | wqkvT 8.4M | woT 4.2M | qkv 33.5M | tab (f32)
    f16* xh    = (f16*)d_ws;
    f16* wqkvT = xh + (size_t)16777216;
    f16* woT   = wqkvT + (size_t)8388608;
    f16* qkv   = woT + (size_t)4194304;
    float* tab = (float*)(qkv + (size_t)33554432);
    f16* ao = xh;  // alias: xh dead after GEMM1

    hipFuncSetAttribute(reinterpret_cast<const void*>(&k_gemm256<f16>),
                        hipFuncAttributeMaxDynamicSharedMemorySize, 131072);
    hipFuncSetAttribute(reinterpret_cast<const void*>(&k_gemm256<float>),
                        hipFuncAttributeMaxDynamicSharedMemorySize, 131072);

    k_cast<<<16384, 256, 0, stream>>>(x, xh, 4194304);
    k_transpose<<<dim3(64, 64), 256, 0, stream>>>(Wq, wqkvT, 2048, 2048);
    k_transpose<<<dim3(32, 64), 256, 0, stream>>>(Wk, wqkvT + (size_t)2048 * 2048, 2048, 1024);
    k_transpose<<<dim3(32, 64), 256, 0, stream>>>(Wv, wqkvT + (size_t)3072 * 2048, 2048, 1024);
    k_transpose<<<dim3(64, 64), 256, 0, stream>>>(Wo, woT, 2048, 2048);
    k_tables<<<512, 256, 0, stream>>>(tab);
    // QKV projection: qkv[8192][4096]
    k_gemm256<f16><<<dim3(16, 32), 512, 131072, stream>>>(xh, wqkvT, qkv, 8192, 4096, 2048);
    k_rope<<<49152, 256, 0, stream>>>(qkv, tab);
    k_attn<<<512, 256, 0, stream>>>(qkv, ao);
    // output projection -> fp32
    k_gemm256<float><<<dim3(8, 32), 512, 131072, stream>>>(ao, woT, out, 8192, 2048, 2048);
}

// Round 7
// 453.451 us; speedup vs baseline: 1.7764x; 1.0135x over previous
//
#include <hip/hip_runtime.h>

typedef _Float16 f16;
typedef __attribute__((ext_vector_type(8))) _Float16 f16x8;
typedef __attribute__((ext_vector_type(4))) _Float16 f16x4;
typedef __attribute__((ext_vector_type(4))) float f32x4;
typedef __attribute__((ext_vector_type(16))) float f32x16;
typedef __attribute__((ext_vector_type(4))) unsigned u32x4;

#define T_SEQ 2048
#define NBATCH 4

__device__ __forceinline__ void gld_lds16(const f16* g, f16* l) {
    __builtin_amdgcn_global_load_lds((const __attribute__((address_space(1))) void*)g,
                                     (__attribute__((address_space(3))) void*)l, 16, 0, 0);
}

__device__ __forceinline__ unsigned pk2(float a, float b) {
    __attribute__((ext_vector_type(2))) __fp16 h = __builtin_amdgcn_cvt_pkrtz(a, b);
    return __builtin_bit_cast(unsigned, h);
}

// ---------- cast x fp32 -> fp16 ----------
__global__ __launch_bounds__(256) void k_cast(const float* __restrict__ in,
                                              f16* __restrict__ out, int n4) {
    int i = blockIdx.x * 256 + threadIdx.x;
    if (i < n4) {
        float4 v = ((const float4*)in)[i];
        f16x4 o = { (f16)v.x, (f16)v.y, (f16)v.z, (f16)v.w };
        ((f16x4*)out)[i] = o;
    }
}

// ---------- transpose + cast: dst[n][k] = (f16)src[k][n] ----------
__global__ __launch_bounds__(256) void k_transpose(const float* __restrict__ src,
                                                   f16* __restrict__ dst, int K, int N) {
    __shared__ float tile[32][33];
    int n0 = blockIdx.x * 32, k0 = blockIdx.y * 32;
    int tx = threadIdx.x & 31, ty = threadIdx.x >> 5;  // 32 x 8
#pragma unroll
    for (int j = 0; j < 32; j += 8)
        tile[ty + j][tx] = src[(size_t)(k0 + ty + j) * N + n0 + tx];
    __syncthreads();
#pragma unroll
    for (int j = 0; j < 32; j += 8)
        dst[(size_t)(n0 + ty + j) * K + k0 + tx] = (f16)tile[tx][ty + j];
}

// ---------- xPos tables: cos | sin | scale, each [T][64] fp32 ----------
__global__ __launch_bounds__(256) void k_tables(float* __restrict__ tab) {
    int i = blockIdx.x * 256 + threadIdx.x;  // exactly 131072
    int t = i >> 6, f = i & 63;
    float inv_freq = powf(10000.0f, -(2.0f * f) / 128.0f);
    float ang = (float)t * inv_freq;
    float sv = (2.0f * f + 51.2f) / 179.2f;      // (half_idx + 0.4*HD)/(1.4*HD)
    float pw = ((float)t - 1024.0f) / 512.0f;    // (t - T/2)/SCALE_BASE
    tab[i] = cosf(ang);
    tab[131072 + i] = sinf(ang);
    tab[262144 + i] = powf(sv, pw);
}

// ---------- V blocked-transpose for attention ----------
// vtg unit c (16B) of tile (bk,kt):  kchunk=c>>7, d=c&127; content =
// V[b][k=kt*64+kchunk*8+j][kvh][d]  -> linear write, coalesced read from qkv.
__global__ __launch_bounds__(256) void k_vtrans(const f16* __restrict__ qkv, f16* __restrict__ vtg) {
    const int kt = blockIdx.x, bk = blockIdx.y;
    const int b = bk >> 3, kvh = bk & 7;
    const int tid = threadIdx.x;
    __shared__ f16 tile[64][132];
#pragma unroll
    for (int p = 0; p < 4; ++p) {
        int idx = p * 256 + tid;
        int r = idx >> 4, dc = (idx & 15) * 8;
        f16x8 v = *(const f16x8*)(qkv + (size_t)(b * T_SEQ + kt * 64 + r) * 4096 + 3072 + kvh * 128 + dc);
#pragma unroll
        for (int j = 0; j < 8; ++j) tile[r][dc + j] = v[j];
    }
    __syncthreads();
    f16* outb = vtg + (size_t)(bk * 32 + kt) * 8192;
#pragma unroll
    for (int p = 0; p < 4; ++p) {
        int c = p * 256 + tid;
        int kchunk = c >> 7, d = c & 127;
        f16x8 o;
#pragma unroll
        for (int j = 0; j < 8; ++j) o[j] = tile[kchunk * 8 + j][d];
        *(f16x8*)(outb + (size_t)c * 8) = o;
    }
}

// ---------- 256x256 8-phase GEMM: C[m][n] = sum_k A[m][k]*B[n][k] (both row-K) ----------
template <typename OutT>
__global__ __launch_bounds__(512, 1) void k_gemm256(const f16* __restrict__ A,
                                                    const f16* __restrict__ B,
                                                    OutT* __restrict__ C, int M, int N, int K) {
    extern __shared__ char smem[];
    f16* As = (f16*)smem;            // [2][256][64]
    f16* Bs = (f16*)smem + 32768;    // [2][256][64]
    const int tid = threadIdx.x, lane = tid & 63, w = tid >> 6;
    const int wr4 = w >> 1, wc2 = w & 1;
    const int cq = lane & 15, gq = lane >> 4;
    const int nbx = gridDim.x;
    const int nwg = nbx * gridDim.y;
    const int bid0 = blockIdx.y * nbx + blockIdx.x;
    const int bid = (bid0 & 7) * (nwg >> 3) + (bid0 >> 3);  // XCD swizzle (nwg%8==0)
    const int m0 = (bid / nbx) * 256, n0 = (bid % nbx) * 256;
    const int KT = K >> 6;

    f32x4 acc[2][2][2][4] = {};
    f16x8 aL[2][2], aH[2][2], bL[4][2], bH[4][2];

    auto stageA = [&](int buf, int half, int t) {
#pragma unroll
        for (int r = 0; r < 2; ++r) {
            int cb = r * 512 + w * 64;
            int c = cb + lane;
            int row = c >> 3, cc = c & 7;
            gld_lds16(A + (size_t)(m0 + half * 128 + row) * K + t * 64 + ((cc ^ (row & 7)) * 8),
                      As + buf * 16384 + half * 8192 + cb * 8);
        }
    };
    auto stageB = [&](int buf, int half, int t) {
#pragma unroll
        for (int r = 0; r < 2; ++r) {
            int cb = r * 512 + w * 64;
            int c = cb + lane;
            int row = c >> 3, cc = c & 7;
            gld_lds16(B + (size_t)(n0 + half * 128 + row) * K + t * 64 + ((cc ^ (row & 7)) * 8),
                      Bs + buf * 16384 + half * 8192 + cb * 8);
        }
    };
    auto rdA = [&](int buf, int qr, f16x8 a[2][2]) {
#pragma unroll
        for (int mi = 0; mi < 2; ++mi)
#pragma unroll
            for (int ks = 0; ks < 2; ++ks) {
                int R = qr * 128 + wr4 * 32 + mi * 16 + cq;
                a[mi][ks] = *(const f16x8*)&As[buf * 16384 + R * 64 + (((ks * 4 + gq) ^ (cq & 7)) * 8)];
            }
    };
    auto rdB = [&](int buf, int qc, f16x8 b[4][2]) {
#pragma unroll
        for (int ni = 0; ni < 4; ++ni)
#pragma unroll
            for (int ks = 0; ks < 2; ++ks) {
                int R = qc * 128 + wc2 * 64 + ni * 16 + cq;
                b[ni][ks] = *(const f16x8*)&Bs[buf * 16384 + R * 64 + (((ks * 4 + gq) ^ (cq & 7)) * 8)];
            }
    };

    stageA(0, 0, 0); stageB(0, 0, 0); stageB(0, 1, 0); stageA(0, 1, 0);
    if (KT > 1) { stageA(1, 0, 1); stageB(1, 0, 1); stageB(1, 1, 1); }
    asm volatile("s_waitcnt vmcnt(6)");
    __builtin_amdgcn_s_barrier();

#pragma unroll 1
    for (int t = 0; t < KT; ++t) {
        const int buf = t & 1;
        // ---- p1: Q(0,0) ----
        rdA(buf, 0, aL); rdB(buf, 0, bL);
        if (t + 1 < KT) stageA(buf ^ 1, 1, t + 1);  // Ahi(t+1)
        __builtin_amdgcn_s_barrier();
        asm volatile("s_waitcnt lgkmcnt(0)");
        __builtin_amdgcn_sched_barrier(0);
        __builtin_amdgcn_s_setprio(1);
#pragma unroll
        for (int mi = 0; mi < 2; ++mi)
#pragma unroll
            for (int ni = 0; ni < 4; ++ni)
#pragma unroll
                for (int ks = 0; ks < 2; ++ks)
                    acc[0][0][mi][ni] = __builtin_amdgcn_mfma_f32_16x16x32_f16(aL[mi][ks], bL[ni][ks], acc[0][0][mi][ni], 0, 0, 0);
        __builtin_amdgcn_s_setprio(0);
        __builtin_amdgcn_s_barrier();
        // ---- p2: Q(0,1) ----
        rdB(buf, 1, bH);
        if (t + 2 < KT) stageA(buf, 0, t + 2);
        __builtin_amdgcn_s_barrier();
        asm volatile("s_waitcnt lgkmcnt(0)");
        __builtin_amdgcn_sched_barrier(0);
        __builtin_amdgcn_s_setprio(1);
#pragma unroll
        for (int mi = 0; mi < 2; ++mi)
#pragma unroll
            for (int ni = 0; ni < 4; ++ni)
#pragma unroll
                for (int ks = 0; ks < 2; ++ks)
                    acc[0][1][mi][ni] = __builtin_amdgcn_mfma_f32_16x16x32_f16(aL[mi][ks], bH[ni][ks], acc[0][1][mi][ni], 0, 0, 0);
        __builtin_amdgcn_s_setprio(0);
        __builtin_amdgcn_s_barrier();
        // ---- p3: Q(1,1) ----
        rdA(buf, 1, aH);
        if (t + 2 < KT) stageB(buf, 0, t + 2);
        __builtin_amdgcn_s_barrier();
        asm volatile("s_waitcnt lgkmcnt(0)");
        __builtin_amdgcn_sched_barrier(0);
        __builtin_amdgcn_s_setprio(1);
#pragma unroll
        for (int mi = 0; mi < 2; ++mi)
#pragma unroll
            for (int ni = 0; ni < 4; ++ni)
#pragma unroll
                for (int ks = 0; ks < 2; ++ks)
                    acc[1][1][mi][ni] = __builtin_amdgcn_mfma_f32_16x16x32_f16(aH[mi][ks], bH[ni][ks], acc[1][1][mi][ni], 0, 0, 0);
        __builtin_amdgcn_s_setprio(0);
        __builtin_amdgcn_s_barrier();
        // ---- p4: Q(1,0) ----
        if (t + 2 < KT) stageB(buf, 1, t + 2);
        __builtin_amdgcn_s_barrier();
        __builtin_amdgcn_sched_barrier(0);
        __builtin_amdgcn_s_setprio(1);
#pragma unroll
        for (int mi = 0; mi < 2; ++mi)
#pragma unroll
            for (int ni = 0; ni < 4; ++ni)
#pragma unroll
                for (int ks = 0; ks < 2; ++ks)
                    acc[1][0][mi][ni] = __builtin_amdgcn_mfma_f32_16x16x32_f16(aH[mi][ks], bL[ni][ks], acc[1][0][mi][ni], 0, 0, 0);
        __builtin_amdgcn_s_setprio(0);
        if (t + 2 < KT) asm volatile("s_waitcnt vmcnt(6)");
        else            asm volatile("s_waitcnt vmcnt(0)");
        __builtin_amdgcn_s_barrier();
    }

#pragma unroll
    for (int qr = 0; qr < 2; ++qr)
#pragma unroll
        for (int qc = 0; qc < 2; ++qc)
#pragma unroll
            for (int mi = 0; mi < 2; ++mi)
#pragma unroll
                for (int ni = 0; ni < 4; ++ni)
#pragma unroll
                    for (int i = 0; i < 4; ++i) {
                        int row = m0 + qr * 128 + wr4 * 32 + mi * 16 + gq * 4 + i;
                        int col = n0 + qc * 128 + wc2 * 64 + ni * 16 + cq;
                        C[(size_t)row * N + col] = (OutT)acc[qr][qc][mi][ni][i];
                    }
}

// ---------- in-place xPos RoPE on qkv [8192][4096]; Q gets *scale*rsqrt(d), K gets /scale ----------
__global__ __launch_bounds__(256) void k_rope(f16* __restrict__ qkv, const float* __restrict__ tab) {
    int idx = blockIdx.x * 256 + threadIdx.x;
    const int QTOT = NBATCH * T_SEQ * 16 * 64;  // 8,388,608
    int f, col0, bt;
    bool isQ = idx < QTOT;
    if (isQ) {
        f = idx & 63; int hh = (idx >> 6) & 15; bt = idx >> 10;
        col0 = hh * 128 + f;
    } else {
        int j = idx - QTOT;
        f = j & 63; int hh = (j >> 6) & 7; bt = j >> 9;
        col0 = 2048 + hh * 128 + f;
    }
    int t = bt & (T_SEQ - 1);
    float cs = tab[t * 64 + f], sn = tab[131072 + t * 64 + f], sc = tab[262144 + t * 64 + f];
    float mult = isQ ? sc * 0.08838834764831845f : 1.0f / sc;  // fold 1/sqrt(128) into Q
    size_t p = (size_t)bt * 4096 + col0;
    float x1 = (float)qkv[p], x2 = (float)qkv[p + 64];
    qkv[p]      = (f16)((x1 * cs - x2 * sn) * mult);
    qkv[p + 64] = (f16)((x2 * cs + x1 * sn) * mult);
}

// ---------- causal GQA flash attention, v4: conflict-free layouts, no V round-trip ----------
// K LDS [row][slot], slot s of row r holds K-chunk s^(r&15) (full 16-chunk involution:
// 2-way max on reads, staged via pre-swizzled global source). V staged from vtg blocked
// layout: LDS chunk id = kchunk*128 + d -> PV reads are stride-1 b128 (conflict-free).
// One barrier per kv tile; K+V both double-buffered via global_load_lds only.
__global__ __launch_bounds__(256) void k_attn(const f16* __restrict__ qkv,
                                              const f16* __restrict__ vtg,
                                              f16* __restrict__ ao) {
    const int bid0 = blockIdx.x;
    const int bid = (bid0 & 7) * 64 + (bid0 >> 3);  // XCD swizzle
    const int pr = bid & 7, h = (bid >> 3) & 15, b = bid >> 7;
    const int kvh = h >> 1, bk = b * 8 + kvh;
    const int tid = threadIdx.x, lane = tid & 63, w = tid >> 6;
    const int l31 = lane & 31, hi = lane >> 5;

    __shared__ f16 Klds[2][64 * 128];
    __shared__ f16 Vlds[2][8 * 128 * 8];

    const f16* kbase = qkv + (size_t)b * T_SEQ * 4096 + 2048 + kvh * 128;
    const f16* vbase = vtg + (size_t)bk * 32 * 8192;

    auto stage = [&](int buf, int kt) {
#pragma unroll
        for (int qq = 0; qq < 4; ++qq) {
            int c = w * 256 + qq * 64 + lane;
            int row = c >> 4;
            int ch = (c & 15) ^ (row & 15);
            gld_lds16(kbase + (size_t)(kt * 64 + row) * 4096 + ch * 8,
                      &Klds[buf][(w * 256 + qq * 64) * 8]);
        }
#pragma unroll
        for (int qq = 0; qq < 4; ++qq) {
            int c = w * 256 + qq * 64 + lane;
            gld_lds16(vbase + ((size_t)kt * 1024 + c) * 8,
                      &Vlds[buf][(w * 256 + qq * 64) * 8]);
        }
    };

#pragma unroll 1
    for (int hf = 0; hf < 2; ++hf) {
        const int qt = hf ? pr : (15 - pr);
        const int q0 = qt * 128;
        const int nkt = 2 * qt + 2;  // even, >= 2
        const int qrow = q0 + w * 32 + l31;

        f16x8 qf[8];
#pragma unroll
        for (int ds = 0; ds < 8; ++ds)
            qf[ds] = *(const f16x8*)(qkv + (size_t)(b * T_SEQ + qrow) * 4096 + h * 128 + ds * 16 + hi * 8);

        f32x16 Ot[4] = {};
        float mrow = -1e30f, lrow = 0.0f;

        stage(0, 0);
        __syncthreads();

#pragma unroll 1
        for (int kt = 0; kt < nkt; ++kt) {
            const int kb = kt & 1;
            if (kt + 1 < nkt) stage(kb ^ 1, kt + 1);

            if (!(kt == 2 * qt + 1 && w < 2)) {
                // ---- St = K Q^T (swapped): lane q = l31, k rows in regs ----
                f32x16 St0 = {}, St1 = {};
                __builtin_amdgcn_s_setprio(1);
#pragma unroll
                for (int ds = 0; ds < 8; ++ds) {
                    int slot = (((2 * ds + hi) ^ (l31 & 15)) << 3);
                    f16x8 k0 = *(const f16x8*)&Klds[kb][l31 * 128 + slot];
                    f16x8 k1 = *(const f16x8*)&Klds[kb][(32 + l31) * 128 + slot];
                    St0 = __builtin_amdgcn_mfma_f32_32x32x16_f16(k0, qf[ds], St0, 0, 0, 0);
                    St1 = __builtin_amdgcn_mfma_f32_32x32x16_f16(k1, qf[ds], St1, 0, 0, 0);
                }
                __builtin_amdgcn_s_setprio(0);

                // ---- causal mask ----
                if (kt >= 2 * qt) {
                    int kbase2 = kt * 64;
#pragma unroll
                    for (int r = 0; r < 16; ++r) {
                        int krel = (r & 3) + 8 * (r >> 2) + 4 * hi;
                        if (kbase2 + krel > qrow) St0[r] = -1e30f;
                        if (kbase2 + 32 + krel > qrow) St1[r] = -1e30f;
                    }
                }

                // ---- in-register online softmax ----
                float tm[16];
#pragma unroll
                for (int r = 0; r < 16; ++r) tm[r] = fmaxf(St0[r], St1[r]);
#pragma unroll
                for (int d = 8; d >= 1; d >>= 1)
#pragma unroll
                    for (int r = 0; r < 8; ++r)
                        if (r < d) tm[r] = fmaxf(tm[r], tm[r + d]);
                float tmax = tm[0];
                float mtile = fmaxf(tmax, __shfl_xor(tmax, 32, 64));

                if (!__all((mtile - mrow) <= 8.0f)) {  // T13 defer-max
                    float mnew = fmaxf(mrow, mtile);
                    float fs = __expf(mrow - mnew);
                    mrow = mnew;
                    lrow *= fs;
#pragma unroll
                    for (int dblk = 0; dblk < 4; ++dblk)
#pragma unroll
                        for (int e = 0; e < 16; ++e) Ot[dblk][e] *= fs;
                }
#pragma unroll
                for (int r = 0; r < 16; ++r) {
                    St0[r] = __expf(St0[r] - mrow);
                    St1[r] = __expf(St1[r] - mrow);
                }
                float ts[16];
#pragma unroll
                for (int r = 0; r < 16; ++r) ts[r] = St0[r] + St1[r];
#pragma unroll
                for (int d = 8; d >= 1; d >>= 1)
#pragma unroll
                    for (int r = 0; r < 8; ++r)
                        if (r < d) ts[r] += ts[r + d];
                float tsum = ts[0];
                lrow += tsum + __shfl_xor(tsum, 32, 64);

                // ---- pack P (cvt_pkrtz + shfl_xor 32) + PV ----
#define PV_P(o, pos) ((o) < 4 ? St0[((o) & 3) * 4 + (pos)] : St1[((o) & 3) * 4 + (pos)])
#pragma unroll
                for (int s = 0; s < 4; ++s) {
                    unsigned x1 = pk2(PV_P(2 * s, 0), PV_P(2 * s, 1));
                    unsigned x2 = pk2(PV_P(2 * s, 2), PV_P(2 * s, 3));
                    unsigned y1 = pk2(PV_P(2 * s + 1, 0), PV_P(2 * s + 1, 1));
                    unsigned y2 = pk2(PV_P(2 * s + 1, 2), PV_P(2 * s + 1, 3));
                    unsigned sx1 = __shfl_xor(x1, 32, 64);
                    unsigned sx2 = __shfl_xor(x2, 32, 64);
                    unsigned sy1 = __shfl_xor(y1, 32, 64);
                    unsigned sy2 = __shfl_xor(y2, 32, 64);
                    u32x4 pw;
                    pw[0] = hi ? sy1 : x1;
                    pw[1] = hi ? sy2 : x2;
                    pw[2] = hi ? y1 : sx1;
                    pw[3] = hi ? y2 : sx2;
                    f16x8 pa = __builtin_bit_cast(f16x8, pw);
                    __builtin_amdgcn_s_setprio(1);
#pragma unroll
                    for (int dblk = 0; dblk < 4; ++dblk) {
                        f16x8 vb = *(const f16x8*)&Vlds[kb][(((2 * s + hi) << 7) + 32 * dblk + l31) << 3];
                        Ot[dblk] = __builtin_amdgcn_mfma_f32_32x32x16_f16(vb, pa, Ot[dblk], 0, 0, 0);
                    }
                    __builtin_amdgcn_s_setprio(0);
                }
#undef PV_P
            }
            __syncthreads();  // buf kb readers done; K/V(kt+1) staged (vmcnt drained)
        }

        // ---- epilogue ----
        {
            float inv = 1.0f / lrow;
            size_t rowb = (size_t)(b * T_SEQ + qrow) * 2048 + h * 128;
#pragma unroll
            for (int dblk = 0; dblk < 4; ++dblk)
#pragma unroll
                for (int rg = 0; rg < 4; ++rg) {
                    f16x4 o4 = { (f16)(Ot[dblk][rg * 4 + 0] * inv), (f16)(Ot[dblk][rg * 4 + 1] * inv),
                                 (f16)(Ot[dblk][rg * 4 + 2] * inv), (f16)(Ot[dblk][rg * 4 + 3] * inv) };
                    *(f16x4*)(ao + rowb + dblk * 32 + rg * 8 + hi * 4) = o4;
                }
        }
    }
}

extern "C" void kernel_launch(void* const* d_in, const int* in_sizes, int n_in,
                              void* d_out, int out_size, void* d_ws, size_t ws_size,
                              hipStream_t stream) {
    const float* x  = (const float*)d_in[0];
    const float* Wq = (const float*)d_in[1];
    const float* Wk = (const float*)d_in[2];
    const float* Wv = (const float*)d_in[3];
    const float* Wo = (const float*)d_in[4];
    float* out = (float*)d_out;

    // workspace (fp16 elems): xh 16.7M | wqkvT 8.4M | woT 4.2M | qkv 33.5M | tab (f32)
    f16* xh    = (f16*)d_ws;
    f16* wqkvT = xh + (size_t)16777216;
    f16* woT   = wqkvT + (size_t)8388608;
    f16* qkv   = woT + (size_t)4194304;
    float* tab = (float*)(qkv + (size_t)33554432);
    f16* ao  = xh;     // alias: xh dead after GEMM1
    f16* vtg = wqkvT;  // alias: wqkvT dead after GEMM1 (8.4M f16 = exact fit)

    hipFuncSetAttribute(reinterpret_cast<const void*>(&k_gemm256<f16>),
                        hipFuncAttributeMaxDynamicSharedMemorySize, 131072);
    hipFuncSetAttribute(reinterpret_cast<const void*>(&k_gemm256<float>),
                        hipFuncAttributeMaxDynamicSharedMemorySize, 131072);

    k_cast<<<16384, 256, 0, stream>>>(x, xh, 4194304);
    k_transpose<<<dim3(64, 64), 256, 0, stream>>>(Wq, wqkvT, 2048, 2048);
    k_transpose<<<dim3(32, 64), 256, 0, stream>>>(Wk, wqkvT + (size_t)2048 * 2048, 2048, 1024);
    k_transpose<<<dim3(32, 64), 256, 0, stream>>>(Wv, wqkvT + (size_t)3072 * 2048, 2048, 1024);
    k_transpose<<<dim3(64, 64), 256, 0, stream>>>(Wo, woT, 2048, 2048);
    k_tables<<<512, 256, 0, stream>>>(tab);
    // QKV projection: qkv[8192][4096]
    k_gemm256<f16><<<dim3(16, 32), 512, 131072, stream>>>(xh, wqkvT, qkv, 8192, 4096, 2048);
    k_vtrans<<<dim3(32, 32), 256, 0, stream>>>(qkv, vtg);
    k_rope<<<49152, 256, 0, stream>>>(qkv, tab);
    k_attn<<<512, 256, 0, stream>>>(qkv, vtg, ao);
    // output projection -> fp32
    k_gemm256<float><<<dim3(8, 32), 512, 131072, stream>>>(ao, woT, out, 8192, 2048, 2048);
}

// Round 8
// 383.205 us; speedup vs baseline: 2.1020x; 1.1833x over previous
//
#include <hip/hip_runtime.h>

typedef _Float16 f16;
typedef __attribute__((ext_vector_type(8))) _Float16 f16x8;
typedef __attribute__((ext_vector_type(4))) _Float16 f16x4;
typedef __attribute__((ext_vector_type(4))) float f32x4;
typedef __attribute__((ext_vector_type(16))) float f32x16;
typedef __attribute__((ext_vector_type(4))) unsigned u32x4;

#define T_SEQ 2048
#define NBATCH 4

__device__ __forceinline__ void gld_lds16(const f16* g, f16* l) {
    __builtin_amdgcn_global_load_lds((const __attribute__((address_space(1))) void*)g,
                                     (__attribute__((address_space(3))) void*)l, 16, 0, 0);
}

__device__ __forceinline__ unsigned pk2(float a, float b) {
    __attribute__((ext_vector_type(2))) __fp16 h = __builtin_amdgcn_cvt_pkrtz(a, b);
    return __builtin_bit_cast(unsigned, h);
}

// ---------- fused prep: cast x | transpose Wq/Wk/Wv/Wo | xPos tables ----------
// block ranges: [0,16384) cast; [16384,20480) WqT; [20480,22528) WkT;
// [22528,24576) WvT; [24576,28672) WoT; [28672,29184) tables.
__global__ __launch_bounds__(256) void k_prep(const float* __restrict__ x,
                                              const float* __restrict__ Wq,
                                              const float* __restrict__ Wk,
                                              const float* __restrict__ Wv,
                                              const float* __restrict__ Wo,
                                              f16* __restrict__ xh,
                                              f16* __restrict__ wqkvT,
                                              f16* __restrict__ woT,
                                              float* __restrict__ tab) {
    __shared__ float tile[32][33];
    int bidx = blockIdx.x;
    if (bidx < 16384) {  // cast x fp32 -> fp16 (float4 per thread)
        int i = bidx * 256 + threadIdx.x;
        float4 v = ((const float4*)x)[i];
        f16x4 o = { (f16)v.x, (f16)v.y, (f16)v.z, (f16)v.w };
        ((f16x4*)xh)[i] = o;
        return;
    }
    bidx -= 16384;
    if (bidx >= 12288) {  // tables: cos | sin | scale, each [T][64] fp32
        int i = (bidx - 12288) * 256 + threadIdx.x;  // 131072 total
        int t = i >> 6, f = i & 63;
        float inv_freq = powf(10000.0f, -(2.0f * f) / 128.0f);
        float ang = (float)t * inv_freq;
        float sv = (2.0f * f + 51.2f) / 179.2f;
        float pw = ((float)t - 1024.0f) / 512.0f;
        tab[i] = cosf(ang);
        tab[131072 + i] = sinf(ang);
        tab[262144 + i] = powf(sv, pw);
        return;
    }
    // weight transpose+cast: dst[n][k] = (f16)src[k][n], K=2048
    const float* src; f16* dst; int N, bx, by;
    if (bidx < 4096)      { src = Wq; dst = wqkvT;                      N = 2048; bx = bidx & 63; by = bidx >> 6; }
    else if (bidx < 6144) { src = Wk; dst = wqkvT + (size_t)2048 * 2048; N = 1024; int t2 = bidx - 4096; bx = t2 & 31; by = t2 >> 5; }
    else if (bidx < 8192) { src = Wv; dst = wqkvT + (size_t)3072 * 2048; N = 1024; int t2 = bidx - 6144; bx = t2 & 31; by = t2 >> 5; }
    else                  { src = Wo; dst = woT;                        N = 2048; int t2 = bidx - 8192; bx = t2 & 63; by = t2 >> 6; }
    int n0 = bx * 32, k0 = by * 32;
    int tx = threadIdx.x & 31, ty = threadIdx.x >> 5;  // 32 x 8
#pragma unroll
    for (int j = 0; j < 32; j += 8)
        tile[ty + j][tx] = src[(size_t)(k0 + ty + j) * N + n0 + tx];
    __syncthreads();
#pragma unroll
    for (int j = 0; j < 32; j += 8)
        dst[(size_t)(n0 + ty + j) * 2048 + k0 + tx] = (f16)tile[tx][ty + j];
}

// ---------- V blocked-transpose for attention ----------
__global__ __launch_bounds__(256) void k_vtrans(const f16* __restrict__ qkv, f16* __restrict__ vtg) {
    const int kt = blockIdx.x, bk = blockIdx.y;
    const int b = bk >> 3, kvh = bk & 7;
    const int tid = threadIdx.x;
    __shared__ f16 tile[64][132];
#pragma unroll
    for (int p = 0; p < 4; ++p) {
        int idx = p * 256 + tid;
        int r = idx >> 4, dc = (idx & 15) * 8;
        f16x8 v = *(const f16x8*)(qkv + (size_t)(b * T_SEQ + kt * 64 + r) * 4096 + 3072 + kvh * 128 + dc);
#pragma unroll
        for (int j = 0; j < 8; ++j) tile[r][dc + j] = v[j];
    }
    __syncthreads();
    f16* outb = vtg + (size_t)(bk * 32 + kt) * 8192;
#pragma unroll
    for (int p = 0; p < 4; ++p) {
        int c = p * 256 + tid;
        int kchunk = c >> 7, d = c & 127;
        f16x8 o;
#pragma unroll
        for (int j = 0; j < 8; ++j) o[j] = tile[kchunk * 8 + j][d];
        *(f16x8*)(outb + (size_t)c * 8) = o;
    }
}

// ---------- 256x256 8-phase GEMM: C[m][n] = sum_k A[m][k]*B[n][k] (both row-K) ----------
template <typename OutT>
__global__ __launch_bounds__(512, 1) void k_gemm256(const f16* __restrict__ A,
                                                    const f16* __restrict__ B,
                                                    OutT* __restrict__ C, int M, int N, int K) {
    extern __shared__ char smem[];
    f16* As = (f16*)smem;            // [2][256][64]
    f16* Bs = (f16*)smem + 32768;    // [2][256][64]
    const int tid = threadIdx.x, lane = tid & 63, w = tid >> 6;
    const int wr4 = w >> 1, wc2 = w & 1;
    const int cq = lane & 15, gq = lane >> 4;
    const int nbx = gridDim.x;
    const int nwg = nbx * gridDim.y;
    const int bid0 = blockIdx.y * nbx + blockIdx.x;
    const int bid = (bid0 & 7) * (nwg >> 3) + (bid0 >> 3);  // XCD swizzle (nwg%8==0)
    const int m0 = (bid / nbx) * 256, n0 = (bid % nbx) * 256;
    const int KT = K >> 6;

    f32x4 acc[2][2][2][4] = {};
    f16x8 aL[2][2], aH[2][2], bL[4][2], bH[4][2];

    auto stageA = [&](int buf, int half, int t) {
#pragma unroll
        for (int r = 0; r < 2; ++r) {
            int cb = r * 512 + w * 64;
            int c = cb + lane;
            int row = c >> 3, cc = c & 7;
            gld_lds16(A + (size_t)(m0 + half * 128 + row) * K + t * 64 + ((cc ^ (row & 7)) * 8),
                      As + buf * 16384 + half * 8192 + cb * 8);
        }
    };
    auto stageB = [&](int buf, int half, int t) {
#pragma unroll
        for (int r = 0; r < 2; ++r) {
            int cb = r * 512 + w * 64;
            int c = cb + lane;
            int row = c >> 3, cc = c & 7;
            gld_lds16(B + (size_t)(n0 + half * 128 + row) * K + t * 64 + ((cc ^ (row & 7)) * 8),
                      Bs + buf * 16384 + half * 8192 + cb * 8);
        }
    };
    auto rdA = [&](int buf, int qr, f16x8 a[2][2]) {
#pragma unroll
        for (int mi = 0; mi < 2; ++mi)
#pragma unroll
            for (int ks = 0; ks < 2; ++ks) {
                int R = qr * 128 + wr4 * 32 + mi * 16 + cq;
                a[mi][ks] = *(const f16x8*)&As[buf * 16384 + R * 64 + (((ks * 4 + gq) ^ (cq & 7)) * 8)];
            }
    };
    auto rdB = [&](int buf, int qc, f16x8 b[4][2]) {
#pragma unroll
        for (int ni = 0; ni < 4; ++ni)
#pragma unroll
            for (int ks = 0; ks < 2; ++ks) {
                int R = qc * 128 + wc2 * 64 + ni * 16 + cq;
                b[ni][ks] = *(const f16x8*)&Bs[buf * 16384 + R * 64 + (((ks * 4 + gq) ^ (cq & 7)) * 8)];
            }
    };

    stageA(0, 0, 0); stageB(0, 0, 0); stageB(0, 1, 0); stageA(0, 1, 0);
    if (KT > 1) { stageA(1, 0, 1); stageB(1, 0, 1); stageB(1, 1, 1); }
    asm volatile("s_waitcnt vmcnt(6)");
    __builtin_amdgcn_s_barrier();

#pragma unroll 1
    for (int t = 0; t < KT; ++t) {
        const int buf = t & 1;
        // ---- p1: Q(0,0) ----
        rdA(buf, 0, aL); rdB(buf, 0, bL);
        if (t + 1 < KT) stageA(buf ^ 1, 1, t + 1);  // Ahi(t+1)
        __builtin_amdgcn_s_barrier();
        asm volatile("s_waitcnt lgkmcnt(0)");
        __builtin_amdgcn_sched_barrier(0);
        __builtin_amdgcn_s_setprio(1);
#pragma unroll
        for (int mi = 0; mi < 2; ++mi)
#pragma unroll
            for (int ni = 0; ni < 4; ++ni)
#pragma unroll
                for (int ks = 0; ks < 2; ++ks)
                    acc[0][0][mi][ni] = __builtin_amdgcn_mfma_f32_16x16x32_f16(aL[mi][ks], bL[ni][ks], acc[0][0][mi][ni], 0, 0, 0);
        __builtin_amdgcn_s_setprio(0);
        __builtin_amdgcn_s_barrier();
        // ---- p2: Q(0,1) ----
        rdB(buf, 1, bH);
        if (t + 2 < KT) stageA(buf, 0, t + 2);
        __builtin_amdgcn_s_barrier();
        asm volatile("s_waitcnt lgkmcnt(0)");
        __builtin_amdgcn_sched_barrier(0);
        __builtin_amdgcn_s_setprio(1);
#pragma unroll
        for (int mi = 0; mi < 2; ++mi)
#pragma unroll
            for (int ni = 0; ni < 4; ++ni)
#pragma unroll
                for (int ks = 0; ks < 2; ++ks)
                    acc[0][1][mi][ni] = __builtin_amdgcn_mfma_f32_16x16x32_f16(aL[mi][ks], bH[ni][ks], acc[0][1][mi][ni], 0, 0, 0);
        __builtin_amdgcn_s_setprio(0);
        __builtin_amdgcn_s_barrier();
        // ---- p3: Q(1,1) ----
        rdA(buf, 1, aH);
        if (t + 2 < KT) stageB(buf, 0, t + 2);
        __builtin_amdgcn_s_barrier();
        asm volatile("s_waitcnt lgkmcnt(0)");
        __builtin_amdgcn_sched_barrier(0);
        __builtin_amdgcn_s_setprio(1);
#pragma unroll
        for (int mi = 0; mi < 2; ++mi)
#pragma unroll
            for (int ni = 0; ni < 4; ++ni)
#pragma unroll
                for (int ks = 0; ks < 2; ++ks)
                    acc[1][1][mi][ni] = __builtin_amdgcn_mfma_f32_16x16x32_f16(aH[mi][ks], bH[ni][ks], acc[1][1][mi][ni], 0, 0, 0);
        __builtin_amdgcn_s_setprio(0);
        __builtin_amdgcn_s_barrier();
        // ---- p4: Q(1,0) ----
        if (t + 2 < KT) stageB(buf, 1, t + 2);
        __builtin_amdgcn_s_barrier();
        __builtin_amdgcn_sched_barrier(0);
        __builtin_amdgcn_s_setprio(1);
#pragma unroll
        for (int mi = 0; mi < 2; ++mi)
#pragma unroll
            for (int ni = 0; ni < 4; ++ni)
#pragma unroll
                for (int ks = 0; ks < 2; ++ks)
                    acc[1][0][mi][ni] = __builtin_amdgcn_mfma_f32_16x16x32_f16(aH[mi][ks], bL[ni][ks], acc[1][0][mi][ni], 0, 0, 0);
        __builtin_amdgcn_s_setprio(0);
        if (t + 2 < KT) asm volatile("s_waitcnt vmcnt(6)");
        else            asm volatile("s_waitcnt vmcnt(0)");
        __builtin_amdgcn_s_barrier();
    }

#pragma unroll
    for (int qr = 0; qr < 2; ++qr)
#pragma unroll
        for (int qc = 0; qc < 2; ++qc)
#pragma unroll
            for (int mi = 0; mi < 2; ++mi)
#pragma unroll
                for (int ni = 0; ni < 4; ++ni)
#pragma unroll
                    for (int i = 0; i < 4; ++i) {
                        int row = m0 + qr * 128 + wr4 * 32 + mi * 16 + gq * 4 + i;
                        int col = n0 + qc * 128 + wc2 * 64 + ni * 16 + cq;
                        C[(size_t)row * N + col] = (OutT)acc[qr][qc][mi][ni][i];
                    }
}

// ---------- in-place xPos RoPE on qkv [8192][4096]; Q gets *scale*rsqrt(d), K gets /scale ----------
__global__ __launch_bounds__(256) void k_rope(f16* __restrict__ qkv, const float* __restrict__ tab) {
    int idx = blockIdx.x * 256 + threadIdx.x;
    const int QTOT = NBATCH * T_SEQ * 16 * 64;  // 8,388,608
    int f, col0, bt;
    bool isQ = idx < QTOT;
    if (isQ) {
        f = idx & 63; int hh = (idx >> 6) & 15; bt = idx >> 10;
        col0 = hh * 128 + f;
    } else {
        int j = idx - QTOT;
        f = j & 63; int hh = (j >> 6) & 7; bt = j >> 9;
        col0 = 2048 + hh * 128 + f;
    }
    int t = bt & (T_SEQ - 1);
    float cs = tab[t * 64 + f], sn = tab[131072 + t * 64 + f], sc = tab[262144 + t * 64 + f];
    float mult = isQ ? sc * 0.08838834764831845f : 1.0f / sc;  // fold 1/sqrt(128) into Q
    size_t p = (size_t)bt * 4096 + col0;
    float x1 = (float)qkv[p], x2 = (float)qkv[p + 64];
    qkv[p]      = (f16)((x1 * cs - x2 * sn) * mult);
    qkv[p + 64] = (f16)((x2 * cs + x1 * sn) * mult);
}

// ---------- causal GQA flash attention, v5: 2 heads/block, 8 waves sharing K/V LDS ----------
// grid 256 = b(4) x kvh(8) x pair(8); block 512 = 8 waves. Waves 0-3: head 2kvh,
// waves 4-7: head 2kvh+1; each wave owns 32 q-rows. K/V staged once per block
// (halved L2 traffic, halved staging per wave); 16 waves/CU for latency hiding.
__global__ __launch_bounds__(512) void k_attn(const f16* __restrict__ qkv,
                                              const f16* __restrict__ vtg,
                                              f16* __restrict__ ao) {
    const int bid0 = blockIdx.x;
    const int bid = (bid0 & 7) * 32 + (bid0 >> 3);  // XCD swizzle (256 = 8x32)
    const int pr = bid & 7, kvh = (bid >> 3) & 7, b = bid >> 6;
    const int bk = b * 8 + kvh;
    const int tid = threadIdx.x, lane = tid & 63, w = tid >> 6;
    const int w4 = w & 3, hg = w >> 2;
    const int h = kvh * 2 + hg;
    const int l31 = lane & 31, hi = lane >> 5;

    __shared__ f16 Klds[2][64 * 128];
    __shared__ f16 Vlds[2][8 * 128 * 8];

    const f16* kbase = qkv + (size_t)b * T_SEQ * 4096 + 2048 + kvh * 128;
    const f16* vbase = vtg + (size_t)bk * 32 * 8192;

    auto stage = [&](int buf, int kt) {
#pragma unroll
        for (int qq = 0; qq < 2; ++qq) {
            int c = w * 128 + qq * 64 + lane;
            int row = c >> 4;
            int ch = (c & 15) ^ (row & 15);
            gld_lds16(kbase + (size_t)(kt * 64 + row) * 4096 + ch * 8,
                      &Klds[buf][(w * 128 + qq * 64) * 8]);
        }
#pragma unroll
        for (int qq = 0; qq < 2; ++qq) {
            int c = w * 128 + qq * 64 + lane;
            gld_lds16(vbase + ((size_t)kt * 1024 + c) * 8,
                      &Vlds[buf][(w * 128 + qq * 64) * 8]);
        }
    };

#pragma unroll 1
    for (int hf = 0; hf < 2; ++hf) {
        const int qt = hf ? pr : (15 - pr);
        const int q0 = qt * 128;
        const int nkt = 2 * qt + 2;  // even, >= 2
        const int qrow = q0 + w4 * 32 + l31;

        f16x8 qf[8];
#pragma unroll
        for (int ds = 0; ds < 8; ++ds)
            qf[ds] = *(const f16x8*)(qkv + (size_t)(b * T_SEQ + qrow) * 4096 + h * 128 + ds * 16 + hi * 8);

        f32x16 Ot[4] = {};
        float mrow = -1e30f, lrow = 0.0f;

        stage(0, 0);
        __syncthreads();

#pragma unroll 1
        for (int kt = 0; kt < nkt; ++kt) {
            const int kb = kt & 1;
            if (kt + 1 < nkt) stage(kb ^ 1, kt + 1);

            if (!(kt == 2 * qt + 1 && w4 < 2)) {
                // ---- St = K Q^T (swapped): lane q = l31, k rows in regs ----
                f32x16 St0 = {}, St1 = {};
                __builtin_amdgcn_s_setprio(1);
#pragma unroll
                for (int ds = 0; ds < 8; ++ds) {
                    int slot = (((2 * ds + hi) ^ (l31 & 15)) << 3);
                    f16x8 k0 = *(const f16x8*)&Klds[kb][l31 * 128 + slot];
                    f16x8 k1 = *(const f16x8*)&Klds[kb][(32 + l31) * 128 + slot];
                    St0 = __builtin_amdgcn_mfma_f32_32x32x16_f16(k0, qf[ds], St0, 0, 0, 0);
                    St1 = __builtin_amdgcn_mfma_f32_32x32x16_f16(k1, qf[ds], St1, 0, 0, 0);
                }
                __builtin_amdgcn_s_setprio(0);

                // ---- causal mask ----
                if (kt >= 2 * qt) {
                    int kbase2 = kt * 64;
#pragma unroll
                    for (int r = 0; r < 16; ++r) {
                        int krel = (r & 3) + 8 * (r >> 2) + 4 * hi;
                        if (kbase2 + krel > qrow) St0[r] = -1e30f;
                        if (kbase2 + 32 + krel > qrow) St1[r] = -1e30f;
                    }
                }

                // ---- in-register online softmax ----
                float tm[16];
#pragma unroll
                for (int r = 0; r < 16; ++r) tm[r] = fmaxf(St0[r], St1[r]);
#pragma unroll
                for (int d = 8; d >= 1; d >>= 1)
#pragma unroll
                    for (int r = 0; r < 8; ++r)
                        if (r < d) tm[r] = fmaxf(tm[r], tm[r + d]);
                float tmax = tm[0];
                float mtile = fmaxf(tmax, __shfl_xor(tmax, 32, 64));

                if (!__all((mtile - mrow) <= 8.0f)) {  // T13 defer-max
                    float mnew = fmaxf(mrow, mtile);
                    float fs = __expf(mrow - mnew);
                    mrow = mnew;
                    lrow *= fs;
#pragma unroll
                    for (int dblk = 0; dblk < 4; ++dblk)
#pragma unroll
                        for (int e = 0; e < 16; ++e) Ot[dblk][e] *= fs;
                }
#pragma unroll
                for (int r = 0; r < 16; ++r) {
                    St0[r] = __expf(St0[r] - mrow);
                    St1[r] = __expf(St1[r] - mrow);
                }
                float ts[16];
#pragma unroll
                for (int r = 0; r < 16; ++r) ts[r] = St0[r] + St1[r];
#pragma unroll
                for (int d = 8; d >= 1; d >>= 1)
#pragma unroll
                    for (int r = 0; r < 8; ++r)
                        if (r < d) ts[r] += ts[r + d];
                float tsum = ts[0];
                lrow += tsum + __shfl_xor(tsum, 32, 64);

                // ---- pack P (cvt_pkrtz + shfl_xor 32) + PV ----
#define PV_P(o, pos) ((o) < 4 ? St0[((o) & 3) * 4 + (pos)] : St1[((o) & 3) * 4 + (pos)])
#pragma unroll
                for (int s = 0; s < 4; ++s) {
                    unsigned x1 = pk2(PV_P(2 * s, 0), PV_P(2 * s, 1));
                    unsigned x2 = pk2(PV_P(2 * s, 2), PV_P(2 * s, 3));
                    unsigned y1 = pk2(PV_P(2 * s + 1, 0), PV_P(2 * s + 1, 1));
                    unsigned y2 = pk2(PV_P(2 * s + 1, 2), PV_P(2 * s + 1, 3));
                    unsigned sx1 = __shfl_xor(x1, 32, 64);
                    unsigned sx2 = __shfl_xor(x2, 32, 64);
                    unsigned sy1 = __shfl_xor(y1, 32, 64);
                    unsigned sy2 = __shfl_xor(y2, 32, 64);
                    u32x4 pw;
                    pw[0] = hi ? sy1 : x1;
                    pw[1] = hi ? sy2 : x2;
                    pw[2] = hi ? y1 : sx1;
                    pw[3] = hi ? y2 : sx2;
                    f16x8 pa = __builtin_bit_cast(f16x8, pw);
                    __builtin_amdgcn_s_setprio(1);
#pragma unroll
                    for (int dblk = 0; dblk < 4; ++dblk) {
                        f16x8 vb = *(const f16x8*)&Vlds[kb][(((2 * s + hi) << 7) + 32 * dblk + l31) << 3];
                        Ot[dblk] = __builtin_amdgcn_mfma_f32_32x32x16_f16(vb, pa, Ot[dblk], 0, 0, 0);
                    }
                    __builtin_amdgcn_s_setprio(0);
                }
#undef PV_P
            }
            __syncthreads();  // buf kb readers done; K/V(kt+1) staged (vmcnt drained)
        }

        // ---- epilogue ----
        {
            float inv = 1.0f / lrow;
            size_t rowb = (size_t)(b * T_SEQ + qrow) * 2048 + h * 128;
#pragma unroll
            for (int dblk = 0; dblk < 4; ++dblk)
#pragma unroll
                for (int rg = 0; rg < 4; ++rg) {
                    f16x4 o4 = { (f16)(Ot[dblk][rg * 4 + 0] * inv), (f16)(Ot[dblk][rg * 4 + 1] * inv),
                                 (f16)(Ot[dblk][rg * 4 + 2] * inv), (f16)(Ot[dblk][rg * 4 + 3] * inv) };
                    *(f16x4*)(ao + rowb + dblk * 32 + rg * 8 + hi * 4) = o4;
                }
        }
    }
}

extern "C" void kernel_launch(void* const* d_in, const int* in_sizes, int n_in,
                              void* d_out, int out_size, void* d_ws, size_t ws_size,
                              hipStream_t stream) {
    const float* x  = (const float*)d_in[0];
    const float* Wq = (const float*)d_in[1];
    const float* Wk = (const float*)d_in[2];
    const float* Wv = (const float*)d_in[3];
    const float* Wo = (const float*)d_in[4];
    float* out = (float*)d_out;

    // workspace (fp16 elems): xh 16.7M | wqkvT 8.4M | woT 4.2M | qkv 33.5M | tab (f32)
    f16* xh    = (f16*)d_ws;
    f16* wqkvT = xh + (size_t)16777216;
    f16* woT   = wqkvT + (size_t)8388608;
    f16* qkv   = woT + (size_t)4194304;
    float* tab = (float*)(qkv + (size_t)33554432);
    f16* ao  = xh;     // alias: xh dead after GEMM1
    f16* vtg = wqkvT;  // alias: wqkvT dead after GEMM1 (8.4M f16 = exact fit)

    hipFuncSetAttribute(reinterpret_cast<const void*>(&k_gemm256<f16>),
                        hipFuncAttributeMaxDynamicSharedMemorySize, 131072);
    hipFuncSetAttribute(reinterpret_cast<const void*>(&k_gemm256<float>),
                        hipFuncAttributeMaxDynamicSharedMemorySize, 131072);

    k_prep<<<29184, 256, 0, stream>>>(x, Wq, Wk, Wv, Wo, xh, wqkvT, woT, tab);
    // QKV projection: qkv[8192][4096]
    k_gemm256<f16><<<dim3(16, 32), 512, 131072, stream>>>(xh, wqkvT, qkv, 8192, 4096, 2048);
    k_vtrans<<<dim3(32, 32), 256, 0, stream>>>(qkv, vtg);
    k_rope<<<49152, 256, 0, stream>>>(qkv, tab);
    k_attn<<<256, 512, 0, stream>>>(qkv, vtg, ao);
    // output projection -> fp32
    k_gemm256<float><<<dim3(8, 32), 512, 131072, stream>>>(ao, woT, out, 8192, 2048, 2048);
}

// Round 9
// 381.533 us; speedup vs baseline: 2.1112x; 1.0044x over previous
//
#include <hip/hip_runtime.h>

typedef _Float16 f16;
typedef __attribute__((ext_vector_type(8))) _Float16 f16x8;
typedef __attribute__((ext_vector_type(4))) _Float16 f16x4;
typedef __attribute__((ext_vector_type(4))) float f32x4;
typedef __attribute__((ext_vector_type(16))) float f32x16;
typedef __attribute__((ext_vector_type(4))) unsigned u32x4;

#define T_SEQ 2048
#define NBATCH 4

__device__ __forceinline__ void gld_lds16(const f16* g, f16* l) {
    __builtin_amdgcn_global_load_lds((const __attribute__((address_space(1))) void*)g,
                                     (__attribute__((address_space(3))) void*)l, 16, 0, 0);
}

__device__ __forceinline__ unsigned pk2(float a, float b) {
    __attribute__((ext_vector_type(2))) __fp16 h = __builtin_amdgcn_cvt_pkrtz(a, b);
    return __builtin_bit_cast(unsigned, h);
}

// ---------- fused prep: cast x | transpose Wq/Wk/Wv/Wo | xPos tables ----------
__global__ __launch_bounds__(256) void k_prep(const float* __restrict__ x,
                                              const float* __restrict__ Wq,
                                              const float* __restrict__ Wk,
                                              const float* __restrict__ Wv,
                                              const float* __restrict__ Wo,
                                              f16* __restrict__ xh,
                                              f16* __restrict__ wqkvT,
                                              f16* __restrict__ woT,
                                              float* __restrict__ tab) {
    __shared__ float tile[32][33];
    int bidx = blockIdx.x;
    if (bidx < 16384) {  // cast x fp32 -> fp16 (float4 per thread)
        int i = bidx * 256 + threadIdx.x;
        float4 v = ((const float4*)x)[i];
        f16x4 o = { (f16)v.x, (f16)v.y, (f16)v.z, (f16)v.w };
        ((f16x4*)xh)[i] = o;
        return;
    }
    bidx -= 16384;
    if (bidx >= 12288) {  // tables: cos | sin | scale, each [T][64] fp32
        int i = (bidx - 12288) * 256 + threadIdx.x;  // 131072 total
        int t = i >> 6, f = i & 63;
        float inv_freq = powf(10000.0f, -(2.0f * f) / 128.0f);
        float ang = (float)t * inv_freq;
        float sv = (2.0f * f + 51.2f) / 179.2f;
        float pw = ((float)t - 1024.0f) / 512.0f;
        tab[i] = cosf(ang);
        tab[131072 + i] = sinf(ang);
        tab[262144 + i] = powf(sv, pw);
        return;
    }
    // weight transpose+cast: dst[n][k] = (f16)src[k][n], K=2048
    const float* src; f16* dst; int N, bx, by;
    if (bidx < 4096)      { src = Wq; dst = wqkvT;                      N = 2048; bx = bidx & 63; by = bidx >> 6; }
    else if (bidx < 6144) { src = Wk; dst = wqkvT + (size_t)2048 * 2048; N = 1024; int t2 = bidx - 4096; bx = t2 & 31; by = t2 >> 5; }
    else if (bidx < 8192) { src = Wv; dst = wqkvT + (size_t)3072 * 2048; N = 1024; int t2 = bidx - 6144; bx = t2 & 31; by = t2 >> 5; }
    else                  { src = Wo; dst = woT;                        N = 2048; int t2 = bidx - 8192; bx = t2 & 63; by = t2 >> 6; }
    int n0 = bx * 32, k0 = by * 32;
    int tx = threadIdx.x & 31, ty = threadIdx.x >> 5;  // 32 x 8
#pragma unroll
    for (int j = 0; j < 32; j += 8)
        tile[ty + j][tx] = src[(size_t)(k0 + ty + j) * N + n0 + tx];
    __syncthreads();
#pragma unroll
    for (int j = 0; j < 32; j += 8)
        dst[(size_t)(n0 + ty + j) * 2048 + k0 + tx] = (f16)tile[tx][ty + j];
}

// ---------- V blocked-transpose for attention ----------
__global__ __launch_bounds__(256) void k_vtrans(const f16* __restrict__ qkv, f16* __restrict__ vtg) {
    const int kt = blockIdx.x, bk = blockIdx.y;
    const int b = bk >> 3, kvh = bk & 7;
    const int tid = threadIdx.x;
    __shared__ f16 tile[64][132];
#pragma unroll
    for (int p = 0; p < 4; ++p) {
        int idx = p * 256 + tid;
        int r = idx >> 4, dc = (idx & 15) * 8;
        f16x8 v = *(const f16x8*)(qkv + (size_t)(b * T_SEQ + kt * 64 + r) * 4096 + 3072 + kvh * 128 + dc);
#pragma unroll
        for (int j = 0; j < 8; ++j) tile[r][dc + j] = v[j];
    }
    __syncthreads();
    f16* outb = vtg + (size_t)(bk * 32 + kt) * 8192;
#pragma unroll
    for (int p = 0; p < 4; ++p) {
        int c = p * 256 + tid;
        int kchunk = c >> 7, d = c & 127;
        f16x8 o;
#pragma unroll
        for (int j = 0; j < 8; ++j) o[j] = tile[kchunk * 8 + j][d];
        *(f16x8*)(outb + (size_t)c * 8) = o;
    }
}

// ---------- 256x256 8-phase GEMM: C[m][n] = sum_k A[m][k]*B[n][k] (both row-K) ----------
// XCD supertile swizzle: XCD x = bid0&7 owns an 8m x (nbx/2)n tile block ->
// per-XCD K-slice working set ~512 KB (fits 4 MB L2), panels fetched once.
template <typename OutT>
__global__ __launch_bounds__(512, 1) void k_gemm256(const f16* __restrict__ A,
                                                    const f16* __restrict__ B,
                                                    OutT* __restrict__ C, int M, int N, int K) {
    extern __shared__ char smem[];
    f16* As = (f16*)smem;            // [2][256][64]
    f16* Bs = (f16*)smem + 32768;    // [2][256][64]
    const int tid = threadIdx.x, lane = tid & 63, w = tid >> 6;
    const int wr4 = w >> 1, wc2 = w & 1;
    const int cq = lane & 15, gq = lane >> 4;
    const int nbx = gridDim.x;                 // n tiles: 16 (GEMM1) or 8 (GEMM2)
    const int bid0 = blockIdx.y * nbx + blockIdx.x;
    const int x = bid0 & 7, idx = bid0 >> 3;   // XCD id, local index
    const int snb = (nbx == 16) ? 3 : 2;       // log2(nbx/2)
    const int mt = (x >> 1) * 8 + (idx >> snb);
    const int nt = (x & 1) * (nbx >> 1) + (idx & ((nbx >> 1) - 1));
    const int m0 = mt * 256, n0 = nt * 256;
    const int KT = K >> 6;

    f32x4 acc[2][2][2][4] = {};
    f16x8 aL[2][2], aH[2][2], bL[4][2], bH[4][2];

    auto stageA = [&](int buf, int half, int t) {
#pragma unroll
        for (int r = 0; r < 2; ++r) {
            int cb = r * 512 + w * 64;
            int c = cb + lane;
            int row = c >> 3, cc = c & 7;
            gld_lds16(A + (size_t)(m0 + half * 128 + row) * K + t * 64 + ((cc ^ (row & 7)) * 8),
                      As + buf * 16384 + half * 8192 + cb * 8);
        }
    };
    auto stageB = [&](int buf, int half, int t) {
#pragma unroll
        for (int r = 0; r < 2; ++r) {
            int cb = r * 512 + w * 64;
            int c = cb + lane;
            int row = c >> 3, cc = c & 7;
            gld_lds16(B + (size_t)(n0 + half * 128 + row) * K + t * 64 + ((cc ^ (row & 7)) * 8),
                      Bs + buf * 16384 + half * 8192 + cb * 8);
        }
    };
    auto rdA = [&](int buf, int qr, f16x8 a[2][2]) {
#pragma unroll
        for (int mi = 0; mi < 2; ++mi)
#pragma unroll
            for (int ks = 0; ks < 2; ++ks) {
                int R = qr * 128 + wr4 * 32 + mi * 16 + cq;
                a[mi][ks] = *(const f16x8*)&As[buf * 16384 + R * 64 + (((ks * 4 + gq) ^ (cq & 7)) * 8)];
            }
    };
    auto rdB = [&](int buf, int qc, f16x8 b[4][2]) {
#pragma unroll
        for (int ni = 0; ni < 4; ++ni)
#pragma unroll
            for (int ks = 0; ks < 2; ++ks) {
                int R = qc * 128 + wc2 * 64 + ni * 16 + cq;
                b[ni][ks] = *(const f16x8*)&Bs[buf * 16384 + R * 64 + (((ks * 4 + gq) ^ (cq & 7)) * 8)];
            }
    };

    stageA(0, 0, 0); stageB(0, 0, 0); stageB(0, 1, 0); stageA(0, 1, 0);
    if (KT > 1) { stageA(1, 0, 1); stageB(1, 0, 1); stageB(1, 1, 1); }
    asm volatile("s_waitcnt vmcnt(6)");
    __builtin_amdgcn_s_barrier();

#pragma unroll 1
    for (int t = 0; t < KT; ++t) {
        const int buf = t & 1;
        // ---- p1: Q(0,0) ----
        rdA(buf, 0, aL); rdB(buf, 0, bL);
        if (t + 1 < KT) stageA(buf ^ 1, 1, t + 1);  // Ahi(t+1)
        __builtin_amdgcn_s_barrier();
        asm volatile("s_waitcnt lgkmcnt(0)");
        __builtin_amdgcn_sched_barrier(0);
        __builtin_amdgcn_s_setprio(1);
#pragma unroll
        for (int mi = 0; mi < 2; ++mi)
#pragma unroll
            for (int ni = 0; ni < 4; ++ni)
#pragma unroll
                for (int ks = 0; ks < 2; ++ks)
                    acc[0][0][mi][ni] = __builtin_amdgcn_mfma_f32_16x16x32_f16(aL[mi][ks], bL[ni][ks], acc[0][0][mi][ni], 0, 0, 0);
        __builtin_amdgcn_s_setprio(0);
        __builtin_amdgcn_s_barrier();
        // ---- p2: Q(0,1) ----
        rdB(buf, 1, bH);
        if (t + 2 < KT) stageA(buf, 0, t + 2);
        __builtin_amdgcn_s_barrier();
        asm volatile("s_waitcnt lgkmcnt(0)");
        __builtin_amdgcn_sched_barrier(0);
        __builtin_amdgcn_s_setprio(1);
#pragma unroll
        for (int mi = 0; mi < 2; ++mi)
#pragma unroll
            for (int ni = 0; ni < 4; ++ni)
#pragma unroll
                for (int ks = 0; ks < 2; ++ks)
                    acc[0][1][mi][ni] = __builtin_amdgcn_mfma_f32_16x16x32_f16(aL[mi][ks], bH[ni][ks], acc[0][1][mi][ni], 0, 0, 0);
        __builtin_amdgcn_s_setprio(0);
        __builtin_amdgcn_s_barrier();
        // ---- p3: Q(1,1) ----
        rdA(buf, 1, aH);
        if (t + 2 < KT) stageB(buf, 0, t + 2);
        __builtin_amdgcn_s_barrier();
        asm volatile("s_waitcnt lgkmcnt(0)");
        __builtin_amdgcn_sched_barrier(0);
        __builtin_amdgcn_s_setprio(1);
#pragma unroll
        for (int mi = 0; mi < 2; ++mi)
#pragma unroll
            for (int ni = 0; ni < 4; ++ni)
#pragma unroll
                for (int ks = 0; ks < 2; ++ks)
                    acc[1][1][mi][ni] = __builtin_amdgcn_mfma_f32_16x16x32_f16(aH[mi][ks], bH[ni][ks], acc[1][1][mi][ni], 0, 0, 0);
        __builtin_amdgcn_s_setprio(0);
        __builtin_amdgcn_s_barrier();
        // ---- p4: Q(1,0) ----
        if (t + 2 < KT) stageB(buf, 1, t + 2);
        __builtin_amdgcn_s_barrier();
        __builtin_amdgcn_sched_barrier(0);
        __builtin_amdgcn_s_setprio(1);
#pragma unroll
        for (int mi = 0; mi < 2; ++mi)
#pragma unroll
            for (int ni = 0; ni < 4; ++ni)
#pragma unroll
                for (int ks = 0; ks < 2; ++ks)
                    acc[1][0][mi][ni] = __builtin_amdgcn_mfma_f32_16x16x32_f16(aH[mi][ks], bL[ni][ks], acc[1][0][mi][ni], 0, 0, 0);
        __builtin_amdgcn_s_setprio(0);
        if (t + 2 < KT) asm volatile("s_waitcnt vmcnt(6)");
        else            asm volatile("s_waitcnt vmcnt(0)");
        __builtin_amdgcn_s_barrier();
    }

#pragma unroll
    for (int qr = 0; qr < 2; ++qr)
#pragma unroll
        for (int qc = 0; qc < 2; ++qc)
#pragma unroll
            for (int mi = 0; mi < 2; ++mi)
#pragma unroll
                for (int ni = 0; ni < 4; ++ni)
#pragma unroll
                    for (int i = 0; i < 4; ++i) {
                        int row = m0 + qr * 128 + wr4 * 32 + mi * 16 + gq * 4 + i;
                        int col = n0 + qc * 128 + wc2 * 64 + ni * 16 + cq;
                        C[(size_t)row * N + col] = (OutT)acc[qr][qc][mi][ni][i];
                    }
}

// ---------- in-place xPos RoPE on qkv [8192][4096]; Q gets *scale*rsqrt(d), K gets /scale ----------
__global__ __launch_bounds__(256) void k_rope(f16* __restrict__ qkv, const float* __restrict__ tab) {
    int idx = blockIdx.x * 256 + threadIdx.x;
    const int QTOT = NBATCH * T_SEQ * 16 * 64;  // 8,388,608
    int f, col0, bt;
    bool isQ = idx < QTOT;
    if (isQ) {
        f = idx & 63; int hh = (idx >> 6) & 15; bt = idx >> 10;
        col0 = hh * 128 + f;
    } else {
        int j = idx - QTOT;
        f = j & 63; int hh = (j >> 6) & 7; bt = j >> 9;
        col0 = 2048 + hh * 128 + f;
    }
    int t = bt & (T_SEQ - 1);
    float cs = tab[t * 64 + f], sn = tab[131072 + t * 64 + f], sc = tab[262144 + t * 64 + f];
    float mult = isQ ? sc * 0.08838834764831845f : 1.0f / sc;  // fold 1/sqrt(128) into Q
    size_t p = (size_t)bt * 4096 + col0;
    float x1 = (float)qkv[p], x2 = (float)qkv[p + 64];
    qkv[p]      = (f16)((x1 * cs - x2 * sn) * mult);
    qkv[p + 64] = (f16)((x2 * cs + x1 * sn) * mult);
}

// ---------- causal GQA flash attention, v5: 2 heads/block, 8 waves sharing K/V LDS ----------
__global__ __launch_bounds__(512) void k_attn(const f16* __restrict__ qkv,
                                              const f16* __restrict__ vtg,
                                              f16* __restrict__ ao) {
    const int bid0 = blockIdx.x;
    const int bid = (bid0 & 7) * 32 + (bid0 >> 3);  // XCD swizzle (256 = 8x32)
    const int pr = bid & 7, kvh = (bid >> 3) & 7, b = bid >> 6;
    const int bk = b * 8 + kvh;
    const int tid = threadIdx.x, lane = tid & 63, w = tid >> 6;
    const int w4 = w & 3, hg = w >> 2;
    const int h = kvh * 2 + hg;
    const int l31 = lane & 31, hi = lane >> 5;

    __shared__ f16 Klds[2][64 * 128];
    __shared__ f16 Vlds[2][8 * 128 * 8];

    const f16* kbase = qkv + (size_t)b * T_SEQ * 4096 + 2048 + kvh * 128;
    const f16* vbase = vtg + (size_t)bk * 32 * 8192;

    auto stage = [&](int buf, int kt) {
#pragma unroll
        for (int qq = 0; qq < 2; ++qq) {
            int c = w * 128 + qq * 64 + lane;
            int row = c >> 4;
            int ch = (c & 15) ^ (row & 15);
            gld_lds16(kbase + (size_t)(kt * 64 + row) * 4096 + ch * 8,
                      &Klds[buf][(w * 128 + qq * 64) * 8]);
        }
#pragma unroll
        for (int qq = 0; qq < 2; ++qq) {
            int c = w * 128 + qq * 64 + lane;
            gld_lds16(vbase + ((size_t)kt * 1024 + c) * 8,
                      &Vlds[buf][(w * 128 + qq * 64) * 8]);
        }
    };

#pragma unroll 1
    for (int hf = 0; hf < 2; ++hf) {
        const int qt = hf ? pr : (15 - pr);
        const int q0 = qt * 128;
        const int nkt = 2 * qt + 2;  // even, >= 2
        const int qrow = q0 + w4 * 32 + l31;

        f16x8 qf[8];
#pragma unroll
        for (int ds = 0; ds < 8; ++ds)
            qf[ds] = *(const f16x8*)(qkv + (size_t)(b * T_SEQ + qrow) * 4096 + h * 128 + ds * 16 + hi * 8);

        f32x16 Ot[4] = {};
        float mrow = -1e30f, lrow = 0.0f;

        stage(0, 0);
        __syncthreads();

#pragma unroll 1
        for (int kt = 0; kt < nkt; ++kt) {
            const int kb = kt & 1;
            if (kt + 1 < nkt) stage(kb ^ 1, kt + 1);

            if (!(kt == 2 * qt + 1 && w4 < 2)) {
                // ---- St = K Q^T (swapped): lane q = l31, k rows in regs ----
                f32x16 St0 = {}, St1 = {};
                __builtin_amdgcn_s_setprio(1);
#pragma unroll
                for (int ds = 0; ds < 8; ++ds) {
                    int slot = (((2 * ds + hi) ^ (l31 & 15)) << 3);
                    f16x8 k0 = *(const f16x8*)&Klds[kb][l31 * 128 + slot];
                    f16x8 k1 = *(const f16x8*)&Klds[kb][(32 + l31) * 128 + slot];
                    St0 = __builtin_amdgcn_mfma_f32_32x32x16_f16(k0, qf[ds], St0, 0, 0, 0);
                    St1 = __builtin_amdgcn_mfma_f32_32x32x16_f16(k1, qf[ds], St1, 0, 0, 0);
                }
                __builtin_amdgcn_s_setprio(0);

                // ---- causal mask ----
                if (kt >= 2 * qt) {
                    int kbase2 = kt * 64;
#pragma unroll
                    for (int r = 0; r < 16; ++r) {
                        int krel = (r & 3) + 8 * (r >> 2) + 4 * hi;
                        if (kbase2 + krel > qrow) St0[r] = -1e30f;
                        if (kbase2 + 32 + krel > qrow) St1[r] = -1e30f;
                    }
                }

                // ---- in-register online softmax ----
                float tm[16];
#pragma unroll
                for (int r = 0; r < 16; ++r) tm[r] = fmaxf(St0[r], St1[r]);
#pragma unroll
                for (int d = 8; d >= 1; d >>= 1)
#pragma unroll
                    for (int r = 0; r < 8; ++r)
                        if (r < d) tm[r] = fmaxf(tm[r], tm[r + d]);
                float tmax = tm[0];
                float mtile = fmaxf(tmax, __shfl_xor(tmax, 32, 64));

                if (!__all((mtile - mrow) <= 8.0f)) {  // T13 defer-max
                    float mnew = fmaxf(mrow, mtile);
                    float fs = __expf(mrow - mnew);
                    mrow = mnew;
                    lrow *= fs;
#pragma unroll
                    for (int dblk = 0; dblk < 4; ++dblk)
#pragma unroll
                        for (int e = 0; e < 16; ++e) Ot[dblk][e] *= fs;
                }
#pragma unroll
                for (int r = 0; r < 16; ++r) {
                    St0[r] = __expf(St0[r] - mrow);
                    St1[r] = __expf(St1[r] - mrow);
                }
                float ts[16];
#pragma unroll
                for (int r = 0; r < 16; ++r) ts[r] = St0[r] + St1[r];
#pragma unroll
                for (int d = 8; d >= 1; d >>= 1)
#pragma unroll
                    for (int r = 0; r < 8; ++r)
                        if (r < d) ts[r] += ts[r + d];
                float tsum = ts[0];
                lrow += tsum + __shfl_xor(tsum, 32, 64);

                // ---- pack P (cvt_pkrtz + shfl_xor 32) + PV ----
#define PV_P(o, pos) ((o) < 4 ? St0[((o) & 3) * 4 + (pos)] : St1[((o) & 3) * 4 + (pos)])
#pragma unroll
                for (int s = 0; s < 4; ++s) {
                    unsigned x1 = pk2(PV_P(2 * s, 0), PV_P(2 * s, 1));
                    unsigned x2 = pk2(PV_P(2 * s, 2), PV_P(2 * s, 3));
                    unsigned y1 = pk2(PV_P(2 * s + 1, 0), PV_P(2 * s + 1, 1));
                    unsigned y2 = pk2(PV_P(2 * s + 1, 2), PV_P(2 * s + 1, 3));
                    unsigned sx1 = __shfl_xor(x1, 32, 64);
                    unsigned sx2 = __shfl_xor(x2, 32, 64);
                    unsigned sy1 = __shfl_xor(y1, 32, 64);
                    unsigned sy2 = __shfl_xor(y2, 32, 64);
                    u32x4 pw;
                    pw[0] = hi ? sy1 : x1;
                    pw[1] = hi ? sy2 : x2;
                    pw[2] = hi ? y1 : sx1;
                    pw[3] = hi ? y2 : sx2;
                    f16x8 pa = __builtin_bit_cast(f16x8, pw);
                    __builtin_amdgcn_s_setprio(1);
#pragma unroll
                    for (int dblk = 0; dblk < 4; ++dblk) {
                        f16x8 vb = *(const f16x8*)&Vlds[kb][(((2 * s + hi) << 7) + 32 * dblk + l31) << 3];
                        Ot[dblk] = __builtin_amdgcn_mfma_f32_32x32x16_f16(vb, pa, Ot[dblk], 0, 0, 0);
                    }
                    __builtin_amdgcn_s_setprio(0);
                }
#undef PV_P
            }
            __syncthreads();  // buf kb readers done; K/V(kt+1) staged (vmcnt drained)
        }

        // ---- epilogue ----
        {
            float inv = 1.0f / lrow;
            size_t rowb = (size_t)(b * T_SEQ + qrow) * 2048 + h * 128;
#pragma unroll
            for (int dblk = 0; dblk < 4; ++dblk)
#pragma unroll
                for (int rg = 0; rg < 4; ++rg) {
                    f16x4 o4 = { (f16)(Ot[dblk][rg * 4 + 0] * inv), (f16)(Ot[dblk][rg * 4 + 1] * inv),
                                 (f16)(Ot[dblk][rg * 4 + 2] * inv), (f16)(Ot[dblk][rg * 4 + 3] * inv) };
                    *(f16x4*)(ao + rowb + dblk * 32 + rg * 8 + hi * 4) = o4;
                }
        }
    }
}

extern "C" void kernel_launch(void* const* d_in, const int* in_sizes, int n_in,
                              void* d_out, int out_size, void* d_ws, size_t ws_size,
                              hipStream_t stream) {
    const float* x  = (const float*)d_in[0];
    const float* Wq = (const float*)d_in[1];
    const float* Wk = (const float*)d_in[2];
    const float* Wv = (const float*)d_in[3];
    const float* Wo = (const float*)d_in[4];
    float* out = (float*)d_out;

    // workspace (fp16 elems): xh 16.7M | wqkvT 8.4M | woT 4.2M | qkv 33.5M | tab (f32)
    f16* xh    = (f16*)d_ws;
    f16* wqkvT = xh + (size_t)16777216;
    f16* woT   = wqkvT + (size_t)8388608;
    f16* qkv   = woT + (size_t)4194304;
    float* tab = (float*)(qkv + (size_t)33554432);
    f16* ao  = xh;     // alias: xh dead after GEMM1
    f16* vtg = wqkvT;  // alias: wqkvT dead after GEMM1 (8.4M f16 = exact fit)

    hipFuncSetAttribute(reinterpret_cast<const void*>(&k_gemm256<f16>),
                        hipFuncAttributeMaxDynamicSharedMemorySize, 131072);
    hipFuncSetAttribute(reinterpret_cast<const void*>(&k_gemm256<float>),
                        hipFuncAttributeMaxDynamicSharedMemorySize, 131072);

    k_prep<<<29184, 256, 0, stream>>>(x, Wq, Wk, Wv, Wo, xh, wqkvT, woT, tab);
    // QKV projection: qkv[8192][4096]
    k_gemm256<f16><<<dim3(16, 32), 512, 131072, stream>>>(xh, wqkvT, qkv, 8192, 4096, 2048);
    k_vtrans<<<dim3(32, 32), 256, 0, stream>>>(qkv, vtg);
    k_rope<<<49152, 256, 0, stream>>>(qkv, tab);
    k_attn<<<256, 512, 0, stream>>>(qkv, vtg, ao);
    // output projection -> fp32
    k_gemm256<float><<<dim3(8, 32), 512, 131072, stream>>>(ao, woT, out, 8192, 2048, 2048);
}

// Round 10
// 373.696 us; speedup vs baseline: 2.1555x; 1.0210x over previous
//
#include <hip/hip_runtime.h>

typedef _Float16 f16;
typedef __attribute__((ext_vector_type(8))) _Float16 f16x8;
typedef __attribute__((ext_vector_type(4))) _Float16 f16x4;
typedef __attribute__((ext_vector_type(4))) float f32x4;
typedef __attribute__((ext_vector_type(16))) float f32x16;
typedef __attribute__((ext_vector_type(4))) unsigned u32x4;

#define T_SEQ 2048
#define NBATCH 4

__device__ __forceinline__ void gld_lds16(const f16* g, f16* l) {
    __builtin_amdgcn_global_load_lds((const __attribute__((address_space(1))) void*)g,
                                     (__attribute__((address_space(3))) void*)l, 16, 0, 0);
}

__device__ __forceinline__ unsigned pk2(float a, float b) {
    __attribute__((ext_vector_type(2))) __fp16 h = __builtin_amdgcn_cvt_pkrtz(a, b);
    return __builtin_bit_cast(unsigned, h);
}

// ---------- fused prep: cast x | transpose Wq/Wk/Wv/Wo | xPos tables ----------
__global__ __launch_bounds__(256) void k_prep(const float* __restrict__ x,
                                              const float* __restrict__ Wq,
                                              const float* __restrict__ Wk,
                                              const float* __restrict__ Wv,
                                              const float* __restrict__ Wo,
                                              f16* __restrict__ xh,
                                              f16* __restrict__ wqkvT,
                                              f16* __restrict__ woT,
                                              float* __restrict__ tab) {
    __shared__ float tile[32][33];
    int bidx = blockIdx.x;
    if (bidx < 16384) {  // cast x fp32 -> fp16 (float4 per thread)
        int i = bidx * 256 + threadIdx.x;
        float4 v = ((const float4*)x)[i];
        f16x4 o = { (f16)v.x, (f16)v.y, (f16)v.z, (f16)v.w };
        ((f16x4*)xh)[i] = o;
        return;
    }
    bidx -= 16384;
    if (bidx >= 12288) {  // tables: cos | sin | scale, each [T][64] fp32
        int i = (bidx - 12288) * 256 + threadIdx.x;  // 131072 total
        int t = i >> 6, f = i & 63;
        float inv_freq = powf(10000.0f, -(2.0f * f) / 128.0f);
        float ang = (float)t * inv_freq;
        float sv = (2.0f * f + 51.2f) / 179.2f;
        float pw = ((float)t - 1024.0f) / 512.0f;
        tab[i] = cosf(ang);
        tab[131072 + i] = sinf(ang);
        tab[262144 + i] = powf(sv, pw);
        return;
    }
    // weight transpose+cast: dst[n][k] = (f16)src[k][n], K=2048
    const float* src; f16* dst; int N, bx, by;
    if (bidx < 4096)      { src = Wq; dst = wqkvT;                      N = 2048; bx = bidx & 63; by = bidx >> 6; }
    else if (bidx < 6144) { src = Wk; dst = wqkvT + (size_t)2048 * 2048; N = 1024; int t2 = bidx - 4096; bx = t2 & 31; by = t2 >> 5; }
    else if (bidx < 8192) { src = Wv; dst = wqkvT + (size_t)3072 * 2048; N = 1024; int t2 = bidx - 6144; bx = t2 & 31; by = t2 >> 5; }
    else                  { src = Wo; dst = woT;                        N = 2048; int t2 = bidx - 8192; bx = t2 & 63; by = t2 >> 6; }
    int n0 = bx * 32, k0 = by * 32;
    int tx = threadIdx.x & 31, ty = threadIdx.x >> 5;  // 32 x 8
#pragma unroll
    for (int j = 0; j < 32; j += 8)
        tile[ty + j][tx] = src[(size_t)(k0 + ty + j) * N + n0 + tx];
    __syncthreads();
#pragma unroll
    for (int j = 0; j < 32; j += 8)
        dst[(size_t)(n0 + ty + j) * 2048 + k0 + tx] = (f16)tile[tx][ty + j];
}

// ---------- V blocked-transpose for attention ----------
__global__ __launch_bounds__(256) void k_vtrans(const f16* __restrict__ qkv, f16* __restrict__ vtg) {
    const int kt = blockIdx.x, bk = blockIdx.y;
    const int b = bk >> 3, kvh = bk & 7;
    const int tid = threadIdx.x;
    __shared__ f16 tile[64][132];
#pragma unroll
    for (int p = 0; p < 4; ++p) {
        int idx = p * 256 + tid;
        int r = idx >> 4, dc = (idx & 15) * 8;
        f16x8 v = *(const f16x8*)(qkv + (size_t)(b * T_SEQ + kt * 64 + r) * 4096 + 3072 + kvh * 128 + dc);
#pragma unroll
        for (int j = 0; j < 8; ++j) tile[r][dc + j] = v[j];
    }
    __syncthreads();
    f16* outb = vtg + (size_t)(bk * 32 + kt) * 8192;
#pragma unroll
    for (int p = 0; p < 4; ++p) {
        int c = p * 256 + tid;
        int kchunk = c >> 7, d = c & 127;
        f16x8 o;
#pragma unroll
        for (int j = 0; j < 8; ++j) o[j] = tile[kchunk * 8 + j][d];
        *(f16x8*)(outb + (size_t)c * 8) = o;
    }
}

// ---------- 256x256 GEMM, 2-barrier overlapped K-loop ----------
// All 24 frag ds_reads issue at tile start; M1/M2 consume aL/bL/bH before the mid
// barrier (compiler inserts counted lgkmcnt per use), proving Alo/Blo/Bhi slots dead
// before S2-4 overwrite them. aH's slot is only written by S1 of the NEXT tile
// (after the end barrier). DS-pipe work now overlaps MFMA instead of alternating.
template <typename OutT>
__global__ __launch_bounds__(512, 1) void k_gemm256(const f16* __restrict__ A,
                                                    const f16* __restrict__ B,
                                                    OutT* __restrict__ C, int M, int N, int K) {
    extern __shared__ char smem[];
    f16* As = (f16*)smem;            // [2][256][64]
    f16* Bs = (f16*)smem + 32768;    // [2][256][64]
    const int tid = threadIdx.x, lane = tid & 63, w = tid >> 6;
    const int wr4 = w >> 1, wc2 = w & 1;
    const int cq = lane & 15, gq = lane >> 4;
    const int nbx = gridDim.x;                 // n tiles: 16 (GEMM1) or 8 (GEMM2)
    const int bid0 = blockIdx.y * nbx + blockIdx.x;
    const int x = bid0 & 7, idx = bid0 >> 3;   // XCD id, local index
    const int snb = (nbx == 16) ? 3 : 2;       // log2(nbx/2)
    const int mt = (x >> 1) * 8 + (idx >> snb);
    const int nt = (x & 1) * (nbx >> 1) + (idx & ((nbx >> 1) - 1));
    const int m0 = mt * 256, n0 = nt * 256;
    const int KT = K >> 6;

    f32x4 acc[2][2][2][4] = {};
    f16x8 aL[2][2], aH[2][2], bL[4][2], bH[4][2];

    auto stageA = [&](int buf, int half, int t) {
#pragma unroll
        for (int r = 0; r < 2; ++r) {
            int cb = r * 512 + w * 64;
            int c = cb + lane;
            int row = c >> 3, cc = c & 7;
            gld_lds16(A + (size_t)(m0 + half * 128 + row) * K + t * 64 + ((cc ^ (row & 7)) * 8),
                      As + buf * 16384 + half * 8192 + cb * 8);
        }
    };
    auto stageB = [&](int buf, int half, int t) {
#pragma unroll
        for (int r = 0; r < 2; ++r) {
            int cb = r * 512 + w * 64;
            int c = cb + lane;
            int row = c >> 3, cc = c & 7;
            gld_lds16(B + (size_t)(n0 + half * 128 + row) * K + t * 64 + ((cc ^ (row & 7)) * 8),
                      Bs + buf * 16384 + half * 8192 + cb * 8);
        }
    };
    auto rdA = [&](int buf, int qr, f16x8 a[2][2]) {
#pragma unroll
        for (int mi = 0; mi < 2; ++mi)
#pragma unroll
            for (int ks = 0; ks < 2; ++ks) {
                int R = qr * 128 + wr4 * 32 + mi * 16 + cq;
                a[mi][ks] = *(const f16x8*)&As[buf * 16384 + R * 64 + (((ks * 4 + gq) ^ (cq & 7)) * 8)];
            }
    };
    auto rdB = [&](int buf, int qc, f16x8 b[4][2]) {
#pragma unroll
        for (int ni = 0; ni < 4; ++ni)
#pragma unroll
            for (int ks = 0; ks < 2; ++ks) {
                int R = qc * 128 + wc2 * 64 + ni * 16 + cq;
                b[ni][ks] = *(const f16x8*)&Bs[buf * 16384 + R * 64 + (((ks * 4 + gq) ^ (cq & 7)) * 8)];
            }
    };

    // prologue: tile0 all 4 halves + tile1 {Alo,Blo,Bhi}; drain tile0's 8
    stageA(0, 0, 0); stageB(0, 0, 0); stageB(0, 1, 0); stageA(0, 1, 0);
    if (KT > 1) { stageA(1, 0, 1); stageB(1, 0, 1); stageB(1, 1, 1); }
    asm volatile("s_waitcnt vmcnt(6)");
    __builtin_amdgcn_s_barrier();

#pragma unroll 1
    for (int t = 0; t < KT; ++t) {
        const int buf = t & 1;
        // issue ALL fragment reads for this tile (reads overlap MFMA below)
        rdA(buf, 0, aL); rdB(buf, 0, bL); rdB(buf, 1, bH); rdA(buf, 1, aH);
        // M1: Q(0,0) = aL x bL
        __builtin_amdgcn_s_setprio(1);
#pragma unroll
        for (int mi = 0; mi < 2; ++mi)
#pragma unroll
            for (int ni = 0; ni < 4; ++ni)
#pragma unroll
                for (int ks = 0; ks < 2; ++ks)
                    acc[0][0][mi][ni] = __builtin_amdgcn_mfma_f32_16x16x32_f16(aL[mi][ks], bL[ni][ks], acc[0][0][mi][ni], 0, 0, 0);
        __builtin_amdgcn_s_setprio(0);
        if (t + 1 < KT) stageA(buf ^ 1, 1, t + 1);  // S1: Ahi(t+1) -> other buf
        // M2: Q(0,1) = aL x bH
        __builtin_amdgcn_s_setprio(1);
#pragma unroll
        for (int mi = 0; mi < 2; ++mi)
#pragma unroll
            for (int ni = 0; ni < 4; ++ni)
#pragma unroll
                for (int ks = 0; ks < 2; ++ks)
                    acc[0][1][mi][ni] = __builtin_amdgcn_mfma_f32_16x16x32_f16(aL[mi][ks], bH[ni][ks], acc[0][1][mi][ni], 0, 0, 0);
        __builtin_amdgcn_s_setprio(0);
        // all waves consumed aL/bL/bH (M1,M2 done) -> Alo/Blo/Bhi slots dead
        __builtin_amdgcn_s_barrier();
        if (t + 2 < KT) { stageA(buf, 0, t + 2); stageB(buf, 0, t + 2); stageB(buf, 1, t + 2); }  // S2-4
        // M3: Q(1,1) = aH x bH ; M4: Q(1,0) = aH x bL
        __builtin_amdgcn_s_setprio(1);
#pragma unroll
        for (int mi = 0; mi < 2; ++mi)
#pragma unroll
            for (int ni = 0; ni < 4; ++ni)
#pragma unroll
                for (int ks = 0; ks < 2; ++ks)
                    acc[1][1][mi][ni] = __builtin_amdgcn_mfma_f32_16x16x32_f16(aH[mi][ks], bH[ni][ks], acc[1][1][mi][ni], 0, 0, 0);
#pragma unroll
        for (int mi = 0; mi < 2; ++mi)
#pragma unroll
            for (int ni = 0; ni < 4; ++ni)
#pragma unroll
                for (int ks = 0; ks < 2; ++ks)
                    acc[1][0][mi][ni] = __builtin_amdgcn_mfma_f32_16x16x32_f16(aH[mi][ks], bL[ni][ks], acc[1][0][mi][ni], 0, 0, 0);
        __builtin_amdgcn_s_setprio(0);
        // counted drain: all of tile t+1 arrives; t+2's 3 half-tiles stay in flight
        if (t + 2 < KT)      asm volatile("s_waitcnt vmcnt(6)");
        else                 asm volatile("s_waitcnt vmcnt(0)");
        __builtin_amdgcn_s_barrier();
    }

#pragma unroll
    for (int qr = 0; qr < 2; ++qr)
#pragma unroll
        for (int qc = 0; qc < 2; ++qc)
#pragma unroll
            for (int mi = 0; mi < 2; ++mi)
#pragma unroll
                for (int ni = 0; ni < 4; ++ni)
#pragma unroll
                    for (int i = 0; i < 4; ++i) {
                        int row = m0 + qr * 128 + wr4 * 32 + mi * 16 + gq * 4 + i;
                        int col = n0 + qc * 128 + wc2 * 64 + ni * 16 + cq;
                        C[(size_t)row * N + col] = (OutT)acc[qr][qc][mi][ni][i];
                    }
}

// ---------- in-place xPos RoPE on qkv [8192][4096]; Q gets *scale*rsqrt(d), K gets /scale ----------
__global__ __launch_bounds__(256) void k_rope(f16* __restrict__ qkv, const float* __restrict__ tab) {
    int idx = blockIdx.x * 256 + threadIdx.x;
    const int QTOT = NBATCH * T_SEQ * 16 * 64;  // 8,388,608
    int f, col0, bt;
    bool isQ = idx < QTOT;
    if (isQ) {
        f = idx & 63; int hh = (idx >> 6) & 15; bt = idx >> 10;
        col0 = hh * 128 + f;
    } else {
        int j = idx - QTOT;
        f = j & 63; int hh = (j >> 6) & 7; bt = j >> 9;
        col0 = 2048 + hh * 128 + f;
    }
    int t = bt & (T_SEQ - 1);
    float cs = tab[t * 64 + f], sn = tab[131072 + t * 64 + f], sc = tab[262144 + t * 64 + f];
    float mult = isQ ? sc * 0.08838834764831845f : 1.0f / sc;  // fold 1/sqrt(128) into Q
    size_t p = (size_t)bt * 4096 + col0;
    float x1 = (float)qkv[p], x2 = (float)qkv[p + 64];
    qkv[p]      = (f16)((x1 * cs - x2 * sn) * mult);
    qkv[p + 64] = (f16)((x2 * cs + x1 * sn) * mult);
}

// ---------- causal GQA flash attention, v5: 2 heads/block, 8 waves sharing K/V LDS ----------
__global__ __launch_bounds__(512) void k_attn(const f16* __restrict__ qkv,
                                              const f16* __restrict__ vtg,
                                              f16* __restrict__ ao) {
    const int bid0 = blockIdx.x;
    const int bid = (bid0 & 7) * 32 + (bid0 >> 3);  // XCD swizzle (256 = 8x32)
    const int pr = bid & 7, kvh = (bid >> 3) & 7, b = bid >> 6;
    const int bk = b * 8 + kvh;
    const int tid = threadIdx.x, lane = tid & 63, w = tid >> 6;
    const int w4 = w & 3, hg = w >> 2;
    const int h = kvh * 2 + hg;
    const int l31 = lane & 31, hi = lane >> 5;

    __shared__ f16 Klds[2][64 * 128];
    __shared__ f16 Vlds[2][8 * 128 * 8];

    const f16* kbase = qkv + (size_t)b * T_SEQ * 4096 + 2048 + kvh * 128;
    const f16* vbase = vtg + (size_t)bk * 32 * 8192;

    auto stage = [&](int buf, int kt) {
#pragma unroll
        for (int qq = 0; qq < 2; ++qq) {
            int c = w * 128 + qq * 64 + lane;
            int row = c >> 4;
            int ch = (c & 15) ^ (row & 15);
            gld_lds16(kbase + (size_t)(kt * 64 + row) * 4096 + ch * 8,
                      &Klds[buf][(w * 128 + qq * 64) * 8]);
        }
#pragma unroll
        for (int qq = 0; qq < 2; ++qq) {
            int c = w * 128 + qq * 64 + lane;
            gld_lds16(vbase + ((size_t)kt * 1024 + c) * 8,
                      &Vlds[buf][(w * 128 + qq * 64) * 8]);
        }
    };

#pragma unroll 1
    for (int hf = 0; hf < 2; ++hf) {
        const int qt = hf ? pr : (15 - pr);
        const int q0 = qt * 128;
        const int nkt = 2 * qt + 2;  // even, >= 2
        const int qrow = q0 + w4 * 32 + l31;

        f16x8 qf[8];
#pragma unroll
        for (int ds = 0; ds < 8; ++ds)
            qf[ds] = *(const f16x8*)(qkv + (size_t)(b * T_SEQ + qrow) * 4096 + h * 128 + ds * 16 + hi * 8);

        f32x16 Ot[4] = {};
        float mrow = -1e30f, lrow = 0.0f;

        stage(0, 0);
        __syncthreads();

#pragma unroll 1
        for (int kt = 0; kt < nkt; ++kt) {
            const int kb = kt & 1;
            if (kt + 1 < nkt) stage(kb ^ 1, kt + 1);

            if (!(kt == 2 * qt + 1 && w4 < 2)) {
                // ---- St = K Q^T (swapped): lane q = l31, k rows in regs ----
                f32x16 St0 = {}, St1 = {};
                __builtin_amdgcn_s_setprio(1);
#pragma unroll
                for (int ds = 0; ds < 8; ++ds) {
                    int slot = (((2 * ds + hi) ^ (l31 & 15)) << 3);
                    f16x8 k0 = *(const f16x8*)&Klds[kb][l31 * 128 + slot];
                    f16x8 k1 = *(const f16x8*)&Klds[kb][(32 + l31) * 128 + slot];
                    St0 = __builtin_amdgcn_mfma_f32_32x32x16_f16(k0, qf[ds], St0, 0, 0, 0);
                    St1 = __builtin_amdgcn_mfma_f32_32x32x16_f16(k1, qf[ds], St1, 0, 0, 0);
                }
                __builtin_amdgcn_s_setprio(0);

                // ---- causal mask ----
                if (kt >= 2 * qt) {
                    int kbase2 = kt * 64;
#pragma unroll
                    for (int r = 0; r < 16; ++r) {
                        int krel = (r & 3) + 8 * (r >> 2) + 4 * hi;
                        if (kbase2 + krel > qrow) St0[r] = -1e30f;
                        if (kbase2 + 32 + krel > qrow) St1[r] = -1e30f;
                    }
                }

                // ---- in-register online softmax ----
                float tm[16];
#pragma unroll
                for (int r = 0; r < 16; ++r) tm[r] = fmaxf(St0[r], St1[r]);
#pragma unroll
                for (int d = 8; d >= 1; d >>= 1)
#pragma unroll
                    for (int r = 0; r < 8; ++r)
                        if (r < d) tm[r] = fmaxf(tm[r], tm[r + d]);
                float tmax = tm[0];
                float mtile = fmaxf(tmax, __shfl_xor(tmax, 32, 64));

                if (!__all((mtile - mrow) <= 8.0f)) {  // T13 defer-max
                    float mnew = fmaxf(mrow, mtile);
                    float fs = __expf(mrow - mnew);
                    mrow = mnew;
                    lrow *= fs;
#pragma unroll
                    for (int dblk = 0; dblk < 4; ++dblk)
#pragma unroll
                        for (int e = 0; e < 16; ++e) Ot[dblk][e] *= fs;
                }
#pragma unroll
                for (int r = 0; r < 16; ++r) {
                    St0[r] = __expf(St0[r] - mrow);
                    St1[r] = __expf(St1[r] - mrow);
                }
                float ts[16];
#pragma unroll
                for (int r = 0; r < 16; ++r) ts[r] = St0[r] + St1[r];
#pragma unroll
                for (int d = 8; d >= 1; d >>= 1)
#pragma unroll
                    for (int r = 0; r < 8; ++r)
                        if (r < d) ts[r] += ts[r + d];
                float tsum = ts[0];
                lrow += tsum + __shfl_xor(tsum, 32, 64);

                // ---- pack P (cvt_pkrtz + shfl_xor 32) + PV ----
#define PV_P(o, pos) ((o) < 4 ? St0[((o) & 3) * 4 + (pos)] : St1[((o) & 3) * 4 + (pos)])
#pragma unroll
                for (int s = 0; s < 4; ++s) {
                    unsigned x1 = pk2(PV_P(2 * s, 0), PV_P(2 * s, 1));
                    unsigned x2 = pk2(PV_P(2 * s, 2), PV_P(2 * s, 3));
                    unsigned y1 = pk2(PV_P(2 * s + 1, 0), PV_P(2 * s + 1, 1));
                    unsigned y2 = pk2(PV_P(2 * s + 1, 2), PV_P(2 * s + 1, 3));
                    unsigned sx1 = __shfl_xor(x1, 32, 64);
                    unsigned sx2 = __shfl_xor(x2, 32, 64);
                    unsigned sy1 = __shfl_xor(y1, 32, 64);
                    unsigned sy2 = __shfl_xor(y2, 32, 64);
                    u32x4 pw;
                    pw[0] = hi ? sy1 : x1;
                    pw[1] = hi ? sy2 : x2;
                    pw[2] = hi ? y1 : sx1;
                    pw[3] = hi ? y2 : sx2;
                    f16x8 pa = __builtin_bit_cast(f16x8, pw);
                    __builtin_amdgcn_s_setprio(1);
#pragma unroll
                    for (int dblk = 0; dblk < 4; ++dblk) {
                        f16x8 vb = *(const f16x8*)&Vlds[kb][(((2 * s + hi) << 7) + 32 * dblk + l31) << 3];
                        Ot[dblk] = __builtin_amdgcn_mfma_f32_32x32x16_f16(vb, pa, Ot[dblk], 0, 0, 0);
                    }
                    __builtin_amdgcn_s_setprio(0);
                }
#undef PV_P
            }
            __syncthreads();  // buf kb readers done; K/V(kt+1) staged (vmcnt drained)
        }

        // ---- epilogue ----
        {
            float inv = 1.0f / lrow;
            size_t rowb = (size_t)(b * T_SEQ + qrow) * 2048 + h * 128;
#pragma unroll
            for (int dblk = 0; dblk < 4; ++dblk)
#pragma unroll
                for (int rg = 0; rg < 4; ++rg) {
                    f16x4 o4 = { (f16)(Ot[dblk][rg * 4 + 0] * inv), (f16)(Ot[dblk][rg * 4 + 1] * inv),
                                 (f16)(Ot[dblk][rg * 4 + 2] * inv), (f16)(Ot[dblk][rg * 4 + 3] * inv) };
                    *(f16x4*)(ao + rowb + dblk * 32 + rg * 8 + hi * 4) = o4;
                }
        }
    }
}

extern "C" void kernel_launch(void* const* d_in, const int* in_sizes, int n_in,
                              void* d_out, int out_size, void* d_ws, size_t ws_size,
                              hipStream_t stream) {
    const float* x  = (const float*)d_in[0];
    const float* Wq = (const float*)d_in[1];
    const float* Wk = (const float*)d_in[2];
    const float* Wv = (const float*)d_in[3];
    const float* Wo = (const float*)d_in[4];
    float* out = (float*)d_out;

    // workspace (fp16 elems): xh 16.7M | wqkvT 8.4M | woT 4.2M | qkv 33.5M | tab (f32)
    f16* xh    = (f16*)d_ws;
    f16* wqkvT = xh + (size_t)16777216;
    f16* woT   = wqkvT + (size_t)8388608;
    f16* qkv   = woT + (size_t)4194304;
    float* tab = (float*)(qkv + (size_t)33554432);
    f16* ao  = xh;     // alias: xh dead after GEMM1
    f16* vtg = wqkvT;  // alias: wqkvT dead after GEMM1 (8.4M f16 = exact fit)

    hipFuncSetAttribute(reinterpret_cast<const void*>(&k_gemm256<f16>),
                        hipFuncAttributeMaxDynamicSharedMemorySize, 131072);
    hipFuncSetAttribute(reinterpret_cast<const void*>(&k_gemm256<float>),
                        hipFuncAttributeMaxDynamicSharedMemorySize, 131072);

    k_prep<<<29184, 256, 0, stream>>>(x, Wq, Wk, Wv, Wo, xh, wqkvT, woT, tab);
    // QKV projection: qkv[8192][4096]
    k_gemm256<f16><<<dim3(16, 32), 512, 131072, stream>>>(xh, wqkvT, qkv, 8192, 4096, 2048);
    k_vtrans<<<dim3(32, 32), 256, 0, stream>>>(qkv, vtg);
    k_rope<<<49152, 256, 0, stream>>>(qkv, tab);
    k_attn<<<256, 512, 0, stream>>>(qkv, vtg, ao);
    // output projection -> fp32
    k_gemm256<float><<<dim3(8, 32), 512, 131072, stream>>>(ao, woT, out, 8192, 2048, 2048);
}

// Round 11
// 370.469 us; speedup vs baseline: 2.1743x; 1.0087x over previous
//
#include <hip/hip_runtime.h>

typedef _Float16 f16;
typedef __attribute__((ext_vector_type(8))) _Float16 f16x8;
typedef __attribute__((ext_vector_type(4))) _Float16 f16x4;
typedef __attribute__((ext_vector_type(4))) float f32x4;
typedef __attribute__((ext_vector_type(16))) float f32x16;
typedef __attribute__((ext_vector_type(4))) unsigned u32x4;

#define T_SEQ 2048
#define NBATCH 4

__device__ __forceinline__ void gld_lds16(const f16* g, f16* l) {
    __builtin_amdgcn_global_load_lds((const __attribute__((address_space(1))) void*)g,
                                     (__attribute__((address_space(3))) void*)l, 16, 0, 0);
}

__device__ __forceinline__ unsigned pk2(float a, float b) {
    __attribute__((ext_vector_type(2))) __fp16 h = __builtin_amdgcn_cvt_pkrtz(a, b);
    return __builtin_bit_cast(unsigned, h);
}

// ---------- fused prep: cast x | transpose Wq/Wk/Wv/Wo | xPos tables ----------
__global__ __launch_bounds__(256) void k_prep(const float* __restrict__ x,
                                              const float* __restrict__ Wq,
                                              const float* __restrict__ Wk,
                                              const float* __restrict__ Wv,
                                              const float* __restrict__ Wo,
                                              f16* __restrict__ xh,
                                              f16* __restrict__ wqkvT,
                                              f16* __restrict__ woT,
                                              float* __restrict__ tab) {
    __shared__ float tile[32][33];
    int bidx = blockIdx.x;
    if (bidx < 16384) {  // cast x fp32 -> fp16 (float4 per thread)
        int i = bidx * 256 + threadIdx.x;
        float4 v = ((const float4*)x)[i];
        f16x4 o = { (f16)v.x, (f16)v.y, (f16)v.z, (f16)v.w };
        ((f16x4*)xh)[i] = o;
        return;
    }
    bidx -= 16384;
    if (bidx >= 12288) {  // tables: cos | sin | scale, each [T][64] fp32
        int i = (bidx - 12288) * 256 + threadIdx.x;  // 131072 total
        int t = i >> 6, f = i & 63;
        float inv_freq = powf(10000.0f, -(2.0f * f) / 128.0f);
        float ang = (float)t * inv_freq;
        float sv = (2.0f * f + 51.2f) / 179.2f;
        float pw = ((float)t - 1024.0f) / 512.0f;
        tab[i] = cosf(ang);
        tab[131072 + i] = sinf(ang);
        tab[262144 + i] = powf(sv, pw);
        return;
    }
    // weight transpose+cast: dst[n][k] = (f16)src[k][n], K=2048
    const float* src; f16* dst; int N, bx, by;
    if (bidx < 4096)      { src = Wq; dst = wqkvT;                      N = 2048; bx = bidx & 63; by = bidx >> 6; }
    else if (bidx < 6144) { src = Wk; dst = wqkvT + (size_t)2048 * 2048; N = 1024; int t2 = bidx - 4096; bx = t2 & 31; by = t2 >> 5; }
    else if (bidx < 8192) { src = Wv; dst = wqkvT + (size_t)3072 * 2048; N = 1024; int t2 = bidx - 6144; bx = t2 & 31; by = t2 >> 5; }
    else                  { src = Wo; dst = woT;                        N = 2048; int t2 = bidx - 8192; bx = t2 & 63; by = t2 >> 6; }
    int n0 = bx * 32, k0 = by * 32;
    int tx = threadIdx.x & 31, ty = threadIdx.x >> 5;  // 32 x 8
#pragma unroll
    for (int j = 0; j < 32; j += 8)
        tile[ty + j][tx] = src[(size_t)(k0 + ty + j) * N + n0 + tx];
    __syncthreads();
#pragma unroll
    for (int j = 0; j < 32; j += 8)
        dst[(size_t)(n0 + ty + j) * 2048 + k0 + tx] = (f16)tile[tx][ty + j];
}

// ---------- V blocked-transpose for attention ----------
__global__ __launch_bounds__(256) void k_vtrans(const f16* __restrict__ qkv, f16* __restrict__ vtg) {
    const int kt = blockIdx.x, bk = blockIdx.y;
    const int b = bk >> 3, kvh = bk & 7;
    const int tid = threadIdx.x;
    __shared__ f16 tile[64][132];
#pragma unroll
    for (int p = 0; p < 4; ++p) {
        int idx = p * 256 + tid;
        int r = idx >> 4, dc = (idx & 15) * 8;
        f16x8 v = *(const f16x8*)(qkv + (size_t)(b * T_SEQ + kt * 64 + r) * 4096 + 3072 + kvh * 128 + dc);
#pragma unroll
        for (int j = 0; j < 8; ++j) tile[r][dc + j] = v[j];
    }
    __syncthreads();
    f16* outb = vtg + (size_t)(bk * 32 + kt) * 8192;
#pragma unroll
    for (int p = 0; p < 4; ++p) {
        int c = p * 256 + tid;
        int kchunk = c >> 7, d = c & 127;
        f16x8 o;
#pragma unroll
        for (int j = 0; j < 8; ++j) o[j] = tile[kchunk * 8 + j][d];
        *(f16x8*)(outb + (size_t)c * 8) = o;
    }
}

// ---------- 256x256 GEMM, 2-barrier overlapped K-loop ----------
template <typename OutT>
__global__ __launch_bounds__(512, 1) void k_gemm256(const f16* __restrict__ A,
                                                    const f16* __restrict__ B,
                                                    OutT* __restrict__ C, int M, int N, int K) {
    extern __shared__ char smem[];
    f16* As = (f16*)smem;            // [2][256][64]
    f16* Bs = (f16*)smem + 32768;    // [2][256][64]
    const int tid = threadIdx.x, lane = tid & 63, w = tid >> 6;
    const int wr4 = w >> 1, wc2 = w & 1;
    const int cq = lane & 15, gq = lane >> 4;
    const int nbx = gridDim.x;                 // n tiles: 16 (GEMM1) or 8 (GEMM2)
    const int bid0 = blockIdx.y * nbx + blockIdx.x;
    const int x = bid0 & 7, idx = bid0 >> 3;   // XCD id, local index
    const int snb = (nbx == 16) ? 3 : 2;       // log2(nbx/2)
    const int mt = (x >> 1) * 8 + (idx >> snb);
    const int nt = (x & 1) * (nbx >> 1) + (idx & ((nbx >> 1) - 1));
    const int m0 = mt * 256, n0 = nt * 256;
    const int KT = K >> 6;

    f32x4 acc[2][2][2][4] = {};
    f16x8 aL[2][2], aH[2][2], bL[4][2], bH[4][2];

    auto stageA = [&](int buf, int half, int t) {
#pragma unroll
        for (int r = 0; r < 2; ++r) {
            int cb = r * 512 + w * 64;
            int c = cb + lane;
            int row = c >> 3, cc = c & 7;
            gld_lds16(A + (size_t)(m0 + half * 128 + row) * K + t * 64 + ((cc ^ (row & 7)) * 8),
                      As + buf * 16384 + half * 8192 + cb * 8);
        }
    };
    auto stageB = [&](int buf, int half, int t) {
#pragma unroll
        for (int r = 0; r < 2; ++r) {
            int cb = r * 512 + w * 64;
            int c = cb + lane;
            int row = c >> 3, cc = c & 7;
            gld_lds16(B + (size_t)(n0 + half * 128 + row) * K + t * 64 + ((cc ^ (row & 7)) * 8),
                      Bs + buf * 16384 + half * 8192 + cb * 8);
        }
    };
    auto rdA = [&](int buf, int qr, f16x8 a[2][2]) {
#pragma unroll
        for (int mi = 0; mi < 2; ++mi)
#pragma unroll
            for (int ks = 0; ks < 2; ++ks) {
                int R = qr * 128 + wr4 * 32 + mi * 16 + cq;
                a[mi][ks] = *(const f16x8*)&As[buf * 16384 + R * 64 + (((ks * 4 + gq) ^ (cq & 7)) * 8)];
            }
    };
    auto rdB = [&](int buf, int qc, f16x8 b[4][2]) {
#pragma unroll
        for (int ni = 0; ni < 4; ++ni)
#pragma unroll
            for (int ks = 0; ks < 2; ++ks) {
                int R = qc * 128 + wc2 * 64 + ni * 16 + cq;
                b[ni][ks] = *(const f16x8*)&Bs[buf * 16384 + R * 64 + (((ks * 4 + gq) ^ (cq & 7)) * 8)];
            }
    };

    // prologue: tile0 all 4 halves + tile1 {Alo,Blo,Bhi}; drain tile0's 8
    stageA(0, 0, 0); stageB(0, 0, 0); stageB(0, 1, 0); stageA(0, 1, 0);
    if (KT > 1) { stageA(1, 0, 1); stageB(1, 0, 1); stageB(1, 1, 1); }
    asm volatile("s_waitcnt vmcnt(6)");
    __builtin_amdgcn_s_barrier();

#pragma unroll 1
    for (int t = 0; t < KT; ++t) {
        const int buf = t & 1;
        // issue ALL fragment reads for this tile (reads overlap MFMA below)
        rdA(buf, 0, aL); rdB(buf, 0, bL); rdB(buf, 1, bH); rdA(buf, 1, aH);
        // M1: Q(0,0) = aL x bL
        __builtin_amdgcn_s_setprio(1);
#pragma unroll
        for (int mi = 0; mi < 2; ++mi)
#pragma unroll
            for (int ni = 0; ni < 4; ++ni)
#pragma unroll
                for (int ks = 0; ks < 2; ++ks)
                    acc[0][0][mi][ni] = __builtin_amdgcn_mfma_f32_16x16x32_f16(aL[mi][ks], bL[ni][ks], acc[0][0][mi][ni], 0, 0, 0);
        __builtin_amdgcn_s_setprio(0);
        if (t + 1 < KT) stageA(buf ^ 1, 1, t + 1);  // S1: Ahi(t+1) -> other buf
        // M2: Q(0,1) = aL x bH
        __builtin_amdgcn_s_setprio(1);
#pragma unroll
        for (int mi = 0; mi < 2; ++mi)
#pragma unroll
            for (int ni = 0; ni < 4; ++ni)
#pragma unroll
                for (int ks = 0; ks < 2; ++ks)
                    acc[0][1][mi][ni] = __builtin_amdgcn_mfma_f32_16x16x32_f16(aL[mi][ks], bH[ni][ks], acc[0][1][mi][ni], 0, 0, 0);
        __builtin_amdgcn_s_setprio(0);
        // all waves consumed aL/bL/bH (M1,M2 done) -> Alo/Blo/Bhi slots dead
        __builtin_amdgcn_s_barrier();
        if (t + 2 < KT) { stageA(buf, 0, t + 2); stageB(buf, 0, t + 2); stageB(buf, 1, t + 2); }  // S2-4
        // M3: Q(1,1) = aH x bH ; M4: Q(1,0) = aH x bL
        __builtin_amdgcn_s_setprio(1);
#pragma unroll
        for (int mi = 0; mi < 2; ++mi)
#pragma unroll
            for (int ni = 0; ni < 4; ++ni)
#pragma unroll
                for (int ks = 0; ks < 2; ++ks)
                    acc[1][1][mi][ni] = __builtin_amdgcn_mfma_f32_16x16x32_f16(aH[mi][ks], bH[ni][ks], acc[1][1][mi][ni], 0, 0, 0);
#pragma unroll
        for (int mi = 0; mi < 2; ++mi)
#pragma unroll
            for (int ni = 0; ni < 4; ++ni)
#pragma unroll
                for (int ks = 0; ks < 2; ++ks)
                    acc[1][0][mi][ni] = __builtin_amdgcn_mfma_f32_16x16x32_f16(aH[mi][ks], bL[ni][ks], acc[1][0][mi][ni], 0, 0, 0);
        __builtin_amdgcn_s_setprio(0);
        // counted drain: all of tile t+1 arrives; t+2's 3 half-tiles stay in flight
        if (t + 2 < KT)      asm volatile("s_waitcnt vmcnt(6)");
        else                 asm volatile("s_waitcnt vmcnt(0)");
        __builtin_amdgcn_s_barrier();
    }

#pragma unroll
    for (int qr = 0; qr < 2; ++qr)
#pragma unroll
        for (int qc = 0; qc < 2; ++qc)
#pragma unroll
            for (int mi = 0; mi < 2; ++mi)
#pragma unroll
                for (int ni = 0; ni < 4; ++ni)
#pragma unroll
                    for (int i = 0; i < 4; ++i) {
                        int row = m0 + qr * 128 + wr4 * 32 + mi * 16 + gq * 4 + i;
                        int col = n0 + qc * 128 + wc2 * 64 + ni * 16 + cq;
                        C[(size_t)row * N + col] = (OutT)acc[qr][qc][mi][ni][i];
                    }
}

// ---------- in-place xPos RoPE on qkv [8192][4096]; Q gets *scale*rsqrt(d), K gets /scale ----------
__global__ __launch_bounds__(256) void k_rope(f16* __restrict__ qkv, const float* __restrict__ tab) {
    int idx = blockIdx.x * 256 + threadIdx.x;
    const int QTOT = NBATCH * T_SEQ * 16 * 64;  // 8,388,608
    int f, col0, bt;
    bool isQ = idx < QTOT;
    if (isQ) {
        f = idx & 63; int hh = (idx >> 6) & 15; bt = idx >> 10;
        col0 = hh * 128 + f;
    } else {
        int j = idx - QTOT;
        f = j & 63; int hh = (j >> 6) & 7; bt = j >> 9;
        col0 = 2048 + hh * 128 + f;
    }
    int t = bt & (T_SEQ - 1);
    float cs = tab[t * 64 + f], sn = tab[131072 + t * 64 + f], sc = tab[262144 + t * 64 + f];
    float mult = isQ ? sc * 0.08838834764831845f : 1.0f / sc;  // fold 1/sqrt(128) into Q
    size_t p = (size_t)bt * 4096 + col0;
    float x1 = (float)qkv[p], x2 = (float)qkv[p + 64];
    qkv[p]      = (f16)((x1 * cs - x2 * sn) * mult);
    qkv[p + 64] = (f16)((x2 * cs + x1 * sn) * mult);
}

// ---------- causal GQA flash attention, v6: triple-buffered K/V ring, counted vmcnt ----------
// 2 heads/block, 8 waves. LDS ring of 3 buffers (96 KB dynamic): stage(kt+2) issued at
// tile tail; top-of-tile waits vmcnt(4) only (kt+1's loads stay in flight) -> no full
// HBM/L2 drain inside the loop. Raw s_barrier (no wave writes LDS; ds_reads complete
// before barrier via compiler lgkmcnt; buffer reuse is 2 barriers away).
__global__ __launch_bounds__(512) void k_attn(const f16* __restrict__ qkv,
                                              const f16* __restrict__ vtg,
                                              f16* __restrict__ ao) {
    extern __shared__ f16 asmem[];   // [3][16384]: per buf K 8192 | V 8192
    const int bid0 = blockIdx.x;
    const int bid = (bid0 & 7) * 32 + (bid0 >> 3);  // XCD swizzle (256 = 8x32)
    const int pr = bid & 7, kvh = (bid >> 3) & 7, b = bid >> 6;
    const int bk = b * 8 + kvh;
    const int tid = threadIdx.x, lane = tid & 63, w = tid >> 6;
    const int w4 = w & 3, hg = w >> 2;
    const int h = kvh * 2 + hg;
    const int l31 = lane & 31, hi = lane >> 5;

    const f16* kbase = qkv + (size_t)b * T_SEQ * 4096 + 2048 + kvh * 128;
    const f16* vbase = vtg + (size_t)bk * 32 * 8192;

    auto stage = [&](int buf, int kt) {
        f16* kb_ = asmem + buf * 16384;
        f16* vb_ = kb_ + 8192;
#pragma unroll
        for (int qq = 0; qq < 2; ++qq) {
            int c = w * 128 + qq * 64 + lane;
            int row = c >> 4;
            int ch = (c & 15) ^ (row & 15);
            gld_lds16(kbase + (size_t)(kt * 64 + row) * 4096 + ch * 8, kb_ + (w * 128 + qq * 64) * 8);
        }
#pragma unroll
        for (int qq = 0; qq < 2; ++qq) {
            int c = w * 128 + qq * 64 + lane;
            gld_lds16(vbase + ((size_t)kt * 1024 + c) * 8, vb_ + (w * 128 + qq * 64) * 8);
        }
    };

#pragma unroll 1
    for (int hf = 0; hf < 2; ++hf) {
        const int qt = hf ? pr : (15 - pr);
        const int q0 = qt * 128;
        const int nkt = 2 * qt + 2;  // even, >= 2
        const int qrow = q0 + w4 * 32 + l31;

        f16x8 qf[8];
#pragma unroll
        for (int ds = 0; ds < 8; ++ds)
            qf[ds] = *(const f16x8*)(qkv + (size_t)(b * T_SEQ + qrow) * 4096 + h * 128 + ds * 16 + hi * 8);

        f32x16 Ot[4] = {};
        float mrow = -1e30f, lrow = 0.0f;

        stage(0, 0);
        if (nkt > 1) stage(1, 1);

#pragma unroll 1
        for (int kt = 0; kt < nkt; ++kt) {
            const int kb = kt % 3;
            const f16* Kl = asmem + kb * 16384;
            const f16* Vl = Kl + 8192;
            // wait for THIS tile's loads only; kt+1's 4 loads stay in flight
            if (kt + 1 < nkt) asm volatile("s_waitcnt vmcnt(4)");
            else              asm volatile("s_waitcnt vmcnt(0)");
            __builtin_amdgcn_s_barrier();

            if (!(kt == 2 * qt + 1 && w4 < 2)) {
                // ---- St = K Q^T (swapped): lane q = l31, k rows in regs ----
                f32x16 St0 = {}, St1 = {};
                __builtin_amdgcn_s_setprio(1);
#pragma unroll
                for (int ds = 0; ds < 8; ++ds) {
                    int slot = (((2 * ds + hi) ^ (l31 & 15)) << 3);
                    f16x8 k0 = *(const f16x8*)&Kl[l31 * 128 + slot];
                    f16x8 k1 = *(const f16x8*)&Kl[(32 + l31) * 128 + slot];
                    St0 = __builtin_amdgcn_mfma_f32_32x32x16_f16(k0, qf[ds], St0, 0, 0, 0);
                    St1 = __builtin_amdgcn_mfma_f32_32x32x16_f16(k1, qf[ds], St1, 0, 0, 0);
                }
                __builtin_amdgcn_s_setprio(0);

                // ---- causal mask ----
                if (kt >= 2 * qt) {
                    int kbase2 = kt * 64;
#pragma unroll
                    for (int r = 0; r < 16; ++r) {
                        int krel = (r & 3) + 8 * (r >> 2) + 4 * hi;
                        if (kbase2 + krel > qrow) St0[r] = -1e30f;
                        if (kbase2 + 32 + krel > qrow) St1[r] = -1e30f;
                    }
                }

                // ---- in-register online softmax ----
                float tm[16];
#pragma unroll
                for (int r = 0; r < 16; ++r) tm[r] = fmaxf(St0[r], St1[r]);
#pragma unroll
                for (int d = 8; d >= 1; d >>= 1)
#pragma unroll
                    for (int r = 0; r < 8; ++r)
                        if (r < d) tm[r] = fmaxf(tm[r], tm[r + d]);
                float tmax = tm[0];
                float mtile = fmaxf(tmax, __shfl_xor(tmax, 32, 64));

                if (!__all((mtile - mrow) <= 8.0f)) {  // T13 defer-max
                    float mnew = fmaxf(mrow, mtile);
                    float fs = __expf(mrow - mnew);
                    mrow = mnew;
                    lrow *= fs;
#pragma unroll
                    for (int dblk = 0; dblk < 4; ++dblk)
#pragma unroll
                        for (int e = 0; e < 16; ++e) Ot[dblk][e] *= fs;
                }
#pragma unroll
                for (int r = 0; r < 16; ++r) {
                    St0[r] = __expf(St0[r] - mrow);
                    St1[r] = __expf(St1[r] - mrow);
                }
                float ts[16];
#pragma unroll
                for (int r = 0; r < 16; ++r) ts[r] = St0[r] + St1[r];
#pragma unroll
                for (int d = 8; d >= 1; d >>= 1)
#pragma unroll
                    for (int r = 0; r < 8; ++r)
                        if (r < d) ts[r] += ts[r + d];
                float tsum = ts[0];
                lrow += tsum + __shfl_xor(tsum, 32, 64);

                // ---- pack P (cvt_pkrtz + shfl_xor 32) + PV ----
#define PV_P(o, pos) ((o) < 4 ? St0[((o) & 3) * 4 + (pos)] : St1[((o) & 3) * 4 + (pos)])
#pragma unroll
                for (int s = 0; s < 4; ++s) {
                    unsigned x1 = pk2(PV_P(2 * s, 0), PV_P(2 * s, 1));
                    unsigned x2 = pk2(PV_P(2 * s, 2), PV_P(2 * s, 3));
                    unsigned y1 = pk2(PV_P(2 * s + 1, 0), PV_P(2 * s + 1, 1));
                    unsigned y2 = pk2(PV_P(2 * s + 1, 2), PV_P(2 * s + 1, 3));
                    unsigned sx1 = __shfl_xor(x1, 32, 64);
                    unsigned sx2 = __shfl_xor(x2, 32, 64);
                    unsigned sy1 = __shfl_xor(y1, 32, 64);
                    unsigned sy2 = __shfl_xor(y2, 32, 64);
                    u32x4 pw;
                    pw[0] = hi ? sy1 : x1;
                    pw[1] = hi ? sy2 : x2;
                    pw[2] = hi ? y1 : sx1;
                    pw[3] = hi ? y2 : sx2;
                    f16x8 pa = __builtin_bit_cast(f16x8, pw);
                    __builtin_amdgcn_s_setprio(1);
#pragma unroll
                    for (int dblk = 0; dblk < 4; ++dblk) {
                        f16x8 vb = *(const f16x8*)&Vl[(((2 * s + hi) << 7) + 32 * dblk + l31) << 3];
                        Ot[dblk] = __builtin_amdgcn_mfma_f32_32x32x16_f16(vb, pa, Ot[dblk], 0, 0, 0);
                    }
                    __builtin_amdgcn_s_setprio(0);
                }
#undef PV_P
            }
            __builtin_amdgcn_s_barrier();  // all reads of buf kb done before its next writer issues
            if (kt + 2 < nkt) stage((kt + 2) % 3, kt + 2);
        }

        // ---- epilogue ----
        {
            float inv = 1.0f / lrow;
            size_t rowb = (size_t)(b * T_SEQ + qrow) * 2048 + h * 128;
#pragma unroll
            for (int dblk = 0; dblk < 4; ++dblk)
#pragma unroll
                for (int rg = 0; rg < 4; ++rg) {
                    f16x4 o4 = { (f16)(Ot[dblk][rg * 4 + 0] * inv), (f16)(Ot[dblk][rg * 4 + 1] * inv),
                                 (f16)(Ot[dblk][rg * 4 + 2] * inv), (f16)(Ot[dblk][rg * 4 + 3] * inv) };
                    *(f16x4*)(ao + rowb + dblk * 32 + rg * 8 + hi * 4) = o4;
                }
        }
    }
}

extern "C" void kernel_launch(void* const* d_in, const int* in_sizes, int n_in,
                              void* d_out, int out_size, void* d_ws, size_t ws_size,
                              hipStream_t stream) {
    const float* x  = (const float*)d_in[0];
    const float* Wq = (const float*)d_in[1];
    const float* Wk = (const float*)d_in[2];
    const float* Wv = (const float*)d_in[3];
    const float* Wo = (const float*)d_in[4];
    float* out = (float*)d_out;

    // workspace (fp16 elems): xh 16.7M | wqkvT 8.4M | woT 4.2M | qkv 33.5M | tab (f32)
    f16* xh    = (f16*)d_ws;
    f16* wqkvT = xh + (size_t)16777216;
    f16* woT   = wqkvT + (size_t)8388608;
    f16* qkv   = woT + (size_t)4194304;
    float* tab = (float*)(qkv + (size_t)33554432);
    f16* ao  = xh;     // alias: xh dead after GEMM1
    f16* vtg = wqkvT;  // alias: wqkvT dead after GEMM1 (8.4M f16 = exact fit)

    hipFuncSetAttribute(reinterpret_cast<const void*>(&k_gemm256<f16>),
                        hipFuncAttributeMaxDynamicSharedMemorySize, 131072);
    hipFuncSetAttribute(reinterpret_cast<const void*>(&k_gemm256<float>),
                        hipFuncAttributeMaxDynamicSharedMemorySize, 131072);
    hipFuncSetAttribute(reinterpret_cast<const void*>(&k_attn),
                        hipFuncAttributeMaxDynamicSharedMemorySize, 98304);

    k_prep<<<29184, 256, 0, stream>>>(x, Wq, Wk, Wv, Wo, xh, wqkvT, woT, tab);
    // QKV projection: qkv[8192][4096]
    k_gemm256<f16><<<dim3(16, 32), 512, 131072, stream>>>(xh, wqkvT, qkv, 8192, 4096, 2048);
    k_vtrans<<<dim3(32, 32), 256, 0, stream>>>(qkv, vtg);
    k_rope<<<49152, 256, 0, stream>>>(qkv, tab);
    k_attn<<<256, 512, 98304, stream>>>(qkv, vtg, ao);
    // output projection -> fp32
    k_gemm256<float><<<dim3(8, 32), 512, 131072, stream>>>(ao, woT, out, 8192, 2048, 2048);
}